// Round 2
// baseline (684.519 us; speedup 1.0000x reference)
//
#include <hip/hip_runtime.h>

// ---- problem constants ----
#define B_   2
#define L_   4096
#define DM   768
#define DI   1536     // D_INNER
#define DS   64       // D_STATE
#define H_   24       // NHEADS
#define P_   64       // HEADDIM
#define CD   1664     // CONV_DIM
#define NPJ  3224     // D_IN_PROJ
#define N1   3200     // GEMM1 useful cols (z + xBC; dt cols done exactly in k_dt)
#define Q_   64       // chunk length
#define SP   76       // LDS row stride (floats) for 64-wide scan tiles

typedef short          bf16x8 __attribute__((ext_vector_type(8)));
typedef unsigned short us8    __attribute__((ext_vector_type(8)));
typedef unsigned short us4    __attribute__((ext_vector_type(4)));
typedef float          f32x4  __attribute__((ext_vector_type(4)));

__device__ __forceinline__ unsigned short f2bf(float f) {
  unsigned u = __float_as_uint(f);
  u += 0x7fffu + ((u >> 16) & 1u);   // RNE
  return (unsigned short)(u >> 16);
}
__device__ __forceinline__ float siluf(float x) { return x / (1.f + expf(-x)); }
__device__ __forceinline__ float softplusf(float x) { return (x > 20.f) ? x : log1pf(expf(x)); }

// ---------------- cast -> bf16 ----------------
__global__ void k_cast(const float* __restrict__ src, unsigned short* __restrict__ dst, int n)
{
  const int i = (blockIdx.x * 256 + threadIdx.x) * 4;
  if (i >= n) return;
  f32x4 v = *(const f32x4*)(src + i);
  us4 o;
#pragma unroll
  for (int q = 0; q < 4; ++q) o[q] = f2bf(v[q]);
  *(us4*)(dst + i) = o;
}

// ---------------- transpose + cast (R x C fp32) -> (C x R bf16) ----------------
__global__ __launch_bounds__(256)
void k_transpose_cast(const float* __restrict__ src, unsigned short* __restrict__ dst,
                      int R, int C)
{
  __shared__ float tile[32][33];
  const int tx = threadIdx.x & 31, ty = threadIdx.x >> 5;
  const int r0 = blockIdx.x * 32, c0 = blockIdx.y * 32;
#pragma unroll
  for (int r = 0; r < 4; ++r) {
    int rr = r0 + ty + r * 8, cc = c0 + tx;
    if (rr < R && cc < C) tile[ty + r * 8][tx] = src[(size_t)rr * C + cc];
  }
  __syncthreads();
#pragma unroll
  for (int r = 0; r < 4; ++r) {
    int orow = c0 + ty + r * 8, ocol = r0 + tx;
    if (orow < C && ocol < R) dst[(size_t)orow * R + ocol] = f2bf(tile[tx][ty + r * 8]);
  }
}

// ---------------- bf16 MFMA GEMM: split-column epilogue ----------------
// C(MxN) = A(MxK) @ Bt(NxK)^T. M,N multiples of 128; Bt has >= N rows.
// cols [0,ncol0) -> C0 (ld0); cols [ncol0,N) -> C1 (ld1).
__global__ __launch_bounds__(256)
void k_gemm_split(const unsigned short* __restrict__ A, const unsigned short* __restrict__ Bt,
                  float* __restrict__ C0, int ld0, int ncol0,
                  float* __restrict__ C1, int ld1, int K)
{
  const int m0 = blockIdx.x * 128, n0 = blockIdx.y * 128;
  __shared__ unsigned short As[128][40];   // pad 32->40 shorts: 2-way conflicts (free)
  __shared__ unsigned short Bs[128][40];
  const int tid  = threadIdx.x;
  const int wave = tid >> 6, lane = tid & 63;
  const int quad = lane >> 4, r16 = lane & 15;
  const int wm = (wave >> 1) * 64, wn = (wave & 1) * 64;
  f32x4 acc[4][4];
#pragma unroll
  for (int a = 0; a < 4; ++a)
#pragma unroll
    for (int bq = 0; bq < 4; ++bq) acc[a][bq] = (f32x4){0.f, 0.f, 0.f, 0.f};

  for (int k0 = 0; k0 < K; k0 += 32) {
#pragma unroll
    for (int it = 0; it < 2; ++it) {
      int chunk = tid + it * 256;           // 512 chunks of 8 shorts (16B)
      int row = chunk >> 2, c8 = (chunk & 3) * 8;
      us8 va = *(const us8*)(A + (size_t)(m0 + row) * K + k0 + c8);
      *(us8*)&As[row][c8] = va;
      us8 vb = *(const us8*)(Bt + (size_t)(n0 + row) * K + k0 + c8);
      *(us8*)&Bs[row][c8] = vb;
    }
    __syncthreads();
    bf16x8 af[4], bfr[4];
#pragma unroll
    for (int mi = 0; mi < 4; ++mi) af[mi]  = *(const bf16x8*)&As[wm + mi * 16 + r16][quad * 8];
#pragma unroll
    for (int ni = 0; ni < 4; ++ni) bfr[ni] = *(const bf16x8*)&Bs[wn + ni * 16 + r16][quad * 8];
#pragma unroll
    for (int mi = 0; mi < 4; ++mi)
#pragma unroll
      for (int ni = 0; ni < 4; ++ni)
        acc[mi][ni] = __builtin_amdgcn_mfma_f32_16x16x32_bf16(af[mi], bfr[ni], acc[mi][ni], 0, 0, 0);
    __syncthreads();
  }
#pragma unroll
  for (int mi = 0; mi < 4; ++mi)
#pragma unroll
    for (int ni = 0; ni < 4; ++ni) {
      int col = n0 + wn + ni * 16 + r16;
      float* dst; int ld, c;
      if (col < ncol0) { dst = C0; ld = ld0; c = col; }
      else             { dst = C1; ld = ld1; c = col - ncol0; }
#pragma unroll
      for (int r = 0; r < 4; ++r) {
        int row = m0 + wm + mi * 16 + quad * 4 + r;
        dst[(size_t)row * ld + c] = acc[mi][ni][r];
      }
    }
}

// ---------------- depthwise conv(4) + silu, split into xs / Bm / Cm ----------------
// segment-local rows; halo = 3 rows of raw xbc from previous segment (if g>0)
__global__ void k_conv(const float* __restrict__ xbc, const float* __restrict__ cw,
                       const float* __restrict__ cb, float* __restrict__ xs,
                       float* __restrict__ Bm, float* __restrict__ Cm,
                       const float* __restrict__ halo, int g)
{
  const int ch = blockIdx.x * 256 + threadIdx.x;
  const int lr = blockIdx.y;
  if (ch >= CD) return;
  float acc = cb[ch];
#pragma unroll
  for (int k = 0; k < 4; ++k) {
    int m = lr - 3 + k;
    float v;
    if (m >= 0)       v = xbc[(size_t)m * CD + ch];
    else if (g > 0)   v = halo[(size_t)(m + 3) * CD + ch];
    else              v = 0.f;
    acc += v * cw[ch * 4 + k];
  }
  float v = siluf(acc);
  if (ch < DI)           xs[(size_t)lr * DI + ch] = v;
  else if (ch < DI + DS) Bm[(size_t)lr * DS + (ch - DI)] = v;
  else                   Cm[(size_t)lr * DS + (ch - DI - DS)] = v;
}

// ---------------- save last 3 rows of raw xbc for next segment's conv ----------------
__global__ void k_halo(const float* __restrict__ src, float* __restrict__ dst, int n)
{
  const int i = blockIdx.x * 256 + threadIdx.x;
  if (i < n) dst[i] = src[i];
}

// ---------------- exact fp32 dt: dot(x_row, W_in[:,3200+h]) -> softplus ----------------
__global__ void k_dt(const float* __restrict__ x, const float* __restrict__ W_in,
                     const float* __restrict__ dt_bias, float* __restrict__ dtv,
                     int row0, int n)
{
  const int idx = blockIdx.x * 256 + threadIdx.x;      // lr*H + h
  if (idx >= n) return;
  const int h = idx % H_;
  const int row = row0 + idx / H_;
  const float* xr = x + (size_t)row * DM;
  const float* wc = W_in + N1 + h;                     // column 3200+h
  float acc = 0.f;
  for (int k = 0; k < DM; ++k) acc += xr[k] * wc[(size_t)k * NPJ];
  dtv[idx] = softplusf(acc + dt_bias[h]);
}

// ---------------- per-chunk inclusive cumsum of dt*A (segment-local) ----------------
__global__ void k_cum(const float* __restrict__ dtv, const float* __restrict__ A_log,
                      float* __restrict__ cumA, int NCseg)
{
  const int idx = blockIdx.x * 256 + threadIdx.x;      // h*NCseg + c
  if (idx >= H_ * NCseg) return;
  const int c = idx % NCseg;
  const int h = idx / NCseg;
  const float A = -expf(A_log[h]);
  float cum = 0.f;
  const int rowbase = c * Q_;
  float* outp = cumA + (size_t)idx * Q_;
  for (int i = 0; i < Q_; ++i) {
    cum += dtv[(size_t)(rowbase + i) * H_ + h] * A;
    outp[i] = cum;
  }
}

// ---------------- intra-chunk quadratic form + chunk state contribution ----------------
__global__ __launch_bounds__(256)
void k_intra(const float* __restrict__ xs, const float* __restrict__ Bm,
             const float* __restrict__ Cm, const float* __restrict__ dtv,
             const float* __restrict__ cumA, float* __restrict__ ytot,
             float* __restrict__ Sbuf, int NCseg)
{
  const int c = blockIdx.x, h = blockIdx.y;
  __shared__ float sx[Q_][SP];
  __shared__ float sB[Q_][SP];
  __shared__ float sC[Q_][SP];
  __shared__ float scum[Q_], sdt[Q_], scoef[Q_];
  const int tid = threadIdx.x;
  const int jr = tid >> 2;               // staging row / i / n
  const int blk = (tid & 3) * 16;        // 16-col slice
  const int rowbase = c * Q_;
  {
    const float* xsrc = xs + (size_t)(rowbase + jr) * DI + h * P_ + blk;
    const float* bsrc = Bm + (size_t)(rowbase + jr) * DS + blk;
    const float* csrc = Cm + (size_t)(rowbase + jr) * DS + blk;
#pragma unroll
    for (int q = 0; q < 4; ++q) {
      *(f32x4*)&sx[jr][blk + q * 4] = *(const f32x4*)(xsrc + q * 4);
      *(f32x4*)&sB[jr][blk + q * 4] = *(const f32x4*)(bsrc + q * 4);
      *(f32x4*)&sC[jr][blk + q * 4] = *(const f32x4*)(csrc + q * 4);
    }
    if (tid < Q_) {
      scum[tid] = cumA[((size_t)(h * NCseg + c)) * Q_ + tid];
      sdt[tid]  = dtv[(size_t)(rowbase + tid) * H_ + h];
    }
  }
  __syncthreads();
  if (tid < Q_) scoef[tid] = expf(scum[Q_ - 1] - scum[tid]) * sdt[tid];

  // phase 2: W[i][j] = (C_i.B_j) exp(cum_i-cum_j) dt_j for j<=i
  const int i = jr;
  f32x4 ci[16];
#pragma unroll
  for (int q = 0; q < 16; ++q) ci[q] = *(const f32x4*)&sC[i][q * 4];
  const float cum_i = scum[i];
  float w[16];
  for (int jj = 0; jj < 16; ++jj) {
    int j = blk + jj;
    float val = 0.f;
    if (j <= i) {
      f32x4 s = {0.f, 0.f, 0.f, 0.f};
#pragma unroll
      for (int q = 0; q < 16; ++q) s += ci[q] * *(const f32x4*)&sB[j][q * 4];
      val = (s[0] + s[1] + s[2] + s[3]) * expf(cum_i - scum[j]) * sdt[j];
    }
    w[jj] = val;
  }
  __syncthreads();
#pragma unroll
  for (int jj = 0; jj < 16; ++jj) sC[i][blk + jj] = w[jj];   // W overwrites sC
  __syncthreads();

  // phase 3: Y_intra = W @ X
  f32x4 y[4];
#pragma unroll
  for (int q = 0; q < 4; ++q) y[q] = (f32x4){0.f, 0.f, 0.f, 0.f};
  for (int j = 0; j < Q_; ++j) {
    float wv = sC[i][j];
#pragma unroll
    for (int q = 0; q < 4; ++q) y[q] += wv * *(const f32x4*)&sx[j][blk + q * 4];
  }
  float* yt = ytot + (size_t)(rowbase + i) * DI + h * P_ + blk;
#pragma unroll
  for (int q = 0; q < 4; ++q) *(f32x4*)(yt + q * 4) = y[q];

  // phase 4: T[n][p] = sum_j exp(cum_last-cum_j) dt_j B[j,n] x[j,p]
  f32x4 s4[4];
#pragma unroll
  for (int q = 0; q < 4; ++q) s4[q] = (f32x4){0.f, 0.f, 0.f, 0.f};
  for (int j = 0; j < Q_; ++j) {
    float bw = scoef[j] * sB[j][i];
#pragma unroll
    for (int q = 0; q < 4; ++q) s4[q] += bw * *(const f32x4*)&sx[j][blk + q * 4];
  }
  float* sp = Sbuf + ((size_t)(h * NCseg + c)) * (DS * P_) + i * P_ + blk;
#pragma unroll
  for (int q = 0; q < 4; ++q) *(f32x4*)(sp + q * 4) = s4[q];
}

// ---------------- sequential inter-chunk recurrence (in-place: T -> S_prev) ----------------
__global__ void k_chunkscan(float* __restrict__ Sbuf, const float* __restrict__ cumA,
                            float* __restrict__ Scarry, int g, int NCseg)
{
  const int seg = blockIdx.x, h = blockIdx.y;
  __shared__ float dec[Q_];
  const int tid = threadIdx.x;
  if (tid < NCseg) dec[tid] = expf(cumA[((size_t)(h * NCseg + tid)) * Q_ + (Q_ - 1)]);
  __syncthreads();
  const size_t off = (size_t)seg * 256 + (size_t)tid * 4;
  float* carry = Scarry + (size_t)h * (DS * P_) + off;
  f32x4 s;
  if (g > 0) s = *(const f32x4*)carry;
  else       s = (f32x4){0.f, 0.f, 0.f, 0.f};
  size_t base = (size_t)h * NCseg * (DS * P_) + off;
  for (int c = 0; c < NCseg; ++c) {
    float* p = Sbuf + base + (size_t)c * (DS * P_);
    f32x4 v = *(const f32x4*)p;
    *(f32x4*)p = s;               // store state BEFORE chunk c
    s = s * dec[c] + v;
  }
  *(f32x4*)carry = s;
}

// ---------------- inter-chunk correction + D*x ----------------
__global__ __launch_bounds__(256)
void k_inter(const float* __restrict__ xs, const float* __restrict__ Cm,
             const float* __restrict__ cumA, const float* __restrict__ Sbuf,
             const float* __restrict__ Dp, float* __restrict__ ytot, int NCseg)
{
  const int c = blockIdx.x, h = blockIdx.y;
  __shared__ float sS[DS][SP];
  __shared__ float sC[Q_][SP];
  __shared__ float scum[Q_];
  const int tid = threadIdx.x;
  const int jr = tid >> 2, blk = (tid & 3) * 16;
  const int rowbase = c * Q_;
  {
    const float* ssrc = Sbuf + ((size_t)(h * NCseg + c)) * (DS * P_) + jr * P_ + blk;
    const float* csrc = Cm + (size_t)(rowbase + jr) * DS + blk;
#pragma unroll
    for (int q = 0; q < 4; ++q) {
      *(f32x4*)&sS[jr][blk + q * 4] = *(const f32x4*)(ssrc + q * 4);
      *(f32x4*)&sC[jr][blk + q * 4] = *(const f32x4*)(csrc + q * 4);
    }
    if (tid < Q_) scum[tid] = cumA[((size_t)(h * NCseg + c)) * Q_ + tid];
  }
  __syncthreads();
  const int i = jr;
  f32x4 acc[4];
#pragma unroll
  for (int q = 0; q < 4; ++q) acc[q] = (f32x4){0.f, 0.f, 0.f, 0.f};
  for (int n = 0; n < DS; ++n) {
    float cv = sC[i][n];
#pragma unroll
    for (int q = 0; q < 4; ++q) acc[q] += cv * *(const f32x4*)&sS[n][blk + q * 4];
  }
  const float e = expf(scum[i]);
  const float Dh = Dp[h];
  float* yt = ytot + (size_t)(rowbase + i) * DI + h * P_ + blk;
  const float* xsr = xs + (size_t)(rowbase + i) * DI + h * P_ + blk;
#pragma unroll
  for (int q = 0; q < 4; ++q) {
    f32x4 cur = *(const f32x4*)(yt + q * 4);
    f32x4 xv  = *(const f32x4*)(xsr + q * 4);
    cur += e * acc[q] + Dh * xv;
    *(f32x4*)(yt + q * 4) = cur;
  }
}

// ---------------- gate (silu(z)) + RMSNorm + cast bf16 ----------------
__global__ __launch_bounds__(192)
void k_rms(const float* __restrict__ z, const float* __restrict__ ytot,
           const float* __restrict__ norm_w, unsigned short* __restrict__ ynorm)
{
  const int row = blockIdx.x, tid = threadIdx.x;
  const int e0 = tid * 8;
  const float* zr = z + (size_t)row * DI;
  const float* yr = ytot + (size_t)row * DI;
  f32x4 zv0 = *(const f32x4*)(zr + e0);
  f32x4 zv1 = *(const f32x4*)(zr + e0 + 4);
  f32x4 yv0 = *(const f32x4*)(yr + e0);
  f32x4 yv1 = *(const f32x4*)(yr + e0 + 4);
  f32x4 g0, g1;
  float ss = 0.f;
#pragma unroll
  for (int q = 0; q < 4; ++q) {
    g0[q] = yv0[q] * siluf(zv0[q]); ss += g0[q] * g0[q];
    g1[q] = yv1[q] * siluf(zv1[q]); ss += g1[q] * g1[q];
  }
#pragma unroll
  for (int off = 32; off > 0; off >>= 1) ss += __shfl_down(ss, off);
  __shared__ float wsum[3];
  __shared__ float sscale;
  if ((tid & 63) == 0) wsum[tid >> 6] = ss;
  __syncthreads();
  if (tid == 0) sscale = rsqrtf((wsum[0] + wsum[1] + wsum[2]) * (1.f / DI) + 1e-5f);
  __syncthreads();
  const float sc = sscale;
  us8 o;
#pragma unroll
  for (int q = 0; q < 4; ++q) {
    o[q]     = f2bf(g0[q] * sc * norm_w[e0 + q]);
    o[q + 4] = f2bf(g1[q] * sc * norm_w[e0 + 4 + q]);
  }
  *(us8*)(ynorm + (size_t)row * DI + e0) = o;
}

extern "C" void kernel_launch(void* const* d_in, const int* in_sizes, int n_in,
                              void* d_out, int out_size, void* d_ws, size_t ws_size,
                              hipStream_t stream)
{
  (void)in_sizes; (void)n_in; (void)out_size;
  const float* x       = (const float*)d_in[0];
  const float* W_in    = (const float*)d_in[1];
  const float* conv_w  = (const float*)d_in[2];
  const float* conv_b  = (const float*)d_in[3];
  const float* dt_bias = (const float*)d_in[4];
  const float* A_log   = (const float*)d_in[5];
  const float* Dp      = (const float*)d_in[6];
  const float* norm_w  = (const float*)d_in[7];
  const float* W_out   = (const float*)d_in[8];
  float* out = (float*)d_out;

  // ---- pick largest segment size that fits ws_size ----
  // footprint(nr) = nr*25792 + 7,744,512 bytes
  int nr = 512;
  {
    const int cands[4] = {4096, 2048, 1024, 512};
    for (int ci = 0; ci < 4; ++ci) {
      size_t need = (size_t)cands[ci] * 25792 + 7744512;
      if (need <= ws_size) { nr = cands[ci]; break; }
    }
  }
  const int G = L_ / nr;          // segments per batch
  const int S = B_ * G;           // total segments
  const int NCseg = nr / Q_;      // chunks per segment

  // ---- workspace layout (per-segment buffers reused across segments) ----
  char* ws = (char*)d_ws;
  float* zseg = (float*)ws;  ws += (size_t)nr * DI * 4;        // z cols (gemm1 -> rms)
  float* xbc  = (float*)ws;  ws += (size_t)nr * CD * 4;        // xBC (gemm1 -> conv); ytot overlays
  float* xs   = (float*)ws;  ws += (size_t)nr * DI * 4;        // conv out (-> inter); ynorm overlays
  float* Bm   = (float*)ws;  ws += (size_t)nr * DS * 4;
  float* Cm   = (float*)ws;  ws += (size_t)nr * DS * 4;
  float* dtv  = (float*)ws;  ws += (size_t)nr * H_ * 4;
  float* cumA = (float*)ws;  ws += (size_t)H_ * nr * 4;
  float* Sbuf = (float*)ws;  ws += (size_t)nr * 6144;          // H_*(nr/64)*4096*4 ; xb overlays
  unsigned short* WinT  = (unsigned short*)ws; ws += (size_t)NPJ * DM * 2;
  unsigned short* WoutT = (unsigned short*)ws; ws += (size_t)DM * DI * 2;
  float* Scarry = (float*)ws;  ws += (size_t)H_ * DS * P_ * 4; // inter-segment scan carry
  float* halo   = (float*)ws;  ws += (size_t)2 * 3 * CD * 4;   // conv halo ping-pong
  float* ytot = xbc;                                 // overlay: xbc dead after conv
  unsigned short* xb    = (unsigned short*)Sbuf;     // overlay: Sbuf dead until k_intra
  unsigned short* ynorm = (unsigned short*)xs;       // overlay: xs dead after k_inter

  k_transpose_cast<<<dim3(24, (NPJ + 31) / 32), 256, 0, stream>>>(W_in, WinT, DM, NPJ);
  k_transpose_cast<<<dim3(48, 24), 256, 0, stream>>>(W_out, WoutT, DI, DM);

  for (int s = 0; s < S; ++s) {
    const int g = s % G;
    const size_t row0 = (size_t)s * nr;

    k_cast<<<nr * DM / 1024, 256, 0, stream>>>(x + row0 * DM, xb, nr * DM);
    k_gemm_split<<<dim3(nr / 128, N1 / 128), 256, 0, stream>>>(
        xb, WinT, zseg, DI, DI, xbc, CD, DM);
    if (G > 1)
      k_halo<<<20, 256, 0, stream>>>(xbc + (size_t)(nr - 3) * CD,
                                     halo + ((g + 1) & 1) * (3 * CD), 3 * CD);
    k_conv<<<dim3(7, nr), 256, 0, stream>>>(xbc, conv_w, conv_b, xs, Bm, Cm,
                                            halo + (g & 1) * (3 * CD), g);
    k_dt<<<nr * H_ / 256, 256, 0, stream>>>(x, W_in, dt_bias, dtv, (int)row0, nr * H_);
    k_cum<<<(H_ * NCseg + 255) / 256, 256, 0, stream>>>(dtv, A_log, cumA, NCseg);
    k_intra<<<dim3(NCseg, H_), 256, 0, stream>>>(xs, Bm, Cm, dtv, cumA, ytot, Sbuf, NCseg);
    k_chunkscan<<<dim3(16, H_), 64, 0, stream>>>(Sbuf, cumA, Scarry, g, NCseg);
    k_inter<<<dim3(NCseg, H_), 256, 0, stream>>>(xs, Cm, cumA, Sbuf, Dp, ytot, NCseg);
    k_rms<<<nr, 192, 0, stream>>>(zseg, ytot, norm_w, ynorm);
    k_gemm_split<<<dim3(nr / 128, DM / 128), 256, 0, stream>>>(
        ynorm, WoutT, out + row0 * DM, DM, DM, out + row0 * DM, DM, DI);
  }
}

// Round 3
// 607.946 us; speedup vs baseline: 1.1260x; 1.1260x over previous
//
#include <hip/hip_runtime.h>

// ---- problem constants ----
#define B_   2
#define L_   4096
#define DM   768
#define DI   1536     // D_INNER
#define DS   64       // D_STATE
#define H_   24       // NHEADS
#define P_   64       // HEADDIM
#define CD   1664     // CONV_DIM
#define NPJ  3224     // D_IN_PROJ
#define N1   3200     // GEMM1 useful cols (z + xBC; dt cols done exactly in k_dt)
#define Q_   64       // chunk length
#define SP   76       // LDS row stride (floats) for k_inter tiles
#define HS   72       // fp16 LDS row stride (halves): 36 words = 4 mod 32 -> <=2-way

typedef short          bf16x8 __attribute__((ext_vector_type(8)));
typedef _Float16       f16x8  __attribute__((ext_vector_type(8)));
typedef unsigned short us8    __attribute__((ext_vector_type(8)));
typedef float          f32x4  __attribute__((ext_vector_type(4)));

__device__ __forceinline__ unsigned short f2bf(float f) {
  unsigned u = __float_as_uint(f);
  u += 0x7fffu + ((u >> 16) & 1u);   // RNE
  return (unsigned short)(u >> 16);
}
__device__ __forceinline__ float siluf(float x) { return x / (1.f + expf(-x)); }
__device__ __forceinline__ float softplusf(float x) { return (x > 20.f) ? x : log1pf(expf(x)); }

// ---------------- transpose + cast (R x C fp32) -> (C x R bf16) ----------------
__global__ __launch_bounds__(256)
void k_transpose_cast(const float* __restrict__ src, unsigned short* __restrict__ dst,
                      int R, int C)
{
  __shared__ float tile[32][33];
  const int tx = threadIdx.x & 31, ty = threadIdx.x >> 5;
  const int r0 = blockIdx.x * 32, c0 = blockIdx.y * 32;
#pragma unroll
  for (int r = 0; r < 4; ++r) {
    int rr = r0 + ty + r * 8, cc = c0 + tx;
    if (rr < R && cc < C) tile[ty + r * 8][tx] = src[(size_t)rr * C + cc];
  }
  __syncthreads();
#pragma unroll
  for (int r = 0; r < 4; ++r) {
    int orow = c0 + ty + r * 8, ocol = r0 + tx;
    if (orow < C && ocol < R) dst[(size_t)orow * R + ocol] = f2bf(tile[tx][ty + r * 8]);
  }
}

// ---------------- bf16 MFMA GEMM, split-column epilogue, optional fp32 A ----------------
// C(MxN) = A(MxK) @ Bt(NxK)^T. M,N multiples of 128.
// cols [0,ncol0) -> C0 (ld0); cols [ncol0,N) -> C1 (ld1).
template <bool A_F32>
__global__ __launch_bounds__(256)
void k_gemm_split(const void* __restrict__ Aptr, const unsigned short* __restrict__ Bt,
                  float* __restrict__ C0, int ld0, int ncol0,
                  float* __restrict__ C1, int ld1, int K)
{
  const int m0 = blockIdx.x * 128, n0 = blockIdx.y * 128;
  __shared__ unsigned short As[128][40];
  __shared__ unsigned short Bs[128][40];
  const int tid  = threadIdx.x;
  const int wave = tid >> 6, lane = tid & 63;
  const int quad = lane >> 4, r16 = lane & 15;
  const int wm = (wave >> 1) * 64, wn = (wave & 1) * 64;
  f32x4 acc[4][4];
#pragma unroll
  for (int a = 0; a < 4; ++a)
#pragma unroll
    for (int bq = 0; bq < 4; ++bq) acc[a][bq] = (f32x4){0.f, 0.f, 0.f, 0.f};

  for (int k0 = 0; k0 < K; k0 += 32) {
#pragma unroll
    for (int it = 0; it < 2; ++it) {
      int chunk = tid + it * 256;           // 512 chunks of 8 elems
      int row = chunk >> 2, c8 = (chunk & 3) * 8;
      us8 va;
      if (A_F32) {
        const float* af = (const float*)Aptr + (size_t)(m0 + row) * K + k0 + c8;
        f32x4 v0 = *(const f32x4*)af, v1 = *(const f32x4*)(af + 4);
#pragma unroll
        for (int e = 0; e < 4; ++e) { va[e] = f2bf(v0[e]); va[e + 4] = f2bf(v1[e]); }
      } else {
        va = *(const us8*)((const unsigned short*)Aptr + (size_t)(m0 + row) * K + k0 + c8);
      }
      *(us8*)&As[row][c8] = va;
      us8 vb = *(const us8*)(Bt + (size_t)(n0 + row) * K + k0 + c8);
      *(us8*)&Bs[row][c8] = vb;
    }
    __syncthreads();
    bf16x8 af[4], bfr[4];
#pragma unroll
    for (int mi = 0; mi < 4; ++mi) af[mi]  = *(const bf16x8*)&As[wm + mi * 16 + r16][quad * 8];
#pragma unroll
    for (int ni = 0; ni < 4; ++ni) bfr[ni] = *(const bf16x8*)&Bs[wn + ni * 16 + r16][quad * 8];
#pragma unroll
    for (int mi = 0; mi < 4; ++mi)
#pragma unroll
      for (int ni = 0; ni < 4; ++ni)
        acc[mi][ni] = __builtin_amdgcn_mfma_f32_16x16x32_bf16(af[mi], bfr[ni], acc[mi][ni], 0, 0, 0);
    __syncthreads();
  }
#pragma unroll
  for (int mi = 0; mi < 4; ++mi)
#pragma unroll
    for (int ni = 0; ni < 4; ++ni) {
      int col = n0 + wn + ni * 16 + r16;
      float* dst; int ld, c;
      if (col < ncol0) { dst = C0; ld = ld0; c = col; }
      else             { dst = C1; ld = ld1; c = col - ncol0; }
#pragma unroll
      for (int r = 0; r < 4; ++r) {
        int row = m0 + wm + mi * 16 + quad * 4 + r;
        dst[(size_t)row * ld + c] = acc[mi][ni][r];
      }
    }
}

// ---------------- depthwise conv(4) + silu, split outputs; fused halo save ----------------
__global__ void k_conv(const float* __restrict__ xbc, const float* __restrict__ cw,
                       const float* __restrict__ cb, float* __restrict__ xs,
                       float* __restrict__ Bm, float* __restrict__ Cm,
                       const float* __restrict__ halo, float* __restrict__ halo_next, int g)
{
  const int ch = blockIdx.x * 256 + threadIdx.x;
  const int lr = blockIdx.y;
  const int nr = gridDim.y;
  if (ch >= CD) return;
  float acc = cb[ch];
  float raw = 0.f;
#pragma unroll
  for (int k = 0; k < 4; ++k) {
    int m = lr - 3 + k;
    float v;
    if (m >= 0)       v = xbc[(size_t)m * CD + ch];
    else if (g > 0)   v = halo[(size_t)(m + 3) * CD + ch];
    else              v = 0.f;
    if (k == 3) raw = v;
    acc += v * cw[ch * 4 + k];
  }
  if (lr >= nr - 3) halo_next[(size_t)(lr - (nr - 3)) * CD + ch] = raw;
  float v = siluf(acc);
  if (ch < DI)           xs[(size_t)lr * DI + ch] = v;
  else if (ch < DI + DS) Bm[(size_t)lr * DS + (ch - DI)] = v;
  else                   Cm[(size_t)lr * DS + (ch - DI - DS)] = v;
}

// ---------------- exact fp32 dt ----------------
__global__ void k_dt(const float* __restrict__ x, const float* __restrict__ W_in,
                     const float* __restrict__ dt_bias, float* __restrict__ dtv,
                     int row0, int n)
{
  const int idx = blockIdx.x * 256 + threadIdx.x;      // lr*H + h
  if (idx >= n) return;
  const int h = idx % H_;
  const int row = row0 + idx / H_;
  const float* xr = x + (size_t)row * DM;
  const float* wc = W_in + N1 + h;
  float acc = 0.f;
  for (int k = 0; k < DM; ++k) acc += xr[k] * wc[(size_t)k * NPJ];
  dtv[idx] = softplusf(acc + dt_bias[h]);
}

// ---------------- per-chunk inclusive cumsum of dt*A ----------------
__global__ void k_cum(const float* __restrict__ dtv, const float* __restrict__ A_log,
                      float* __restrict__ cumA, int NCseg)
{
  const int idx = blockIdx.x * 256 + threadIdx.x;      // h*NCseg + c
  if (idx >= H_ * NCseg) return;
  const int c = idx % NCseg;
  const int h = idx / NCseg;
  const float A = -expf(A_log[h]);
  float cum = 0.f;
  const int rowbase = c * Q_;
  float* outp = cumA + (size_t)idx * Q_;
  for (int i = 0; i < Q_; ++i) {
    cum += dtv[(size_t)(rowbase + i) * H_ + h] * A;
    outp[i] = cum;
  }
}

// ---------------- intra-chunk via fp16 MFMA ----------------
// Per block (c,h): G=C@B^T (masked/decayed -> W), Y=W@X, T=(coef.B)^T@X.
// A/B frag elem [m=lane&15][k=quad*8+j]; C/D elem [row=quad*4+r][col=lane&15].
__global__ __launch_bounds__(256)
void k_intra(const float* __restrict__ xs, const float* __restrict__ Bm,
             const float* __restrict__ Cm, const float* __restrict__ dtv,
             const float* __restrict__ cumA, float* __restrict__ ytot,
             float* __restrict__ Sbuf, int NCseg)
{
  const int c = blockIdx.x, h = blockIdx.y;
  __shared__ _Float16 sCW[Q_][HS];   // C, then W
  __shared__ _Float16 sB [Q_][HS];
  __shared__ _Float16 sBT[Q_][HS];   // (coef_j * B[j][n]) transposed -> [n][j]
  __shared__ _Float16 sXT[Q_][HS];   // X transposed -> [p][j]
  __shared__ float scum[Q_], sdt[Q_];
  const int tid = threadIdx.x;
  const int rowbase = c * Q_;

  // ---- stage ----
  {
    const int j = tid >> 2, s16 = (tid & 3) * 16;
    if (tid < Q_) {
      scum[tid] = cumA[((size_t)(h * NCseg + c)) * Q_ + tid];
      sdt[tid]  = dtv[(size_t)(rowbase + tid) * H_ + h];
    }
    f32x4 xv[4], bv[4], cv[4];
    const float* xsrc = xs + (size_t)(rowbase + j) * DI + h * P_ + s16;
    const float* bsrc = Bm + (size_t)(rowbase + j) * DS + s16;
    const float* csrc = Cm + (size_t)(rowbase + j) * DS + s16;
#pragma unroll
    for (int q = 0; q < 4; ++q) {
      xv[q] = *(const f32x4*)(xsrc + q * 4);
      bv[q] = *(const f32x4*)(bsrc + q * 4);
      cv[q] = *(const f32x4*)(csrc + q * 4);
    }
    __syncthreads();                       // scum/sdt visible
    const float coef = expf(scum[Q_ - 1] - scum[j]) * sdt[j];
    union { f16x8 v; _Float16 e[8]; } pc[2], pb[2];
#pragma unroll
    for (int q = 0; q < 4; ++q)
#pragma unroll
      for (int e = 0; e < 4; ++e) {
        int o = q * 4 + e;
        pc[o >> 3].e[o & 7] = (_Float16)cv[q][e];
        pb[o >> 3].e[o & 7] = (_Float16)bv[q][e];
        sBT[s16 + o][j] = (_Float16)(bv[q][e] * coef);
        sXT[s16 + o][j] = (_Float16)xv[q][e];
      }
    *(f16x8*)&sCW[j][s16]     = pc[0].v;
    *(f16x8*)&sCW[j][s16 + 8] = pc[1].v;
    *(f16x8*)&sB [j][s16]     = pb[0].v;
    *(f16x8*)&sB [j][s16 + 8] = pb[1].v;
  }
  __syncthreads();

  const int wave = tid >> 6, lane = tid & 63;
  const int quad = lane >> 4, r16 = lane & 15;
  const int i0 = wave * 16;
  const int irow = i0 + quad * 4;

  // ---- G = C @ B^T (skip fully-masked tiles ni>wave) ----
  f32x4 g[4];
#pragma unroll
  for (int q = 0; q < 4; ++q) g[q] = (f32x4){0.f, 0.f, 0.f, 0.f};
#pragma unroll
  for (int ni = 0; ni < 4; ++ni) {
    if (ni <= wave) {
#pragma unroll
      for (int ks = 0; ks < 2; ++ks)
        g[ni] = __builtin_amdgcn_mfma_f32_16x16x32_f16(
            *(const f16x8*)&sCW[i0 + r16][ks * 32 + quad * 8],
            *(const f16x8*)&sB [ni * 16 + r16][ks * 32 + quad * 8], g[ni], 0, 0, 0);
    }
  }
  // ---- decay + mask -> W ----
  float wv[4][4];
#pragma unroll
  for (int ni = 0; ni < 4; ++ni)
#pragma unroll
    for (int r = 0; r < 4; ++r) {
      int i = irow + r, jcol = ni * 16 + r16;
      float v = 0.f;
      if (ni <= wave && jcol <= i)
        v = g[ni][r] * expf(scum[i] - scum[jcol]) * sdt[jcol];
      wv[ni][r] = v;
    }
  __syncthreads();                         // all reads of sCW(C) done
#pragma unroll
  for (int ni = 0; ni < 4; ++ni)
#pragma unroll
    for (int r = 0; r < 4; ++r)
      sCW[irow + r][ni * 16 + r16] = (_Float16)wv[ni][r];
  __syncthreads();

  // ---- Y = W @ X (waves 0/1: K<=32 -> single k-step) ----
  f32x4 y[4];
#pragma unroll
  for (int q = 0; q < 4; ++q) y[q] = (f32x4){0.f, 0.f, 0.f, 0.f};
#pragma unroll
  for (int ni = 0; ni < 4; ++ni)
#pragma unroll
    for (int ks = 0; ks < 2; ++ks) {
      if (ks == 0 || wave >= 2)
        y[ni] = __builtin_amdgcn_mfma_f32_16x16x32_f16(
            *(const f16x8*)&sCW[i0 + r16][ks * 32 + quad * 8],
            *(const f16x8*)&sXT[ni * 16 + r16][ks * 32 + quad * 8], y[ni], 0, 0, 0);
    }
#pragma unroll
  for (int ni = 0; ni < 4; ++ni)
#pragma unroll
    for (int r = 0; r < 4; ++r)
      ytot[(size_t)(rowbase + irow + r) * DI + h * P_ + ni * 16 + r16] = y[ni][r];

  // ---- T = (coef.B)^T @ X ----
  f32x4 t4[4];
#pragma unroll
  for (int q = 0; q < 4; ++q) t4[q] = (f32x4){0.f, 0.f, 0.f, 0.f};
#pragma unroll
  for (int ni = 0; ni < 4; ++ni)
#pragma unroll
    for (int ks = 0; ks < 2; ++ks)
      t4[ni] = __builtin_amdgcn_mfma_f32_16x16x32_f16(
          *(const f16x8*)&sBT[i0 + r16][ks * 32 + quad * 8],
          *(const f16x8*)&sXT[ni * 16 + r16][ks * 32 + quad * 8], t4[ni], 0, 0, 0);
  float* sp = Sbuf + ((size_t)(h * NCseg + c)) * (DS * P_);
#pragma unroll
  for (int ni = 0; ni < 4; ++ni)
#pragma unroll
    for (int r = 0; r < 4; ++r)
      sp[(irow + r) * P_ + ni * 16 + r16] = t4[ni][r];
}

// ---------------- sequential inter-chunk recurrence (in-place: T -> S_prev) ----------------
__global__ void k_chunkscan(float* __restrict__ Sbuf, const float* __restrict__ cumA,
                            float* __restrict__ Scarry, int g, int NCseg)
{
  const int seg = blockIdx.x, h = blockIdx.y;
  __shared__ float dec[Q_];
  const int tid = threadIdx.x;
  if (tid < NCseg) dec[tid] = expf(cumA[((size_t)(h * NCseg + tid)) * Q_ + (Q_ - 1)]);
  __syncthreads();
  const size_t off = (size_t)seg * 256 + (size_t)tid * 4;
  float* carry = Scarry + (size_t)h * (DS * P_) + off;
  f32x4 s;
  if (g > 0) s = *(const f32x4*)carry;
  else       s = (f32x4){0.f, 0.f, 0.f, 0.f};
  size_t base = (size_t)h * NCseg * (DS * P_) + off;
  for (int c = 0; c < NCseg; ++c) {
    float* p = Sbuf + base + (size_t)c * (DS * P_);
    f32x4 v = *(const f32x4*)p;
    *(f32x4*)p = s;               // store state BEFORE chunk c
    s = s * dec[c] + v;
  }
  *(f32x4*)carry = s;
}

// ---------------- inter-chunk correction + D*x ----------------
__global__ __launch_bounds__(256)
void k_inter(const float* __restrict__ xs, const float* __restrict__ Cm,
             const float* __restrict__ cumA, const float* __restrict__ Sbuf,
             const float* __restrict__ Dp, float* __restrict__ ytot, int NCseg)
{
  const int c = blockIdx.x, h = blockIdx.y;
  __shared__ float sS[DS][SP];
  __shared__ float sC[Q_][SP];
  __shared__ float scum[Q_];
  const int tid = threadIdx.x;
  const int jr = tid >> 2, blk = (tid & 3) * 16;
  const int rowbase = c * Q_;
  {
    const float* ssrc = Sbuf + ((size_t)(h * NCseg + c)) * (DS * P_) + jr * P_ + blk;
    const float* csrc = Cm + (size_t)(rowbase + jr) * DS + blk;
#pragma unroll
    for (int q = 0; q < 4; ++q) {
      *(f32x4*)&sS[jr][blk + q * 4] = *(const f32x4*)(ssrc + q * 4);
      *(f32x4*)&sC[jr][blk + q * 4] = *(const f32x4*)(csrc + q * 4);
    }
    if (tid < Q_) scum[tid] = cumA[((size_t)(h * NCseg + c)) * Q_ + tid];
  }
  __syncthreads();
  const int i = jr;
  f32x4 acc[4];
#pragma unroll
  for (int q = 0; q < 4; ++q) acc[q] = (f32x4){0.f, 0.f, 0.f, 0.f};
  for (int n = 0; n < DS; ++n) {
    float cv = sC[i][n];
#pragma unroll
    for (int q = 0; q < 4; ++q) acc[q] += cv * *(const f32x4*)&sS[n][blk + q * 4];
  }
  const float e = expf(scum[i]);
  const float Dh = Dp[h];
  float* yt = ytot + (size_t)(rowbase + i) * DI + h * P_ + blk;
  const float* xsr = xs + (size_t)(rowbase + i) * DI + h * P_ + blk;
#pragma unroll
  for (int q = 0; q < 4; ++q) {
    f32x4 cur = *(const f32x4*)(yt + q * 4);
    f32x4 xv  = *(const f32x4*)(xsr + q * 4);
    cur += e * acc[q] + Dh * xv;
    *(f32x4*)(yt + q * 4) = cur;
  }
}

// ---------------- gate (silu(z)) + RMSNorm + cast bf16 ----------------
__global__ __launch_bounds__(192)
void k_rms(const float* __restrict__ z, const float* __restrict__ ytot,
           const float* __restrict__ norm_w, unsigned short* __restrict__ ynorm)
{
  const int row = blockIdx.x, tid = threadIdx.x;
  const int e0 = tid * 8;
  const float* zr = z + (size_t)row * DI;
  const float* yr = ytot + (size_t)row * DI;
  f32x4 zv0 = *(const f32x4*)(zr + e0);
  f32x4 zv1 = *(const f32x4*)(zr + e0 + 4);
  f32x4 yv0 = *(const f32x4*)(yr + e0);
  f32x4 yv1 = *(const f32x4*)(yr + e0 + 4);
  f32x4 g0, g1;
  float ss = 0.f;
#pragma unroll
  for (int q = 0; q < 4; ++q) {
    g0[q] = yv0[q] * siluf(zv0[q]); ss += g0[q] * g0[q];
    g1[q] = yv1[q] * siluf(zv1[q]); ss += g1[q] * g1[q];
  }
#pragma unroll
  for (int off = 32; off > 0; off >>= 1) ss += __shfl_down(ss, off);
  __shared__ float wsum[3];
  __shared__ float sscale;
  if ((tid & 63) == 0) wsum[tid >> 6] = ss;
  __syncthreads();
  if (tid == 0) sscale = rsqrtf((wsum[0] + wsum[1] + wsum[2]) * (1.f / DI) + 1e-5f);
  __syncthreads();
  const float sc = sscale;
  us8 o;
#pragma unroll
  for (int q = 0; q < 4; ++q) {
    o[q]     = f2bf(g0[q] * sc * norm_w[e0 + q]);
    o[q + 4] = f2bf(g1[q] * sc * norm_w[e0 + 4 + q]);
  }
  *(us8*)(ynorm + (size_t)row * DI + e0) = o;
}

extern "C" void kernel_launch(void* const* d_in, const int* in_sizes, int n_in,
                              void* d_out, int out_size, void* d_ws, size_t ws_size,
                              hipStream_t stream)
{
  (void)in_sizes; (void)n_in; (void)out_size;
  const float* x       = (const float*)d_in[0];
  const float* W_in    = (const float*)d_in[1];
  const float* conv_w  = (const float*)d_in[2];
  const float* conv_b  = (const float*)d_in[3];
  const float* dt_bias = (const float*)d_in[4];
  const float* A_log   = (const float*)d_in[5];
  const float* Dp      = (const float*)d_in[6];
  const float* norm_w  = (const float*)d_in[7];
  const float* W_out   = (const float*)d_in[8];
  float* out = (float*)d_out;

  // ---- pick largest segment size that fits ws_size ----
  int nr = 512;
  {
    const int cands[4] = {4096, 2048, 1024, 512};
    for (int ci = 0; ci < 4; ++ci) {
      size_t need = (size_t)cands[ci] * 25792 + 7744512;
      if (need <= ws_size) { nr = cands[ci]; break; }
    }
  }
  const int G = L_ / nr;          // segments per batch
  const int S = B_ * G;           // total segments
  const int NCseg = nr / Q_;      // chunks per segment

  // ---- workspace layout ----
  char* ws = (char*)d_ws;
  float* zseg = (float*)ws;  ws += (size_t)nr * DI * 4;
  float* xbc  = (float*)ws;  ws += (size_t)nr * CD * 4;
  float* xs   = (float*)ws;  ws += (size_t)nr * DI * 4;
  float* Bm   = (float*)ws;  ws += (size_t)nr * DS * 4;
  float* Cm   = (float*)ws;  ws += (size_t)nr * DS * 4;
  float* dtv  = (float*)ws;  ws += (size_t)nr * H_ * 4;
  float* cumA = (float*)ws;  ws += (size_t)H_ * nr * 4;
  float* Sbuf = (float*)ws;  ws += (size_t)nr * 6144;
  unsigned short* WinT  = (unsigned short*)ws; ws += (size_t)NPJ * DM * 2;
  unsigned short* WoutT = (unsigned short*)ws; ws += (size_t)DM * DI * 2;
  float* Scarry = (float*)ws;  ws += (size_t)H_ * DS * P_ * 4;
  float* halo   = (float*)ws;  ws += (size_t)2 * 3 * CD * 4;
  float* ytot = xbc;                                 // overlay: xbc dead after conv
  unsigned short* ynorm = (unsigned short*)xs;       // overlay: xs dead after k_inter

  k_transpose_cast<<<dim3(24, (NPJ + 31) / 32), 256, 0, stream>>>(W_in, WinT, DM, NPJ);
  k_transpose_cast<<<dim3(48, 24), 256, 0, stream>>>(W_out, WoutT, DI, DM);

  for (int s = 0; s < S; ++s) {
    const int g = s % G;
    const size_t row0 = (size_t)s * nr;

    k_gemm_split<true><<<dim3(nr / 128, N1 / 128), 256, 0, stream>>>(
        x + row0 * DM, WinT, zseg, DI, DI, xbc, CD, DM);
    k_conv<<<dim3(7, nr), 256, 0, stream>>>(xbc, conv_w, conv_b, xs, Bm, Cm,
                                            halo + (g & 1) * (3 * CD),
                                            halo + ((g + 1) & 1) * (3 * CD), g);
    k_dt<<<nr * H_ / 256, 256, 0, stream>>>(x, W_in, dt_bias, dtv, (int)row0, nr * H_);
    k_cum<<<(H_ * NCseg + 255) / 256, 256, 0, stream>>>(dtv, A_log, cumA, NCseg);
    k_intra<<<dim3(NCseg, H_), 256, 0, stream>>>(xs, Bm, Cm, dtv, cumA, ytot, Sbuf, NCseg);
    k_chunkscan<<<dim3(16, H_), 64, 0, stream>>>(Sbuf, cumA, Scarry, g, NCseg);
    k_inter<<<dim3(NCseg, H_), 256, 0, stream>>>(xs, Cm, cumA, Sbuf, Dp, ytot, NCseg);
    k_rms<<<nr, 192, 0, stream>>>(zseg, ytot, norm_w, ynorm);
    k_gemm_split<false><<<dim3(nr / 128, DM / 128), 256, 0, stream>>>(
        ynorm, WoutT, out + row0 * DM, DM, DM, out + row0 * DM, DM, DI);
  }
}

// Round 4
// 581.825 us; speedup vs baseline: 1.1765x; 1.0449x over previous
//
#include <hip/hip_runtime.h>

// ---- problem constants ----
#define B_   2
#define L_   4096
#define DM   768
#define DI   1536     // D_INNER
#define DS   64       // D_STATE
#define H_   24       // NHEADS
#define P_   64       // HEADDIM
#define CD   1664     // CONV_DIM
#define NPJ  3224     // D_IN_PROJ
#define N1   3200     // GEMM1 useful cols (z + xBC; dt cols done exactly in k_dt)
#define Q_   64       // chunk length
#define SP   76       // LDS row stride (floats) for k_inter tiles
#define HS   72       // fp16 LDS row stride (halves): <=2-way conflicts

typedef short          bf16x8 __attribute__((ext_vector_type(8)));
typedef _Float16       f16x8  __attribute__((ext_vector_type(8)));
typedef unsigned short us8    __attribute__((ext_vector_type(8)));
typedef unsigned short us4    __attribute__((ext_vector_type(4)));
typedef float          f32x4  __attribute__((ext_vector_type(4)));

__device__ __forceinline__ unsigned short f2bf(float f) {
  unsigned u = __float_as_uint(f);
  u += 0x7fffu + ((u >> 16) & 1u);   // RNE
  return (unsigned short)(u >> 16);
}
__device__ __forceinline__ float siluf(float x) { return x / (1.f + expf(-x)); }
__device__ __forceinline__ float softplusf(float x) { return (x > 20.f) ? x : log1pf(expf(x)); }

// async global->LDS, 16B per lane; LDS dest = uniform base + lane*16
__device__ __forceinline__ void gload16(const unsigned short* g, unsigned short* l) {
  __builtin_amdgcn_global_load_lds(
      (const __attribute__((address_space(1))) void*)g,
      (__attribute__((address_space(3))) void*)l, 16, 0, 0);
}

// ---------------- cast fp32 -> bf16 ----------------
__global__ void k_cast(const float* __restrict__ src, unsigned short* __restrict__ dst, int n)
{
  const int i = (blockIdx.x * 256 + threadIdx.x) * 4;
  if (i >= n) return;
  f32x4 v = *(const f32x4*)(src + i);
  us4 o;
#pragma unroll
  for (int q = 0; q < 4; ++q) o[q] = f2bf(v[q]);
  *(us4*)(dst + i) = o;
}

// ---------------- transpose + cast (R x C fp32) -> (C x R bf16) ----------------
__global__ __launch_bounds__(256)
void k_transpose_cast(const float* __restrict__ src, unsigned short* __restrict__ dst,
                      int R, int C)
{
  __shared__ float tile[32][33];
  const int tx = threadIdx.x & 31, ty = threadIdx.x >> 5;
  const int r0 = blockIdx.x * 32, c0 = blockIdx.y * 32;
#pragma unroll
  for (int r = 0; r < 4; ++r) {
    int rr = r0 + ty + r * 8, cc = c0 + tx;
    if (rr < R && cc < C) tile[ty + r * 8][tx] = src[(size_t)rr * C + cc];
  }
  __syncthreads();
#pragma unroll
  for (int r = 0; r < 4; ++r) {
    int orow = c0 + ty + r * 8, ocol = r0 + tx;
    if (orow < C && ocol < R) dst[(size_t)orow * R + ocol] = f2bf(tile[tx][ty + r * 8]);
  }
}

// ---------------- bf16 MFMA GEMM (m97-style global_load_lds staging) ----------------
// C(MxN) = A(MxK) @ Bt(NxK)^T. M,N multiples of 128; K multiple of 32.
// cols [0,ncol0) -> C0 (ld0); cols [ncol0,N) -> C1 (ld1).
__global__ __launch_bounds__(256)
void k_gemm(const unsigned short* __restrict__ A, const unsigned short* __restrict__ Bt,
            float* __restrict__ C0, int ld0, int ncol0,
            float* __restrict__ C1, int ld1, int K)
{
  const int m0 = blockIdx.x * 128, n0 = blockIdx.y * 128;
  __shared__ unsigned short As[128][32];   // UNPADDED: global_load_lds lane-contiguous
  __shared__ unsigned short Bs[128][32];
  const int tid  = threadIdx.x;
  const int wave = tid >> 6, lane = tid & 63;
  const int quad = lane >> 4, r16 = lane & 15;
  const int wm = (wave >> 1) * 64, wn = (wave & 1) * 64;

  // staging addresses: wave w covers rows [w*32, w*32+32), lane -> row w*32+t*16+(lane>>2), kchunk lane&3
  const int wr = wave * 32;
  const int lrow = lane >> 2, lk8 = (lane & 3) * 8;
  const unsigned short* gA0 = A  + (size_t)(m0 + wr + lrow) * K + lk8;
  const unsigned short* gB0 = Bt + (size_t)(n0 + wr + lrow) * K + lk8;
  unsigned short* lA0 = &As[wr][0];
  unsigned short* lA1 = &As[wr + 16][0];
  unsigned short* lB0 = &Bs[wr][0];
  unsigned short* lB1 = &Bs[wr + 16][0];
  const size_t rstep = (size_t)16 * K;

  f32x4 acc[4][4];
#pragma unroll
  for (int a = 0; a < 4; ++a)
#pragma unroll
    for (int bq = 0; bq < 4; ++bq) acc[a][bq] = (f32x4){0.f, 0.f, 0.f, 0.f};

  for (int k0 = 0; k0 < K; k0 += 32) {
    gload16(gA0 + k0,         lA0);
    gload16(gA0 + k0 + rstep, lA1);
    gload16(gB0 + k0,         lB0);
    gload16(gB0 + k0 + rstep, lB1);
    __syncthreads();
    bf16x8 af[4], bfr[4];
#pragma unroll
    for (int mi = 0; mi < 4; ++mi) af[mi]  = *(const bf16x8*)&As[wm + mi * 16 + r16][quad * 8];
#pragma unroll
    for (int ni = 0; ni < 4; ++ni) bfr[ni] = *(const bf16x8*)&Bs[wn + ni * 16 + r16][quad * 8];
#pragma unroll
    for (int mi = 0; mi < 4; ++mi)
#pragma unroll
      for (int ni = 0; ni < 4; ++ni)
        acc[mi][ni] = __builtin_amdgcn_mfma_f32_16x16x32_bf16(af[mi], bfr[ni], acc[mi][ni], 0, 0, 0);
    __syncthreads();
  }
#pragma unroll
  for (int mi = 0; mi < 4; ++mi)
#pragma unroll
    for (int ni = 0; ni < 4; ++ni) {
      int col = n0 + wn + ni * 16 + r16;
      float* dst; int ld, c;
      if (col < ncol0) { dst = C0; ld = ld0; c = col; }
      else             { dst = C1; ld = ld1; c = col - ncol0; }
#pragma unroll
      for (int r = 0; r < 4; ++r) {
        int row = m0 + wm + mi * 16 + quad * 4 + r;
        dst[(size_t)row * ld + c] = acc[mi][ni][r];
      }
    }
}

// ---------------- depthwise conv(4) + silu, split outputs; fused halo save ----------------
__global__ void k_conv(const float* __restrict__ xbc, const float* __restrict__ cw,
                       const float* __restrict__ cb, float* __restrict__ xs,
                       float* __restrict__ Bm, float* __restrict__ Cm,
                       const float* __restrict__ halo, float* __restrict__ halo_next, int g)
{
  const int ch = blockIdx.x * 256 + threadIdx.x;
  const int lr = blockIdx.y;
  const int nr = gridDim.y;
  if (ch >= CD) return;
  float acc = cb[ch];
  float raw = 0.f;
#pragma unroll
  for (int k = 0; k < 4; ++k) {
    int m = lr - 3 + k;
    float v;
    if (m >= 0)       v = xbc[(size_t)m * CD + ch];
    else if (g > 0)   v = halo[(size_t)(m + 3) * CD + ch];
    else              v = 0.f;
    if (k == 3) raw = v;
    acc += v * cw[ch * 4 + k];
  }
  if (lr >= nr - 3) halo_next[(size_t)(lr - (nr - 3)) * CD + ch] = raw;
  float v = siluf(acc);
  if (ch < DI)           xs[(size_t)lr * DI + ch] = v;
  else if (ch < DI + DS) Bm[(size_t)lr * DS + (ch - DI)] = v;
  else                   Cm[(size_t)lr * DS + (ch - DI - DS)] = v;
}

// ---------------- exact fp32 dt ----------------
__global__ void k_dt(const float* __restrict__ x, const float* __restrict__ W_in,
                     const float* __restrict__ dt_bias, float* __restrict__ dtv,
                     int row0, int n)
{
  const int idx = blockIdx.x * 256 + threadIdx.x;      // lr*H + h
  if (idx >= n) return;
  const int h = idx % H_;
  const int row = row0 + idx / H_;
  const float* xr = x + (size_t)row * DM;
  const float* wc = W_in + N1 + h;
  float acc = 0.f;
  for (int k = 0; k < DM; ++k) acc += xr[k] * wc[(size_t)k * NPJ];
  dtv[idx] = softplusf(acc + dt_bias[h]);
}

// ---------------- per-chunk inclusive cumsum of dt*A ----------------
__global__ void k_cum(const float* __restrict__ dtv, const float* __restrict__ A_log,
                      float* __restrict__ cumA, int NCseg)
{
  const int idx = blockIdx.x * 256 + threadIdx.x;      // h*NCseg + c
  if (idx >= H_ * NCseg) return;
  const int c = idx % NCseg;
  const int h = idx / NCseg;
  const float A = -expf(A_log[h]);
  float cum = 0.f;
  const int rowbase = c * Q_;
  float* outp = cumA + (size_t)idx * Q_;
  for (int i = 0; i < Q_; ++i) {
    cum += dtv[(size_t)(rowbase + i) * H_ + h] * A;
    outp[i] = cum;
  }
}

// ---------------- intra-chunk via fp16 MFMA ----------------
// Per block (c,h): G=C@B^T (masked/decayed -> W), Y=W@X, T=(coef.B)^T@X.
// A/B frag elem [m=lane&15][k=quad*8+j]; C/D elem [row=quad*4+r][col=lane&15].
__global__ __launch_bounds__(256)
void k_intra(const float* __restrict__ xs, const float* __restrict__ Bm,
             const float* __restrict__ Cm, const float* __restrict__ dtv,
             const float* __restrict__ cumA, float* __restrict__ ytot,
             float* __restrict__ Sbuf, int NCseg)
{
  const int c = blockIdx.x, h = blockIdx.y;
  __shared__ _Float16 sCW[Q_][HS];   // C, then W
  __shared__ _Float16 sB [Q_][HS];
  __shared__ _Float16 sBT[Q_][HS];   // (coef_j * B[j][n]) transposed -> [n][j]
  __shared__ _Float16 sXT[Q_][HS];   // X transposed -> [p][j]
  __shared__ float scum[Q_], sdt[Q_];
  const int tid = threadIdx.x;
  const int rowbase = c * Q_;

  // ---- stage ----
  {
    const int j = tid >> 2, s16 = (tid & 3) * 16;
    if (tid < Q_) {
      scum[tid] = cumA[((size_t)(h * NCseg + c)) * Q_ + tid];
      sdt[tid]  = dtv[(size_t)(rowbase + tid) * H_ + h];
    }
    f32x4 xv[4], bv[4], cv[4];
    const float* xsrc = xs + (size_t)(rowbase + j) * DI + h * P_ + s16;
    const float* bsrc = Bm + (size_t)(rowbase + j) * DS + s16;
    const float* csrc = Cm + (size_t)(rowbase + j) * DS + s16;
#pragma unroll
    for (int q = 0; q < 4; ++q) {
      xv[q] = *(const f32x4*)(xsrc + q * 4);
      bv[q] = *(const f32x4*)(bsrc + q * 4);
      cv[q] = *(const f32x4*)(csrc + q * 4);
    }
    __syncthreads();                       // scum/sdt visible
    const float coef = expf(scum[Q_ - 1] - scum[j]) * sdt[j];
    union { f16x8 v; _Float16 e[8]; } pc[2], pb[2];
#pragma unroll
    for (int q = 0; q < 4; ++q)
#pragma unroll
      for (int e = 0; e < 4; ++e) {
        int o = q * 4 + e;
        pc[o >> 3].e[o & 7] = (_Float16)cv[q][e];
        pb[o >> 3].e[o & 7] = (_Float16)bv[q][e];
        sBT[s16 + o][j] = (_Float16)(bv[q][e] * coef);
        sXT[s16 + o][j] = (_Float16)xv[q][e];
      }
    *(f16x8*)&sCW[j][s16]     = pc[0].v;
    *(f16x8*)&sCW[j][s16 + 8] = pc[1].v;
    *(f16x8*)&sB [j][s16]     = pb[0].v;
    *(f16x8*)&sB [j][s16 + 8] = pb[1].v;
  }
  __syncthreads();

  const int wave = tid >> 6, lane = tid & 63;
  const int quad = lane >> 4, r16 = lane & 15;
  const int i0 = wave * 16;
  const int irow = i0 + quad * 4;

  // ---- G = C @ B^T (skip fully-masked tiles ni>wave) ----
  f32x4 g[4];
#pragma unroll
  for (int q = 0; q < 4; ++q) g[q] = (f32x4){0.f, 0.f, 0.f, 0.f};
#pragma unroll
  for (int ni = 0; ni < 4; ++ni) {
    if (ni <= wave) {
#pragma unroll
      for (int ks = 0; ks < 2; ++ks)
        g[ni] = __builtin_amdgcn_mfma_f32_16x16x32_f16(
            *(const f16x8*)&sCW[i0 + r16][ks * 32 + quad * 8],
            *(const f16x8*)&sB [ni * 16 + r16][ks * 32 + quad * 8], g[ni], 0, 0, 0);
    }
  }
  // ---- decay + mask -> W ----
  float wv[4][4];
#pragma unroll
  for (int ni = 0; ni < 4; ++ni)
#pragma unroll
    for (int r = 0; r < 4; ++r) {
      int i = irow + r, jcol = ni * 16 + r16;
      float v = 0.f;
      if (ni <= wave && jcol <= i)
        v = g[ni][r] * expf(scum[i] - scum[jcol]) * sdt[jcol];
      wv[ni][r] = v;
    }
  __syncthreads();                         // all reads of sCW(C) done
#pragma unroll
  for (int ni = 0; ni < 4; ++ni)
#pragma unroll
    for (int r = 0; r < 4; ++r)
      sCW[irow + r][ni * 16 + r16] = (_Float16)wv[ni][r];
  __syncthreads();

  // ---- Y = W @ X (waves 0/1: K<=32 -> single k-step) ----
  f32x4 y[4];
#pragma unroll
  for (int q = 0; q < 4; ++q) y[q] = (f32x4){0.f, 0.f, 0.f, 0.f};
#pragma unroll
  for (int ni = 0; ni < 4; ++ni)
#pragma unroll
    for (int ks = 0; ks < 2; ++ks) {
      if (ks == 0 || wave >= 2)
        y[ni] = __builtin_amdgcn_mfma_f32_16x16x32_f16(
            *(const f16x8*)&sCW[i0 + r16][ks * 32 + quad * 8],
            *(const f16x8*)&sXT[ni * 16 + r16][ks * 32 + quad * 8], y[ni], 0, 0, 0);
    }
#pragma unroll
  for (int ni = 0; ni < 4; ++ni)
#pragma unroll
    for (int r = 0; r < 4; ++r)
      ytot[(size_t)(rowbase + irow + r) * DI + h * P_ + ni * 16 + r16] = y[ni][r];

  // ---- T = (coef.B)^T @ X ----
  f32x4 t4[4];
#pragma unroll
  for (int q = 0; q < 4; ++q) t4[q] = (f32x4){0.f, 0.f, 0.f, 0.f};
#pragma unroll
  for (int ni = 0; ni < 4; ++ni)
#pragma unroll
    for (int ks = 0; ks < 2; ++ks)
      t4[ni] = __builtin_amdgcn_mfma_f32_16x16x32_f16(
          *(const f16x8*)&sBT[i0 + r16][ks * 32 + quad * 8],
          *(const f16x8*)&sXT[ni * 16 + r16][ks * 32 + quad * 8], t4[ni], 0, 0, 0);
  float* sp = Sbuf + ((size_t)(h * NCseg + c)) * (DS * P_);
#pragma unroll
  for (int ni = 0; ni < 4; ++ni)
#pragma unroll
    for (int r = 0; r < 4; ++r)
      sp[(irow + r) * P_ + ni * 16 + r16] = t4[ni][r];
}

// ---------------- sequential inter-chunk recurrence (in-place: T -> S_prev) ----------------
__global__ void k_chunkscan(float* __restrict__ Sbuf, const float* __restrict__ cumA,
                            float* __restrict__ Scarry, int g, int NCseg)
{
  const int seg = blockIdx.x, h = blockIdx.y;
  __shared__ float dec[Q_];
  const int tid = threadIdx.x;
  if (tid < NCseg) dec[tid] = expf(cumA[((size_t)(h * NCseg + tid)) * Q_ + (Q_ - 1)]);
  __syncthreads();
  const size_t off = (size_t)seg * 256 + (size_t)tid * 4;
  float* carry = Scarry + (size_t)h * (DS * P_) + off;
  f32x4 s;
  if (g > 0) s = *(const f32x4*)carry;
  else       s = (f32x4){0.f, 0.f, 0.f, 0.f};
  size_t base = (size_t)h * NCseg * (DS * P_) + off;
  for (int c = 0; c < NCseg; ++c) {
    float* p = Sbuf + base + (size_t)c * (DS * P_);
    f32x4 v = *(const f32x4*)p;
    *(f32x4*)p = s;               // store state BEFORE chunk c
    s = s * dec[c] + v;
  }
  *(f32x4*)carry = s;
}

// ---------------- inter-chunk correction + D*x ----------------
__global__ __launch_bounds__(256)
void k_inter(const float* __restrict__ xs, const float* __restrict__ Cm,
             const float* __restrict__ cumA, const float* __restrict__ Sbuf,
             const float* __restrict__ Dp, float* __restrict__ ytot, int NCseg)
{
  const int c = blockIdx.x, h = blockIdx.y;
  __shared__ float sS[DS][SP];
  __shared__ float sC[Q_][SP];
  __shared__ float scum[Q_];
  const int tid = threadIdx.x;
  const int jr = tid >> 2, blk = (tid & 3) * 16;
  const int rowbase = c * Q_;
  {
    const float* ssrc = Sbuf + ((size_t)(h * NCseg + c)) * (DS * P_) + jr * P_ + blk;
    const float* csrc = Cm + (size_t)(rowbase + jr) * DS + blk;
#pragma unroll
    for (int q = 0; q < 4; ++q) {
      *(f32x4*)&sS[jr][blk + q * 4] = *(const f32x4*)(ssrc + q * 4);
      *(f32x4*)&sC[jr][blk + q * 4] = *(const f32x4*)(csrc + q * 4);
    }
    if (tid < Q_) scum[tid] = cumA[((size_t)(h * NCseg + c)) * Q_ + tid];
  }
  __syncthreads();
  const int i = jr;
  f32x4 acc[4];
#pragma unroll
  for (int q = 0; q < 4; ++q) acc[q] = (f32x4){0.f, 0.f, 0.f, 0.f};
  for (int n = 0; n < DS; ++n) {
    float cv = sC[i][n];
#pragma unroll
    for (int q = 0; q < 4; ++q) acc[q] += cv * *(const f32x4*)&sS[n][blk + q * 4];
  }
  const float e = expf(scum[i]);
  const float Dh = Dp[h];
  float* yt = ytot + (size_t)(rowbase + i) * DI + h * P_ + blk;
  const float* xsr = xs + (size_t)(rowbase + i) * DI + h * P_ + blk;
#pragma unroll
  for (int q = 0; q < 4; ++q) {
    f32x4 cur = *(const f32x4*)(yt + q * 4);
    f32x4 xv  = *(const f32x4*)(xsr + q * 4);
    cur += e * acc[q] + Dh * xv;
    *(f32x4*)(yt + q * 4) = cur;
  }
}

// ---------------- gate (silu(z)) + RMSNorm + cast bf16 ----------------
__global__ __launch_bounds__(192)
void k_rms(const float* __restrict__ z, const float* __restrict__ ytot,
           const float* __restrict__ norm_w, unsigned short* __restrict__ ynorm)
{
  const int row = blockIdx.x, tid = threadIdx.x;
  const int e0 = tid * 8;
  const float* zr = z + (size_t)row * DI;
  const float* yr = ytot + (size_t)row * DI;
  f32x4 zv0 = *(const f32x4*)(zr + e0);
  f32x4 zv1 = *(const f32x4*)(zr + e0 + 4);
  f32x4 yv0 = *(const f32x4*)(yr + e0);
  f32x4 yv1 = *(const f32x4*)(yr + e0 + 4);
  f32x4 g0, g1;
  float ss = 0.f;
#pragma unroll
  for (int q = 0; q < 4; ++q) {
    g0[q] = yv0[q] * siluf(zv0[q]); ss += g0[q] * g0[q];
    g1[q] = yv1[q] * siluf(zv1[q]); ss += g1[q] * g1[q];
  }
#pragma unroll
  for (int off = 32; off > 0; off >>= 1) ss += __shfl_down(ss, off);
  __shared__ float wsum[3];
  __shared__ float sscale;
  if ((tid & 63) == 0) wsum[tid >> 6] = ss;
  __syncthreads();
  if (tid == 0) sscale = rsqrtf((wsum[0] + wsum[1] + wsum[2]) * (1.f / DI) + 1e-5f);
  __syncthreads();
  const float sc = sscale;
  us8 o;
#pragma unroll
  for (int q = 0; q < 4; ++q) {
    o[q]     = f2bf(g0[q] * sc * norm_w[e0 + q]);
    o[q + 4] = f2bf(g1[q] * sc * norm_w[e0 + 4 + q]);
  }
  *(us8*)(ynorm + (size_t)row * DI + e0) = o;
}

extern "C" void kernel_launch(void* const* d_in, const int* in_sizes, int n_in,
                              void* d_out, int out_size, void* d_ws, size_t ws_size,
                              hipStream_t stream)
{
  (void)in_sizes; (void)n_in; (void)out_size;
  const float* x       = (const float*)d_in[0];
  const float* W_in    = (const float*)d_in[1];
  const float* conv_w  = (const float*)d_in[2];
  const float* conv_b  = (const float*)d_in[3];
  const float* dt_bias = (const float*)d_in[4];
  const float* A_log   = (const float*)d_in[5];
  const float* Dp      = (const float*)d_in[6];
  const float* norm_w  = (const float*)d_in[7];
  const float* W_out   = (const float*)d_in[8];
  float* out = (float*)d_out;

  // ---- pick largest segment size that fits ws_size ----
  int nr = 512;
  {
    const int cands[4] = {4096, 2048, 1024, 512};
    for (int ci = 0; ci < 4; ++ci) {
      size_t need = (size_t)cands[ci] * 25792 + 7744512;
      if (need <= ws_size) { nr = cands[ci]; break; }
    }
  }
  const int G = L_ / nr;          // segments per batch
  const int S = B_ * G;           // total segments
  const int NCseg = nr / Q_;      // chunks per segment

  // ---- workspace layout ----
  char* ws = (char*)d_ws;
  float* zseg = (float*)ws;  ws += (size_t)nr * DI * 4;
  float* xbc  = (float*)ws;  ws += (size_t)nr * CD * 4;
  float* xs   = (float*)ws;  ws += (size_t)nr * DI * 4;
  float* Bm   = (float*)ws;  ws += (size_t)nr * DS * 4;
  float* Cm   = (float*)ws;  ws += (size_t)nr * DS * 4;
  float* dtv  = (float*)ws;  ws += (size_t)nr * H_ * 4;
  float* cumA = (float*)ws;  ws += (size_t)H_ * nr * 4;
  float* Sbuf = (float*)ws;  ws += (size_t)nr * 6144;
  unsigned short* WinT  = (unsigned short*)ws; ws += (size_t)NPJ * DM * 2;
  unsigned short* WoutT = (unsigned short*)ws; ws += (size_t)DM * DI * 2;
  float* Scarry = (float*)ws;  ws += (size_t)H_ * DS * P_ * 4;
  float* halo   = (float*)ws;  ws += (size_t)2 * 3 * CD * 4;
  float* ytot = xbc;                                 // overlay: xbc dead after conv
  unsigned short* xb    = (unsigned short*)Sbuf;     // overlay: Sbuf dead until k_intra
  unsigned short* ynorm = (unsigned short*)xs;       // overlay: xs dead after k_inter

  k_transpose_cast<<<dim3(24, (NPJ + 31) / 32), 256, 0, stream>>>(W_in, WinT, DM, NPJ);
  k_transpose_cast<<<dim3(48, 24), 256, 0, stream>>>(W_out, WoutT, DI, DM);

  for (int s = 0; s < S; ++s) {
    const int g = s % G;
    const size_t row0 = (size_t)s * nr;

    k_cast<<<nr * DM / 1024, 256, 0, stream>>>(x + row0 * DM, xb, nr * DM);
    k_gemm<<<dim3(nr / 128, N1 / 128), 256, 0, stream>>>(
        xb, WinT, zseg, DI, DI, xbc, CD, DM);
    k_conv<<<dim3(7, nr), 256, 0, stream>>>(xbc, conv_w, conv_b, xs, Bm, Cm,
                                            halo + (g & 1) * (3 * CD),
                                            halo + ((g + 1) & 1) * (3 * CD), g);
    k_dt<<<nr * H_ / 256, 256, 0, stream>>>(x, W_in, dt_bias, dtv, (int)row0, nr * H_);
    k_cum<<<(H_ * NCseg + 255) / 256, 256, 0, stream>>>(dtv, A_log, cumA, NCseg);
    k_intra<<<dim3(NCseg, H_), 256, 0, stream>>>(xs, Bm, Cm, dtv, cumA, ytot, Sbuf, NCseg);
    k_chunkscan<<<dim3(16, H_), 64, 0, stream>>>(Sbuf, cumA, Scarry, g, NCseg);
    k_inter<<<dim3(NCseg, H_), 256, 0, stream>>>(xs, Cm, cumA, Sbuf, Dp, ytot, NCseg);
    k_rms<<<nr, 192, 0, stream>>>(zseg, ytot, norm_w, ynorm);
    k_gemm<<<dim3(nr / 128, DM / 128), 256, 0, stream>>>(
        ynorm, WoutT, out + row0 * DM, DM, DM, out + row0 * DM, DM, DI);
  }
}

// Round 5
// 521.679 us; speedup vs baseline: 1.3121x; 1.1153x over previous
//
#include <hip/hip_runtime.h>

// ---- problem constants ----
#define B_   2
#define L_   4096
#define DM   768
#define DI   1536     // D_INNER
#define DS   64       // D_STATE
#define H_   24       // NHEADS
#define P_   64       // HEADDIM
#define CD   1664     // CONV_DIM
#define NPJ  3224     // D_IN_PROJ
#define N1   3200     // GEMM1 useful cols (z + xBC; dt cols done exactly in k_dt2)
#define Q_   64       // chunk length
#define SP   76       // LDS row stride (floats) for k_inter tiles
#define HS   72       // fp16 LDS row stride (halves): <=2-way conflicts
#define WDS  772      // k_dt2 LDS W stride: bank=(4h+k)%32 -> 3-way max

typedef short          bf16x8 __attribute__((ext_vector_type(8)));
typedef _Float16       f16x8  __attribute__((ext_vector_type(8)));
typedef unsigned short us8    __attribute__((ext_vector_type(8)));
typedef unsigned short us4    __attribute__((ext_vector_type(4)));
typedef float          f32x4  __attribute__((ext_vector_type(4)));

__device__ __forceinline__ unsigned short f2bf(float f) {
  unsigned u = __float_as_uint(f);
  u += 0x7fffu + ((u >> 16) & 1u);   // RNE
  return (unsigned short)(u >> 16);
}
__device__ __forceinline__ float siluf(float x) { return x / (1.f + expf(-x)); }
__device__ __forceinline__ float softplusf(float x) { return (x > 20.f) ? x : log1pf(expf(x)); }

// async global->LDS, 16B per lane; LDS dest = uniform base + lane*16
__device__ __forceinline__ void gload16(const unsigned short* g, unsigned short* l) {
  __builtin_amdgcn_global_load_lds(
      (const __attribute__((address_space(1))) void*)g,
      (__attribute__((address_space(3))) void*)l, 16, 0, 0);
}

// ---------------- cast fp32 -> bf16 ----------------
__global__ void k_cast(const float* __restrict__ src, unsigned short* __restrict__ dst, int n)
{
  const int i = (blockIdx.x * 256 + threadIdx.x) * 4;
  if (i >= n) return;
  f32x4 v = *(const f32x4*)(src + i);
  us4 o;
#pragma unroll
  for (int q = 0; q < 4; ++q) o[q] = f2bf(v[q]);
  *(us4*)(dst + i) = o;
}

// ---------------- transpose + cast (R x C fp32) -> (C x R bf16) ----------------
__global__ __launch_bounds__(256)
void k_transpose_cast(const float* __restrict__ src, unsigned short* __restrict__ dst,
                      int R, int C)
{
  __shared__ float tile[32][33];
  const int tx = threadIdx.x & 31, ty = threadIdx.x >> 5;
  const int r0 = blockIdx.x * 32, c0 = blockIdx.y * 32;
#pragma unroll
  for (int r = 0; r < 4; ++r) {
    int rr = r0 + ty + r * 8, cc = c0 + tx;
    if (rr < R && cc < C) tile[ty + r * 8][tx] = src[(size_t)rr * C + cc];
  }
  __syncthreads();
#pragma unroll
  for (int r = 0; r < 4; ++r) {
    int orow = c0 + ty + r * 8, ocol = r0 + tx;
    if (orow < C && ocol < R) dst[(size_t)orow * R + ocol] = f2bf(tile[tx][ty + r * 8]);
  }
}

// ---------------- gather dt columns of W_in -> contiguous fp32 WdtT[24][768] ----------------
__global__ void k_wdtT(const float* __restrict__ W_in, float* __restrict__ WdtT)
{
  const int idx = blockIdx.x * 256 + threadIdx.x;
  if (idx >= H_ * DM) return;
  const int k = idx / H_, h = idx % H_;            // read-coalesced over h
  WdtT[(size_t)h * DM + k] = W_in[(size_t)k * NPJ + N1 + h];
}

// ---------------- bf16 MFMA GEMM (m97-style global_load_lds staging) ----------------
// C(MxN) = A(MxK) @ Bt(NxK)^T. M,N multiples of 128; K multiple of 32.
// cols [0,ncol0) -> C0 (ld0); cols [ncol0,N) -> C1 (ld1).
__global__ __launch_bounds__(256)
void k_gemm(const unsigned short* __restrict__ A, const unsigned short* __restrict__ Bt,
            float* __restrict__ C0, int ld0, int ncol0,
            float* __restrict__ C1, int ld1, int K)
{
  const int m0 = blockIdx.x * 128, n0 = blockIdx.y * 128;
  __shared__ unsigned short As[128][32];   // UNPADDED: global_load_lds lane-contiguous
  __shared__ unsigned short Bs[128][32];
  const int tid  = threadIdx.x;
  const int wave = tid >> 6, lane = tid & 63;
  const int quad = lane >> 4, r16 = lane & 15;
  const int wm = (wave >> 1) * 64, wn = (wave & 1) * 64;

  const int wr = wave * 32;
  const int lrow = lane >> 2, lk8 = (lane & 3) * 8;
  const unsigned short* gA0 = A  + (size_t)(m0 + wr + lrow) * K + lk8;
  const unsigned short* gB0 = Bt + (size_t)(n0 + wr + lrow) * K + lk8;
  unsigned short* lA0 = &As[wr][0];
  unsigned short* lA1 = &As[wr + 16][0];
  unsigned short* lB0 = &Bs[wr][0];
  unsigned short* lB1 = &Bs[wr + 16][0];
  const size_t rstep = (size_t)16 * K;

  f32x4 acc[4][4];
#pragma unroll
  for (int a = 0; a < 4; ++a)
#pragma unroll
    for (int bq = 0; bq < 4; ++bq) acc[a][bq] = (f32x4){0.f, 0.f, 0.f, 0.f};

  for (int k0 = 0; k0 < K; k0 += 32) {
    gload16(gA0 + k0,         lA0);
    gload16(gA0 + k0 + rstep, lA1);
    gload16(gB0 + k0,         lB0);
    gload16(gB0 + k0 + rstep, lB1);
    __syncthreads();
    bf16x8 af[4], bfr[4];
#pragma unroll
    for (int mi = 0; mi < 4; ++mi) af[mi]  = *(const bf16x8*)&As[wm + mi * 16 + r16][quad * 8];
#pragma unroll
    for (int ni = 0; ni < 4; ++ni) bfr[ni] = *(const bf16x8*)&Bs[wn + ni * 16 + r16][quad * 8];
#pragma unroll
    for (int mi = 0; mi < 4; ++mi)
#pragma unroll
      for (int ni = 0; ni < 4; ++ni)
        acc[mi][ni] = __builtin_amdgcn_mfma_f32_16x16x32_bf16(af[mi], bfr[ni], acc[mi][ni], 0, 0, 0);
    __syncthreads();
  }
#pragma unroll
  for (int mi = 0; mi < 4; ++mi)
#pragma unroll
    for (int ni = 0; ni < 4; ++ni) {
      int col = n0 + wn + ni * 16 + r16;
      float* dst; int ld, c;
      if (col < ncol0) { dst = C0; ld = ld0; c = col; }
      else             { dst = C1; ld = ld1; c = col - ncol0; }
#pragma unroll
      for (int r = 0; r < 4; ++r) {
        int row = m0 + wm + mi * 16 + quad * 4 + r;
        dst[(size_t)row * ld + c] = acc[mi][ni][r];
      }
    }
}

// ---------------- depthwise conv(4) + silu, split outputs; fused halo save ----------------
__global__ void k_conv(const float* __restrict__ xbc, const float* __restrict__ cw,
                       const float* __restrict__ cb, float* __restrict__ xs,
                       float* __restrict__ Bm, float* __restrict__ Cm,
                       const float* __restrict__ halo, float* __restrict__ halo_next, int g)
{
  const int ch = blockIdx.x * 256 + threadIdx.x;
  const int lr = blockIdx.y;
  const int nr = gridDim.y;
  if (ch >= CD) return;
  float acc = cb[ch];
  float raw = 0.f;
#pragma unroll
  for (int k = 0; k < 4; ++k) {
    int m = lr - 3 + k;
    float v;
    if (m >= 0)       v = xbc[(size_t)m * CD + ch];
    else if (g > 0)   v = halo[(size_t)(m + 3) * CD + ch];
    else              v = 0.f;
    if (k == 3) raw = v;
    acc += v * cw[ch * 4 + k];
  }
  if (lr >= nr - 3) halo_next[(size_t)(lr - (nr - 3)) * CD + ch] = raw;
  float v = siluf(acc);
  if (ch < DI)           xs[(size_t)lr * DI + ch] = v;
  else if (ch < DI + DS) Bm[(size_t)lr * DS + (ch - DI)] = v;
  else                   Cm[(size_t)lr * DS + (ch - DI - DS)] = v;
}

// ---------------- exact fp32 dt via LDS-staged WdtT ----------------
// block = 192 threads = 24 heads x 8 rows
__global__ __launch_bounds__(192)
void k_dt2(const float* __restrict__ x, const float* __restrict__ WdtT,
           const float* __restrict__ dt_bias, float* __restrict__ dtv, int row0)
{
  __shared__ float sW[H_][WDS];
  for (int i = threadIdx.x; i < H_ * DM; i += 192)
    sW[i / DM][i % DM] = WdtT[i];
  const int h = threadIdx.x % H_, rloc = threadIdx.x / H_;
  const int lrow = blockIdx.x * 8 + rloc;
  const float* xr = x + (size_t)(row0 + lrow) * DM;
  __syncthreads();
  float acc = 0.f;
#pragma unroll 8
  for (int k = 0; k < DM; k += 4) {
    f32x4 xv = *(const f32x4*)(xr + k);
    f32x4 wv = *(const f32x4*)&sW[h][k];
    acc += xv[0] * wv[0] + xv[1] * wv[1] + xv[2] * wv[2] + xv[3] * wv[3];
  }
  dtv[(size_t)lrow * H_ + h] = softplusf(acc + dt_bias[h]);
}

// ---------------- per-chunk inclusive cumsum of dt*A ----------------
__global__ void k_cum(const float* __restrict__ dtv, const float* __restrict__ A_log,
                      float* __restrict__ cumA, int NCseg)
{
  const int idx = blockIdx.x * 256 + threadIdx.x;      // h*NCseg + c
  if (idx >= H_ * NCseg) return;
  const int c = idx % NCseg;
  const int h = idx / NCseg;
  const float A = -expf(A_log[h]);
  float cum = 0.f;
  const int rowbase = c * Q_;
  float* outp = cumA + (size_t)idx * Q_;
  for (int i = 0; i < Q_; ++i) {
    cum += dtv[(size_t)(rowbase + i) * H_ + h] * A;
    outp[i] = cum;
  }
}

// ---------------- intra-chunk via fp16 MFMA ----------------
// Per block (c,h): G=C@B^T (masked/decayed -> W), Y=W@X, T=(coef.B)^T@X.
// A/B frag elem [m=lane&15][k=quad*8+j]; C/D elem [row=quad*4+r][col=lane&15].
__global__ __launch_bounds__(256)
void k_intra(const float* __restrict__ xs, const float* __restrict__ Bm,
             const float* __restrict__ Cm, const float* __restrict__ dtv,
             const float* __restrict__ cumA, float* __restrict__ ytot,
             float* __restrict__ Sbuf, int NCseg)
{
  const int c = blockIdx.x, h = blockIdx.y;
  __shared__ _Float16 sCW[Q_][HS];   // C, then W
  __shared__ _Float16 sB [Q_][HS];
  __shared__ _Float16 sBT[Q_][HS];   // (coef_j * B[j][n]) transposed -> [n][j]
  __shared__ _Float16 sXT[Q_][HS];   // X transposed -> [p][j]
  __shared__ float scum[Q_], sdt[Q_];
  const int tid = threadIdx.x;
  const int rowbase = c * Q_;

  // ---- stage ----
  {
    const int j = tid >> 2, s16 = (tid & 3) * 16;
    if (tid < Q_) {
      scum[tid] = cumA[((size_t)(h * NCseg + c)) * Q_ + tid];
      sdt[tid]  = dtv[(size_t)(rowbase + tid) * H_ + h];
    }
    f32x4 xv[4], bv[4], cv[4];
    const float* xsrc = xs + (size_t)(rowbase + j) * DI + h * P_ + s16;
    const float* bsrc = Bm + (size_t)(rowbase + j) * DS + s16;
    const float* csrc = Cm + (size_t)(rowbase + j) * DS + s16;
#pragma unroll
    for (int q = 0; q < 4; ++q) {
      xv[q] = *(const f32x4*)(xsrc + q * 4);
      bv[q] = *(const f32x4*)(bsrc + q * 4);
      cv[q] = *(const f32x4*)(csrc + q * 4);
    }
    __syncthreads();                       // scum/sdt visible
    const float coef = expf(scum[Q_ - 1] - scum[j]) * sdt[j];
    union { f16x8 v; _Float16 e[8]; } pc[2], pb[2];
#pragma unroll
    for (int q = 0; q < 4; ++q)
#pragma unroll
      for (int e = 0; e < 4; ++e) {
        int o = q * 4 + e;
        pc[o >> 3].e[o & 7] = (_Float16)cv[q][e];
        pb[o >> 3].e[o & 7] = (_Float16)bv[q][e];
        sBT[s16 + o][j] = (_Float16)(bv[q][e] * coef);
        sXT[s16 + o][j] = (_Float16)xv[q][e];
      }
    *(f16x8*)&sCW[j][s16]     = pc[0].v;
    *(f16x8*)&sCW[j][s16 + 8] = pc[1].v;
    *(f16x8*)&sB [j][s16]     = pb[0].v;
    *(f16x8*)&sB [j][s16 + 8] = pb[1].v;
  }
  __syncthreads();

  const int wave = tid >> 6, lane = tid & 63;
  const int quad = lane >> 4, r16 = lane & 15;
  const int i0 = wave * 16;
  const int irow = i0 + quad * 4;

  // ---- G = C @ B^T (skip fully-masked tiles ni>wave) ----
  f32x4 g[4];
#pragma unroll
  for (int q = 0; q < 4; ++q) g[q] = (f32x4){0.f, 0.f, 0.f, 0.f};
#pragma unroll
  for (int ni = 0; ni < 4; ++ni) {
    if (ni <= wave) {
#pragma unroll
      for (int ks = 0; ks < 2; ++ks)
        g[ni] = __builtin_amdgcn_mfma_f32_16x16x32_f16(
            *(const f16x8*)&sCW[i0 + r16][ks * 32 + quad * 8],
            *(const f16x8*)&sB [ni * 16 + r16][ks * 32 + quad * 8], g[ni], 0, 0, 0);
    }
  }
  // ---- decay + mask -> W ----
  float wv[4][4];
#pragma unroll
  for (int ni = 0; ni < 4; ++ni)
#pragma unroll
    for (int r = 0; r < 4; ++r) {
      int i = irow + r, jcol = ni * 16 + r16;
      float v = 0.f;
      if (ni <= wave && jcol <= i)
        v = g[ni][r] * expf(scum[i] - scum[jcol]) * sdt[jcol];
      wv[ni][r] = v;
    }
  __syncthreads();                         // all reads of sCW(C) done
#pragma unroll
  for (int ni = 0; ni < 4; ++ni)
#pragma unroll
    for (int r = 0; r < 4; ++r)
      sCW[irow + r][ni * 16 + r16] = (_Float16)wv[ni][r];
  __syncthreads();

  // ---- Y = W @ X (waves 0/1: K<=32 -> single k-step) ----
  f32x4 y[4];
#pragma unroll
  for (int q = 0; q < 4; ++q) y[q] = (f32x4){0.f, 0.f, 0.f, 0.f};
#pragma unroll
  for (int ni = 0; ni < 4; ++ni)
#pragma unroll
    for (int ks = 0; ks < 2; ++ks) {
      if (ks == 0 || wave >= 2)
        y[ni] = __builtin_amdgcn_mfma_f32_16x16x32_f16(
            *(const f16x8*)&sCW[i0 + r16][ks * 32 + quad * 8],
            *(const f16x8*)&sXT[ni * 16 + r16][ks * 32 + quad * 8], y[ni], 0, 0, 0);
    }
#pragma unroll
  for (int ni = 0; ni < 4; ++ni)
#pragma unroll
    for (int r = 0; r < 4; ++r)
      ytot[(size_t)(rowbase + irow + r) * DI + h * P_ + ni * 16 + r16] = y[ni][r];

  // ---- T = (coef.B)^T @ X ----
  f32x4 t4[4];
#pragma unroll
  for (int q = 0; q < 4; ++q) t4[q] = (f32x4){0.f, 0.f, 0.f, 0.f};
#pragma unroll
  for (int ni = 0; ni < 4; ++ni)
#pragma unroll
    for (int ks = 0; ks < 2; ++ks)
      t4[ni] = __builtin_amdgcn_mfma_f32_16x16x32_f16(
          *(const f16x8*)&sBT[i0 + r16][ks * 32 + quad * 8],
          *(const f16x8*)&sXT[ni * 16 + r16][ks * 32 + quad * 8], t4[ni], 0, 0, 0);
  float* sp = Sbuf + ((size_t)(h * NCseg + c)) * (DS * P_);
#pragma unroll
  for (int ni = 0; ni < 4; ++ni)
#pragma unroll
    for (int r = 0; r < 4; ++r)
      sp[(irow + r) * P_ + ni * 16 + r16] = t4[ni][r];
}

// ---------------- sequential inter-chunk recurrence (in-place: T -> S_prev) ----------------
__global__ void k_chunkscan(float* __restrict__ Sbuf, const float* __restrict__ cumA,
                            float* __restrict__ Scarry, int g, int NCseg)
{
  const int seg = blockIdx.x, h = blockIdx.y;
  __shared__ float dec[Q_];
  const int tid = threadIdx.x;
  if (tid < NCseg) dec[tid] = expf(cumA[((size_t)(h * NCseg + tid)) * Q_ + (Q_ - 1)]);
  __syncthreads();
  const size_t off = (size_t)seg * 256 + (size_t)tid * 4;
  float* carry = Scarry + (size_t)h * (DS * P_) + off;
  f32x4 s;
  if (g > 0) s = *(const f32x4*)carry;
  else       s = (f32x4){0.f, 0.f, 0.f, 0.f};
  size_t base = (size_t)h * NCseg * (DS * P_) + off;
  for (int c = 0; c < NCseg; ++c) {
    float* p = Sbuf + base + (size_t)c * (DS * P_);
    f32x4 v = *(const f32x4*)p;
    *(f32x4*)p = s;               // store state BEFORE chunk c
    s = s * dec[c] + v;
  }
  *(f32x4*)carry = s;
}

// ---------------- inter-chunk correction + D*x ----------------
__global__ __launch_bounds__(256)
void k_inter(const float* __restrict__ xs, const float* __restrict__ Cm,
             const float* __restrict__ cumA, const float* __restrict__ Sbuf,
             const float* __restrict__ Dp, float* __restrict__ ytot, int NCseg)
{
  const int c = blockIdx.x, h = blockIdx.y;
  __shared__ float sS[DS][SP];
  __shared__ float sC[Q_][SP];
  __shared__ float scum[Q_];
  const int tid = threadIdx.x;
  const int jr = tid >> 2, blk = (tid & 3) * 16;
  const int rowbase = c * Q_;
  {
    const float* ssrc = Sbuf + ((size_t)(h * NCseg + c)) * (DS * P_) + jr * P_ + blk;
    const float* csrc = Cm + (size_t)(rowbase + jr) * DS + blk;
#pragma unroll
    for (int q = 0; q < 4; ++q) {
      *(f32x4*)&sS[jr][blk + q * 4] = *(const f32x4*)(ssrc + q * 4);
      *(f32x4*)&sC[jr][blk + q * 4] = *(const f32x4*)(csrc + q * 4);
    }
    if (tid < Q_) scum[tid] = cumA[((size_t)(h * NCseg + c)) * Q_ + tid];
  }
  __syncthreads();
  const int i = jr;
  f32x4 acc[4];
#pragma unroll
  for (int q = 0; q < 4; ++q) acc[q] = (f32x4){0.f, 0.f, 0.f, 0.f};
  for (int n = 0; n < DS; ++n) {
    float cv = sC[i][n];
#pragma unroll
    for (int q = 0; q < 4; ++q) acc[q] += cv * *(const f32x4*)&sS[n][blk + q * 4];
  }
  const float e = expf(scum[i]);
  const float Dh = Dp[h];
  float* yt = ytot + (size_t)(rowbase + i) * DI + h * P_ + blk;
  const float* xsr = xs + (size_t)(rowbase + i) * DI + h * P_ + blk;
#pragma unroll
  for (int q = 0; q < 4; ++q) {
    f32x4 cur = *(const f32x4*)(yt + q * 4);
    f32x4 xv  = *(const f32x4*)(xsr + q * 4);
    cur += e * acc[q] + Dh * xv;
    *(f32x4*)(yt + q * 4) = cur;
  }
}

// ---------------- gate (silu(z)) + RMSNorm + cast bf16 ----------------
__global__ __launch_bounds__(192)
void k_rms(const float* __restrict__ z, const float* __restrict__ ytot,
           const float* __restrict__ norm_w, unsigned short* __restrict__ ynorm)
{
  const int row = blockIdx.x, tid = threadIdx.x;
  const int e0 = tid * 8;
  const float* zr = z + (size_t)row * DI;
  const float* yr = ytot + (size_t)row * DI;
  f32x4 zv0 = *(const f32x4*)(zr + e0);
  f32x4 zv1 = *(const f32x4*)(zr + e0 + 4);
  f32x4 yv0 = *(const f32x4*)(yr + e0);
  f32x4 yv1 = *(const f32x4*)(yr + e0 + 4);
  f32x4 g0, g1;
  float ss = 0.f;
#pragma unroll
  for (int q = 0; q < 4; ++q) {
    g0[q] = yv0[q] * siluf(zv0[q]); ss += g0[q] * g0[q];
    g1[q] = yv1[q] * siluf(zv1[q]); ss += g1[q] * g1[q];
  }
#pragma unroll
  for (int off = 32; off > 0; off >>= 1) ss += __shfl_down(ss, off);
  __shared__ float wsum[3];
  __shared__ float sscale;
  if ((tid & 63) == 0) wsum[tid >> 6] = ss;
  __syncthreads();
  if (tid == 0) sscale = rsqrtf((wsum[0] + wsum[1] + wsum[2]) * (1.f / DI) + 1e-5f);
  __syncthreads();
  const float sc = sscale;
  us8 o;
#pragma unroll
  for (int q = 0; q < 4; ++q) {
    o[q]     = f2bf(g0[q] * sc * norm_w[e0 + q]);
    o[q + 4] = f2bf(g1[q] * sc * norm_w[e0 + 4 + q]);
  }
  *(us8*)(ynorm + (size_t)row * DI + e0) = o;
}

extern "C" void kernel_launch(void* const* d_in, const int* in_sizes, int n_in,
                              void* d_out, int out_size, void* d_ws, size_t ws_size,
                              hipStream_t stream)
{
  (void)in_sizes; (void)n_in; (void)out_size;
  const float* x       = (const float*)d_in[0];
  const float* W_in    = (const float*)d_in[1];
  const float* conv_w  = (const float*)d_in[2];
  const float* conv_b  = (const float*)d_in[3];
  const float* dt_bias = (const float*)d_in[4];
  const float* A_log   = (const float*)d_in[5];
  const float* Dp      = (const float*)d_in[6];
  const float* norm_w  = (const float*)d_in[7];
  const float* W_out   = (const float*)d_in[8];
  float* out = (float*)d_out;

  // ---- pick largest segment size that fits ws_size ----
  // footprint(nr) = nr*25792 + fixed (8,039,424 = weights + carry + halo + WdtT)
  int nr = 512;
  {
    const int cands[4] = {4096, 2048, 1024, 512};
    for (int ci = 0; ci < 4; ++ci) {
      size_t need = (size_t)cands[ci] * 25792 + 8039424;
      if (need <= ws_size) { nr = cands[ci]; break; }
    }
  }
  const int G = L_ / nr;          // segments per batch
  const int S = B_ * G;           // total segments
  const int NCseg = nr / Q_;      // chunks per segment

  // ---- workspace layout ----
  char* ws = (char*)d_ws;
  float* zseg = (float*)ws;  ws += (size_t)nr * DI * 4;
  float* xbc  = (float*)ws;  ws += (size_t)nr * CD * 4;
  float* xs   = (float*)ws;  ws += (size_t)nr * DI * 4;
  float* Bm   = (float*)ws;  ws += (size_t)nr * DS * 4;
  float* Cm   = (float*)ws;  ws += (size_t)nr * DS * 4;
  float* dtv  = (float*)ws;  ws += (size_t)nr * H_ * 4;
  float* cumA = (float*)ws;  ws += (size_t)H_ * nr * 4;
  float* Sbuf = (float*)ws;  ws += (size_t)nr * 6144;
  unsigned short* WinT  = (unsigned short*)ws; ws += (size_t)NPJ * DM * 2;
  unsigned short* WoutT = (unsigned short*)ws; ws += (size_t)DM * DI * 2;
  float* Scarry = (float*)ws;  ws += (size_t)H_ * DS * P_ * 4;
  float* halo   = (float*)ws;  ws += (size_t)2 * 3 * CD * 4;
  float* WdtT   = (float*)ws;  ws += (size_t)H_ * DM * 4;
  float* ytot = xbc;                                 // overlay: xbc dead after conv
  unsigned short* xb    = (unsigned short*)Sbuf;     // overlay: Sbuf dead until k_intra
  unsigned short* ynorm = (unsigned short*)xs;       // overlay: xs dead after k_inter

  k_transpose_cast<<<dim3(24, (NPJ + 31) / 32), 256, 0, stream>>>(W_in, WinT, DM, NPJ);
  k_transpose_cast<<<dim3(48, 24), 256, 0, stream>>>(W_out, WoutT, DI, DM);
  k_wdtT<<<(H_ * DM + 255) / 256, 256, 0, stream>>>(W_in, WdtT);

  for (int s = 0; s < S; ++s) {
    const int g = s % G;
    const size_t row0 = (size_t)s * nr;

    k_cast<<<nr * DM / 1024, 256, 0, stream>>>(x + row0 * DM, xb, nr * DM);
    k_gemm<<<dim3(nr / 128, N1 / 128), 256, 0, stream>>>(
        xb, WinT, zseg, DI, DI, xbc, CD, DM);
    k_conv<<<dim3(7, nr), 256, 0, stream>>>(xbc, conv_w, conv_b, xs, Bm, Cm,
                                            halo + (g & 1) * (3 * CD),
                                            halo + ((g + 1) & 1) * (3 * CD), g);
    k_dt2<<<nr / 8, 192, 0, stream>>>(x, WdtT, dt_bias, dtv, (int)row0);
    k_cum<<<(H_ * NCseg + 255) / 256, 256, 0, stream>>>(dtv, A_log, cumA, NCseg);
    k_intra<<<dim3(NCseg, H_), 256, 0, stream>>>(xs, Bm, Cm, dtv, cumA, ytot, Sbuf, NCseg);
    k_chunkscan<<<dim3(16, H_), 64, 0, stream>>>(Sbuf, cumA, Scarry, g, NCseg);
    k_inter<<<dim3(NCseg, H_), 256, 0, stream>>>(xs, Cm, cumA, Sbuf, Dp, ytot, NCseg);
    k_rms<<<nr, 192, 0, stream>>>(zseg, ytot, norm_w, ynorm);
    k_gemm<<<dim3(nr / 128, DM / 128), 256, 0, stream>>>(
        ynorm, WoutT, out + row0 * DM, DM, DM, out + row0 * DM, DM, DI);
  }
}

// Round 6
// 473.097 us; speedup vs baseline: 1.4469x; 1.1027x over previous
//
#include <hip/hip_runtime.h>

// ---- problem constants ----
#define B_   2
#define L_   4096
#define DM   768
#define DI   1536     // D_INNER
#define DS   64       // D_STATE
#define H_   24       // NHEADS
#define P_   64       // HEADDIM
#define CD   1664     // CONV_DIM
#define NPJ  3224     // D_IN_PROJ
#define N1   3200     // GEMM1 useful cols (z + xBC; dt cols done exactly in k_dt2)
#define Q_   64       // chunk length
#define SP   76       // LDS row stride (floats) for k_inter tiles
#define HS   72       // fp16 LDS row stride (halves): <=2-way conflicts
#define WDS  772      // k_dt2 LDS W stride

typedef short          bf16x8 __attribute__((ext_vector_type(8)));
typedef _Float16       f16x8  __attribute__((ext_vector_type(8)));
typedef unsigned short us8    __attribute__((ext_vector_type(8)));
typedef unsigned short us4    __attribute__((ext_vector_type(4)));
typedef float          f32x4  __attribute__((ext_vector_type(4)));

__device__ __forceinline__ unsigned short f2bf(float f) {
  unsigned u = __float_as_uint(f);
  u += 0x7fffu + ((u >> 16) & 1u);   // RNE
  return (unsigned short)(u >> 16);
}
__device__ __forceinline__ float siluf(float x) { return x / (1.f + expf(-x)); }
__device__ __forceinline__ float softplusf(float x) { return (x > 20.f) ? x : log1pf(expf(x)); }

// async global->LDS, 16B per lane; LDS dest = uniform base + lane*16
__device__ __forceinline__ void gload16(const unsigned short* g, unsigned short* l) {
  __builtin_amdgcn_global_load_lds(
      (const __attribute__((address_space(1))) void*)g,
      (__attribute__((address_space(3))) void*)l, 16, 0, 0);
}

// ---------------- cast fp32 -> bf16 ----------------
__global__ void k_cast(const float* __restrict__ src, unsigned short* __restrict__ dst, int n)
{
  const int i = (blockIdx.x * 256 + threadIdx.x) * 4;
  if (i >= n) return;
  f32x4 v = *(const f32x4*)(src + i);
  us4 o;
#pragma unroll
  for (int q = 0; q < 4; ++q) o[q] = f2bf(v[q]);
  *(us4*)(dst + i) = o;
}

// ---------------- transpose + cast (R x C fp32) -> (C x R bf16) ----------------
__global__ __launch_bounds__(256)
void k_transpose_cast(const float* __restrict__ src, unsigned short* __restrict__ dst,
                      int R, int C)
{
  __shared__ float tile[32][33];
  const int tx = threadIdx.x & 31, ty = threadIdx.x >> 5;
  const int r0 = blockIdx.x * 32, c0 = blockIdx.y * 32;
#pragma unroll
  for (int r = 0; r < 4; ++r) {
    int rr = r0 + ty + r * 8, cc = c0 + tx;
    if (rr < R && cc < C) tile[ty + r * 8][tx] = src[(size_t)rr * C + cc];
  }
  __syncthreads();
#pragma unroll
  for (int r = 0; r < 4; ++r) {
    int orow = c0 + ty + r * 8, ocol = r0 + tx;
    if (orow < C && ocol < R) dst[(size_t)orow * R + ocol] = f2bf(tile[tx][ty + r * 8]);
  }
}

// ---------------- gather dt columns of W_in -> contiguous fp32 WdtT[24][768] ----------------
__global__ void k_wdtT(const float* __restrict__ W_in, float* __restrict__ WdtT)
{
  const int idx = blockIdx.x * 256 + threadIdx.x;
  if (idx >= H_ * DM) return;
  const int k = idx / H_, h = idx % H_;
  WdtT[(size_t)h * DM + k] = W_in[(size_t)k * NPJ + N1 + h];
}

// ---------------- bf16 MFMA GEMM, BK=64, XOR-swizzled LDS (conflict-free) ----------------
// C(MxN) = A(MxK) @ Bt(NxK)^T. M%BM==0, N%BN==0, K%64==0.
// cols [0,ncol0) -> C0 (ld0); cols [ncol0,N) -> C1 (ld1).
// LDS physical chunk (16B) c of row r holds logical chunk c ^ (r&7).
template<int BM, int BN, int WM, int WN>
__global__ __launch_bounds__(256)
void k_gemm_t(const unsigned short* __restrict__ A, const unsigned short* __restrict__ Bt,
              float* __restrict__ C0, int ld0, int ncol0,
              float* __restrict__ C1, int ld1, int K)
{
  constexpr int MI = WM / 16, NI = WN / 16;
  constexpr int WAVES_N = BN / WN;
  constexpr int RA = BM / 32, RB = BN / 32;
  const int m0 = blockIdx.x * BM, n0 = blockIdx.y * BN;
  __shared__ unsigned short As[BM][64];
  __shared__ unsigned short Bs[BN][64];
  const int tid  = threadIdx.x;
  const int wave = tid >> 6, lane = tid & 63;
  const int quad = lane >> 4, r16 = lane & 15;
  const int wm = (wave / WAVES_N) * WM, wn = (wave % WAVES_N) * WN;

  // staging: round r covers rows [r*32, r*32+32); wave's 8-row band; 8 lanes/row.
  const int lr8 = lane >> 3;                                // 0..7 row-in-band
  const int csw = ((lane & 7) ^ lr8) * 8;                   // swizzled source col (shorts)
  const unsigned short* gA = A  + (size_t)(m0 + wave * 8 + lr8) * K + csw;
  const unsigned short* gB = Bt + (size_t)(n0 + wave * 8 + lr8) * K + csw;
  unsigned short* lA = &As[wave * 8][0] + (size_t)lane * 8; // +lane*16B
  unsigned short* lB = &Bs[wave * 8][0] + (size_t)lane * 8;

  f32x4 acc[MI][NI];
#pragma unroll
  for (int mi = 0; mi < MI; ++mi)
#pragma unroll
    for (int ni = 0; ni < NI; ++ni) acc[mi][ni] = (f32x4){0.f, 0.f, 0.f, 0.f};

  for (int k0 = 0; k0 < K; k0 += 64) {
#pragma unroll
    for (int r = 0; r < RA; ++r)
      gload16(gA + (size_t)(r * 32) * K + k0, lA + (size_t)r * 32 * 64);
#pragma unroll
    for (int r = 0; r < RB; ++r)
      gload16(gB + (size_t)(r * 32) * K + k0, lB + (size_t)r * 32 * 64);
    __syncthreads();
    bf16x8 af[MI][2], bfr[NI][2];
#pragma unroll
    for (int mi = 0; mi < MI; ++mi)
#pragma unroll
      for (int ks = 0; ks < 2; ++ks)
        af[mi][ks] = *(const bf16x8*)&As[wm + mi * 16 + r16][((quad + ks * 4) ^ (r16 & 7)) * 8];
#pragma unroll
    for (int ni = 0; ni < NI; ++ni)
#pragma unroll
      for (int ks = 0; ks < 2; ++ks)
        bfr[ni][ks] = *(const bf16x8*)&Bs[wn + ni * 16 + r16][((quad + ks * 4) ^ (r16 & 7)) * 8];
#pragma unroll
    for (int mi = 0; mi < MI; ++mi)
#pragma unroll
      for (int ni = 0; ni < NI; ++ni)
#pragma unroll
        for (int ks = 0; ks < 2; ++ks)
          acc[mi][ni] = __builtin_amdgcn_mfma_f32_16x16x32_bf16(
              af[mi][ks], bfr[ni][ks], acc[mi][ni], 0, 0, 0);
    __syncthreads();
  }
#pragma unroll
  for (int mi = 0; mi < MI; ++mi)
#pragma unroll
    for (int ni = 0; ni < NI; ++ni) {
      int col = n0 + wn + ni * 16 + r16;
      float* dst; int ld, c;
      if (col < ncol0) { dst = C0; ld = ld0; c = col; }
      else             { dst = C1; ld = ld1; c = col - ncol0; }
#pragma unroll
      for (int r = 0; r < 4; ++r) {
        int row = m0 + wm + mi * 16 + quad * 4 + r;
        dst[(size_t)row * ld + c] = acc[mi][ni][r];
      }
    }
}

// ---------------- depthwise conv(4) + silu, split outputs; fused halo save ----------------
__global__ void k_conv(const float* __restrict__ xbc, const float* __restrict__ cw,
                       const float* __restrict__ cb, float* __restrict__ xs,
                       float* __restrict__ Bm, float* __restrict__ Cm,
                       const float* __restrict__ halo, float* __restrict__ halo_next, int g)
{
  const int ch = blockIdx.x * 256 + threadIdx.x;
  const int lr = blockIdx.y;
  const int nr = gridDim.y;
  if (ch >= CD) return;
  float acc = cb[ch];
  float raw = 0.f;
#pragma unroll
  for (int k = 0; k < 4; ++k) {
    int m = lr - 3 + k;
    float v;
    if (m >= 0)       v = xbc[(size_t)m * CD + ch];
    else if (g > 0)   v = halo[(size_t)(m + 3) * CD + ch];
    else              v = 0.f;
    if (k == 3) raw = v;
    acc += v * cw[ch * 4 + k];
  }
  if (lr >= nr - 3) halo_next[(size_t)(lr - (nr - 3)) * CD + ch] = raw;
  float v = siluf(acc);
  if (ch < DI)           xs[(size_t)lr * DI + ch] = v;
  else if (ch < DI + DS) Bm[(size_t)lr * DS + (ch - DI)] = v;
  else                   Cm[(size_t)lr * DS + (ch - DI - DS)] = v;
}

// ---------------- exact fp32 dt via LDS-staged WdtT ----------------
__global__ __launch_bounds__(192)
void k_dt2(const float* __restrict__ x, const float* __restrict__ WdtT,
           const float* __restrict__ dt_bias, float* __restrict__ dtv, int row0)
{
  __shared__ float sW[H_][WDS];
  for (int i = threadIdx.x; i < H_ * DM; i += 192)
    sW[i / DM][i % DM] = WdtT[i];
  const int h = threadIdx.x % H_, rloc = threadIdx.x / H_;
  const int lrow = blockIdx.x * 8 + rloc;
  const float* xr = x + (size_t)(row0 + lrow) * DM;
  __syncthreads();
  float acc = 0.f;
#pragma unroll 8
  for (int k = 0; k < DM; k += 4) {
    f32x4 xv = *(const f32x4*)(xr + k);
    f32x4 wv = *(const f32x4*)&sW[h][k];
    acc += xv[0] * wv[0] + xv[1] * wv[1] + xv[2] * wv[2] + xv[3] * wv[3];
  }
  dtv[(size_t)lrow * H_ + h] = softplusf(acc + dt_bias[h]);
}

// ---------------- per-chunk inclusive cumsum of dt*A ----------------
__global__ void k_cum(const float* __restrict__ dtv, const float* __restrict__ A_log,
                      float* __restrict__ cumA, int NCseg)
{
  const int idx = blockIdx.x * 256 + threadIdx.x;      // h*NCseg + c
  if (idx >= H_ * NCseg) return;
  const int c = idx % NCseg;
  const int h = idx / NCseg;
  const float A = -expf(A_log[h]);
  float cum = 0.f;
  const int rowbase = c * Q_;
  float* outp = cumA + (size_t)idx * Q_;
  for (int i = 0; i < Q_; ++i) {
    cum += dtv[(size_t)(rowbase + i) * H_ + h] * A;
    outp[i] = cum;
  }
}

// ---------------- intra-chunk via fp16 MFMA ----------------
__global__ __launch_bounds__(256)
void k_intra(const float* __restrict__ xs, const float* __restrict__ Bm,
             const float* __restrict__ Cm, const float* __restrict__ dtv,
             const float* __restrict__ cumA, float* __restrict__ ytot,
             float* __restrict__ Sbuf, int NCseg)
{
  const int c = blockIdx.x, h = blockIdx.y;
  __shared__ _Float16 sCW[Q_][HS];   // C, then W
  __shared__ _Float16 sB [Q_][HS];
  __shared__ _Float16 sBT[Q_][HS];   // (coef_j * B[j][n]) transposed -> [n][j]
  __shared__ _Float16 sXT[Q_][HS];   // X transposed -> [p][j]
  __shared__ float scum[Q_], sdt[Q_];
  const int tid = threadIdx.x;
  const int rowbase = c * Q_;

  {
    const int j = tid >> 2, s16 = (tid & 3) * 16;
    if (tid < Q_) {
      scum[tid] = cumA[((size_t)(h * NCseg + c)) * Q_ + tid];
      sdt[tid]  = dtv[(size_t)(rowbase + tid) * H_ + h];
    }
    f32x4 xv[4], bv[4], cv[4];
    const float* xsrc = xs + (size_t)(rowbase + j) * DI + h * P_ + s16;
    const float* bsrc = Bm + (size_t)(rowbase + j) * DS + s16;
    const float* csrc = Cm + (size_t)(rowbase + j) * DS + s16;
#pragma unroll
    for (int q = 0; q < 4; ++q) {
      xv[q] = *(const f32x4*)(xsrc + q * 4);
      bv[q] = *(const f32x4*)(bsrc + q * 4);
      cv[q] = *(const f32x4*)(csrc + q * 4);
    }
    __syncthreads();
    const float coef = expf(scum[Q_ - 1] - scum[j]) * sdt[j];
    union { f16x8 v; _Float16 e[8]; } pc[2], pb[2];
#pragma unroll
    for (int q = 0; q < 4; ++q)
#pragma unroll
      for (int e = 0; e < 4; ++e) {
        int o = q * 4 + e;
        pc[o >> 3].e[o & 7] = (_Float16)cv[q][e];
        pb[o >> 3].e[o & 7] = (_Float16)bv[q][e];
        sBT[s16 + o][j] = (_Float16)(bv[q][e] * coef);
        sXT[s16 + o][j] = (_Float16)xv[q][e];
      }
    *(f16x8*)&sCW[j][s16]     = pc[0].v;
    *(f16x8*)&sCW[j][s16 + 8] = pc[1].v;
    *(f16x8*)&sB [j][s16]     = pb[0].v;
    *(f16x8*)&sB [j][s16 + 8] = pb[1].v;
  }
  __syncthreads();

  const int wave = tid >> 6, lane = tid & 63;
  const int quad = lane >> 4, r16 = lane & 15;
  const int i0 = wave * 16;
  const int irow = i0 + quad * 4;

  f32x4 g[4];
#pragma unroll
  for (int q = 0; q < 4; ++q) g[q] = (f32x4){0.f, 0.f, 0.f, 0.f};
#pragma unroll
  for (int ni = 0; ni < 4; ++ni) {
    if (ni <= wave) {
#pragma unroll
      for (int ks = 0; ks < 2; ++ks)
        g[ni] = __builtin_amdgcn_mfma_f32_16x16x32_f16(
            *(const f16x8*)&sCW[i0 + r16][ks * 32 + quad * 8],
            *(const f16x8*)&sB [ni * 16 + r16][ks * 32 + quad * 8], g[ni], 0, 0, 0);
    }
  }
  float wv[4][4];
#pragma unroll
  for (int ni = 0; ni < 4; ++ni)
#pragma unroll
    for (int r = 0; r < 4; ++r) {
      int i = irow + r, jcol = ni * 16 + r16;
      float v = 0.f;
      if (ni <= wave && jcol <= i)
        v = g[ni][r] * expf(scum[i] - scum[jcol]) * sdt[jcol];
      wv[ni][r] = v;
    }
  __syncthreads();
#pragma unroll
  for (int ni = 0; ni < 4; ++ni)
#pragma unroll
    for (int r = 0; r < 4; ++r)
      sCW[irow + r][ni * 16 + r16] = (_Float16)wv[ni][r];
  __syncthreads();

  f32x4 y[4];
#pragma unroll
  for (int q = 0; q < 4; ++q) y[q] = (f32x4){0.f, 0.f, 0.f, 0.f};
#pragma unroll
  for (int ni = 0; ni < 4; ++ni)
#pragma unroll
    for (int ks = 0; ks < 2; ++ks) {
      if (ks == 0 || wave >= 2)
        y[ni] = __builtin_amdgcn_mfma_f32_16x16x32_f16(
            *(const f16x8*)&sCW[i0 + r16][ks * 32 + quad * 8],
            *(const f16x8*)&sXT[ni * 16 + r16][ks * 32 + quad * 8], y[ni], 0, 0, 0);
    }
#pragma unroll
  for (int ni = 0; ni < 4; ++ni)
#pragma unroll
    for (int r = 0; r < 4; ++r)
      ytot[(size_t)(rowbase + irow + r) * DI + h * P_ + ni * 16 + r16] = y[ni][r];

  f32x4 t4[4];
#pragma unroll
  for (int q = 0; q < 4; ++q) t4[q] = (f32x4){0.f, 0.f, 0.f, 0.f};
#pragma unroll
  for (int ni = 0; ni < 4; ++ni)
#pragma unroll
    for (int ks = 0; ks < 2; ++ks)
      t4[ni] = __builtin_amdgcn_mfma_f32_16x16x32_f16(
          *(const f16x8*)&sBT[i0 + r16][ks * 32 + quad * 8],
          *(const f16x8*)&sXT[ni * 16 + r16][ks * 32 + quad * 8], t4[ni], 0, 0, 0);
  float* sp = Sbuf + ((size_t)(h * NCseg + c)) * (DS * P_);
#pragma unroll
  for (int ni = 0; ni < 4; ++ni)
#pragma unroll
    for (int r = 0; r < 4; ++r)
      sp[(irow + r) * P_ + ni * 16 + r16] = t4[ni][r];
}

// ---------------- sequential inter-chunk recurrence (in-place: T -> S_prev) ----------------
__global__ void k_chunkscan(float* __restrict__ Sbuf, const float* __restrict__ cumA,
                            float* __restrict__ Scarry, int g, int NCseg)
{
  const int seg = blockIdx.x, h = blockIdx.y;
  __shared__ float dec[Q_];
  const int tid = threadIdx.x;
  if (tid < NCseg) dec[tid] = expf(cumA[((size_t)(h * NCseg + tid)) * Q_ + (Q_ - 1)]);
  __syncthreads();
  const size_t off = (size_t)seg * 256 + (size_t)tid * 4;
  float* carry = Scarry + (size_t)h * (DS * P_) + off;
  f32x4 s;
  if (g > 0) s = *(const f32x4*)carry;
  else       s = (f32x4){0.f, 0.f, 0.f, 0.f};
  size_t base = (size_t)h * NCseg * (DS * P_) + off;
  for (int c = 0; c < NCseg; ++c) {
    float* p = Sbuf + base + (size_t)c * (DS * P_);
    f32x4 v = *(const f32x4*)p;
    *(f32x4*)p = s;               // store state BEFORE chunk c
    s = s * dec[c] + v;
  }
  *(f32x4*)carry = s;
}

// ---------------- inter-chunk correction + D*x ----------------
__global__ __launch_bounds__(256)
void k_inter(const float* __restrict__ xs, const float* __restrict__ Cm,
             const float* __restrict__ cumA, const float* __restrict__ Sbuf,
             const float* __restrict__ Dp, float* __restrict__ ytot, int NCseg)
{
  const int c = blockIdx.x, h = blockIdx.y;
  __shared__ float sS[DS][SP];
  __shared__ float sC[Q_][SP];
  __shared__ float scum[Q_];
  const int tid = threadIdx.x;
  const int jr = tid >> 2, blk = (tid & 3) * 16;
  const int rowbase = c * Q_;
  {
    const float* ssrc = Sbuf + ((size_t)(h * NCseg + c)) * (DS * P_) + jr * P_ + blk;
    const float* csrc = Cm + (size_t)(rowbase + jr) * DS + blk;
#pragma unroll
    for (int q = 0; q < 4; ++q) {
      *(f32x4*)&sS[jr][blk + q * 4] = *(const f32x4*)(ssrc + q * 4);
      *(f32x4*)&sC[jr][blk + q * 4] = *(const f32x4*)(csrc + q * 4);
    }
    if (tid < Q_) scum[tid] = cumA[((size_t)(h * NCseg + c)) * Q_ + tid];
  }
  __syncthreads();
  const int i = jr;
  f32x4 acc[4];
#pragma unroll
  for (int q = 0; q < 4; ++q) acc[q] = (f32x4){0.f, 0.f, 0.f, 0.f};
  for (int n = 0; n < DS; ++n) {
    float cv = sC[i][n];
#pragma unroll
    for (int q = 0; q < 4; ++q) acc[q] += cv * *(const f32x4*)&sS[n][blk + q * 4];
  }
  const float e = expf(scum[i]);
  const float Dh = Dp[h];
  float* yt = ytot + (size_t)(rowbase + i) * DI + h * P_ + blk;
  const float* xsr = xs + (size_t)(rowbase + i) * DI + h * P_ + blk;
#pragma unroll
  for (int q = 0; q < 4; ++q) {
    f32x4 cur = *(const f32x4*)(yt + q * 4);
    f32x4 xv  = *(const f32x4*)(xsr + q * 4);
    cur += e * acc[q] + Dh * xv;
    *(f32x4*)(yt + q * 4) = cur;
  }
}

// ---------------- gate (silu(z)) + RMSNorm + cast bf16 ----------------
__global__ __launch_bounds__(192)
void k_rms(const float* __restrict__ z, const float* __restrict__ ytot,
           const float* __restrict__ norm_w, unsigned short* __restrict__ ynorm)
{
  const int row = blockIdx.x, tid = threadIdx.x;
  const int e0 = tid * 8;
  const float* zr = z + (size_t)row * DI;
  const float* yr = ytot + (size_t)row * DI;
  f32x4 zv0 = *(const f32x4*)(zr + e0);
  f32x4 zv1 = *(const f32x4*)(zr + e0 + 4);
  f32x4 yv0 = *(const f32x4*)(yr + e0);
  f32x4 yv1 = *(const f32x4*)(yr + e0 + 4);
  f32x4 g0, g1;
  float ss = 0.f;
#pragma unroll
  for (int q = 0; q < 4; ++q) {
    g0[q] = yv0[q] * siluf(zv0[q]); ss += g0[q] * g0[q];
    g1[q] = yv1[q] * siluf(zv1[q]); ss += g1[q] * g1[q];
  }
#pragma unroll
  for (int off = 32; off > 0; off >>= 1) ss += __shfl_down(ss, off);
  __shared__ float wsum[3];
  __shared__ float sscale;
  if ((tid & 63) == 0) wsum[tid >> 6] = ss;
  __syncthreads();
  if (tid == 0) sscale = rsqrtf((wsum[0] + wsum[1] + wsum[2]) * (1.f / DI) + 1e-5f);
  __syncthreads();
  const float sc = sscale;
  us8 o;
#pragma unroll
  for (int q = 0; q < 4; ++q) {
    o[q]     = f2bf(g0[q] * sc * norm_w[e0 + q]);
    o[q + 4] = f2bf(g1[q] * sc * norm_w[e0 + 4 + q]);
  }
  *(us8*)(ynorm + (size_t)row * DI + e0) = o;
}

extern "C" void kernel_launch(void* const* d_in, const int* in_sizes, int n_in,
                              void* d_out, int out_size, void* d_ws, size_t ws_size,
                              hipStream_t stream)
{
  (void)in_sizes; (void)n_in; (void)out_size;
  const float* x       = (const float*)d_in[0];
  const float* W_in    = (const float*)d_in[1];
  const float* conv_w  = (const float*)d_in[2];
  const float* conv_b  = (const float*)d_in[3];
  const float* dt_bias = (const float*)d_in[4];
  const float* A_log   = (const float*)d_in[5];
  const float* Dp      = (const float*)d_in[6];
  const float* norm_w  = (const float*)d_in[7];
  const float* W_out   = (const float*)d_in[8];
  float* out = (float*)d_out;

  // ---- pick largest segment size that fits ws_size ----
  int nr = 512;
  {
    const int cands[4] = {4096, 2048, 1024, 512};
    for (int ci = 0; ci < 4; ++ci) {
      size_t need = (size_t)cands[ci] * 25792 + 8039424;
      if (need <= ws_size) { nr = cands[ci]; break; }
    }
  }
  const int G = L_ / nr;          // segments per batch
  const int S = B_ * G;           // total segments
  const int NCseg = nr / Q_;      // chunks per segment

  // ---- workspace layout ----
  char* ws = (char*)d_ws;
  float* zseg = (float*)ws;  ws += (size_t)nr * DI * 4;
  float* xbc  = (float*)ws;  ws += (size_t)nr * CD * 4;
  float* xs   = (float*)ws;  ws += (size_t)nr * DI * 4;
  float* Bm   = (float*)ws;  ws += (size_t)nr * DS * 4;
  float* Cm   = (float*)ws;  ws += (size_t)nr * DS * 4;
  float* dtv  = (float*)ws;  ws += (size_t)nr * H_ * 4;
  float* cumA = (float*)ws;  ws += (size_t)H_ * nr * 4;
  float* Sbuf = (float*)ws;  ws += (size_t)nr * 6144;
  unsigned short* WinT  = (unsigned short*)ws; ws += (size_t)NPJ * DM * 2;
  unsigned short* WoutT = (unsigned short*)ws; ws += (size_t)DM * DI * 2;
  float* Scarry = (float*)ws;  ws += (size_t)H_ * DS * P_ * 4;
  float* halo   = (float*)ws;  ws += (size_t)2 * 3 * CD * 4;
  float* WdtT   = (float*)ws;  ws += (size_t)H_ * DM * 4;
  float* ytot = xbc;                                 // overlay: xbc dead after conv
  unsigned short* xb    = (unsigned short*)Sbuf;     // overlay: Sbuf dead until k_intra
  unsigned short* ynorm = (unsigned short*)xs;       // overlay: xs dead after k_inter

  k_transpose_cast<<<dim3(24, (NPJ + 31) / 32), 256, 0, stream>>>(W_in, WinT, DM, NPJ);
  k_transpose_cast<<<dim3(48, 24), 256, 0, stream>>>(W_out, WoutT, DI, DM);
  k_wdtT<<<(H_ * DM + 255) / 256, 256, 0, stream>>>(W_in, WdtT);

  for (int s = 0; s < S; ++s) {
    const int g = s % G;
    const size_t row0 = (size_t)s * nr;

    k_cast<<<nr * DM / 1024, 256, 0, stream>>>(x + row0 * DM, xb, nr * DM);
    k_gemm_t<128, 128, 64, 64><<<dim3(nr / 128, N1 / 128), 256, 0, stream>>>(
        xb, WinT, zseg, DI, DI, xbc, CD, DM);
    k_conv<<<dim3(7, nr), 256, 0, stream>>>(xbc, conv_w, conv_b, xs, Bm, Cm,
                                            halo + (g & 1) * (3 * CD),
                                            halo + ((g + 1) & 1) * (3 * CD), g);
    k_dt2<<<nr / 8, 192, 0, stream>>>(x, WdtT, dt_bias, dtv, (int)row0);
    k_cum<<<(H_ * NCseg + 255) / 256, 256, 0, stream>>>(dtv, A_log, cumA, NCseg);
    k_intra<<<dim3(NCseg, H_), 256, 0, stream>>>(xs, Bm, Cm, dtv, cumA, ytot, Sbuf, NCseg);
    k_chunkscan<<<dim3(16, H_), 64, 0, stream>>>(Sbuf, cumA, Scarry, g, NCseg);
    k_inter<<<dim3(NCseg, H_), 256, 0, stream>>>(xs, Cm, cumA, Sbuf, Dp, ytot, NCseg);
    k_rms<<<nr, 192, 0, stream>>>(zseg, ytot, norm_w, ynorm);
    k_gemm_t<64, 64, 16, 64><<<dim3(nr / 64, DM / 64), 256, 0, stream>>>(
        ynorm, WoutT, out + row0 * DM, DM, DM, out + row0 * DM, DM, DI);
  }
}

// Round 7
// 437.279 us; speedup vs baseline: 1.5654x; 1.0819x over previous
//
#include <hip/hip_runtime.h>

// ---- problem constants ----
#define B_   2
#define L_   4096
#define DM   768
#define DI   1536     // D_INNER
#define DS   64       // D_STATE
#define H_   24       // NHEADS
#define P_   64       // HEADDIM
#define CD   1664     // CONV_DIM
#define NPJ  3224     // D_IN_PROJ
#define N1   3200     // GEMM1 useful cols (z + xBC; dt cols done exactly in k_dt2)
#define Q_   64       // chunk length
#define SP   76       // LDS row stride (floats) for k_inter tiles
#define HS   72       // fp16 LDS row stride (halves): <=2-way conflicts
#define WDS  772      // k_dt2 LDS W stride
#define CROWS 16      // conv rows per thread

typedef short          bf16x8 __attribute__((ext_vector_type(8)));
typedef _Float16       f16x8  __attribute__((ext_vector_type(8)));
typedef unsigned short us8    __attribute__((ext_vector_type(8)));
typedef unsigned short us4    __attribute__((ext_vector_type(4)));
typedef float          f32x4  __attribute__((ext_vector_type(4)));

__device__ __forceinline__ unsigned short f2bf(float f) {
  unsigned u = __float_as_uint(f);
  u += 0x7fffu + ((u >> 16) & 1u);   // RNE
  return (unsigned short)(u >> 16);
}
__device__ __forceinline__ float bf2f(unsigned short u) {
  return __uint_as_float(((unsigned)u) << 16);
}
__device__ __forceinline__ float siluf(float x) { return x / (1.f + expf(-x)); }
__device__ __forceinline__ float softplusf(float x) { return (x > 20.f) ? x : log1pf(expf(x)); }

// async global->LDS, 16B per lane; LDS dest = uniform base + lane*16
__device__ __forceinline__ void gload16(const unsigned short* g, unsigned short* l) {
  __builtin_amdgcn_global_load_lds(
      (const __attribute__((address_space(1))) void*)g,
      (__attribute__((address_space(3))) void*)l, 16, 0, 0);
}

// ---------------- cast fp32 -> bf16 ----------------
__global__ void k_cast(const float* __restrict__ src, unsigned short* __restrict__ dst, int n)
{
  const int i = (blockIdx.x * 256 + threadIdx.x) * 4;
  if (i >= n) return;
  f32x4 v = *(const f32x4*)(src + i);
  us4 o;
#pragma unroll
  for (int q = 0; q < 4; ++q) o[q] = f2bf(v[q]);
  *(us4*)(dst + i) = o;
}

// ---------------- transpose + cast (R x C fp32) -> (C x R bf16) ----------------
__global__ __launch_bounds__(256)
void k_transpose_cast(const float* __restrict__ src, unsigned short* __restrict__ dst,
                      int R, int C)
{
  __shared__ float tile[32][33];
  const int tx = threadIdx.x & 31, ty = threadIdx.x >> 5;
  const int r0 = blockIdx.x * 32, c0 = blockIdx.y * 32;
#pragma unroll
  for (int r = 0; r < 4; ++r) {
    int rr = r0 + ty + r * 8, cc = c0 + tx;
    if (rr < R && cc < C) tile[ty + r * 8][tx] = src[(size_t)rr * C + cc];
  }
  __syncthreads();
#pragma unroll
  for (int r = 0; r < 4; ++r) {
    int orow = c0 + ty + r * 8, ocol = r0 + tx;
    if (orow < C && ocol < R) dst[(size_t)orow * R + ocol] = f2bf(tile[tx][ty + r * 8]);
  }
}

// ---------------- gather dt columns of W_in -> contiguous fp32 WdtT[24][768] ----------------
__global__ void k_wdtT(const float* __restrict__ W_in, float* __restrict__ WdtT)
{
  const int idx = blockIdx.x * 256 + threadIdx.x;
  if (idx >= H_ * DM) return;
  const int k = idx / H_, h = idx % H_;
  WdtT[(size_t)h * DM + k] = W_in[(size_t)k * NPJ + N1 + h];
}

// ---------------- bf16 MFMA GEMM, BK=64, XOR-swizzled LDS (conflict-free) ----------------
// C(MxN) = A(MxK) @ Bt(NxK)^T. cols [0,ncol0) -> C0 (ld0); rest -> C1 (ld1).
// Output dtype: bf16 if OUT_BF16 else fp32.
template<int BM, int BN, int WM, int WN, bool OUT_BF16>
__global__ __launch_bounds__(256)
void k_gemm_t(const unsigned short* __restrict__ A, const unsigned short* __restrict__ Bt,
              void* __restrict__ C0v, int ld0, int ncol0,
              void* __restrict__ C1v, int ld1, int K)
{
  constexpr int MI = WM / 16, NI = WN / 16;
  constexpr int WAVES_N = BN / WN;
  constexpr int RA = BM / 32, RB = BN / 32;
  const int m0 = blockIdx.x * BM, n0 = blockIdx.y * BN;
  __shared__ unsigned short As[BM][64];
  __shared__ unsigned short Bs[BN][64];
  const int tid  = threadIdx.x;
  const int wave = tid >> 6, lane = tid & 63;
  const int quad = lane >> 4, r16 = lane & 15;
  const int wm = (wave / WAVES_N) * WM, wn = (wave % WAVES_N) * WN;

  const int lr8 = lane >> 3;                                // 0..7 row-in-band
  const int csw = ((lane & 7) ^ lr8) * 8;                   // swizzled source col (shorts)
  const unsigned short* gA = A  + (size_t)(m0 + wave * 8 + lr8) * K + csw;
  const unsigned short* gB = Bt + (size_t)(n0 + wave * 8 + lr8) * K + csw;
  unsigned short* lA = &As[wave * 8][0] + (size_t)lane * 8; // +lane*16B
  unsigned short* lB = &Bs[wave * 8][0] + (size_t)lane * 8;

  f32x4 acc[MI][NI];
#pragma unroll
  for (int mi = 0; mi < MI; ++mi)
#pragma unroll
    for (int ni = 0; ni < NI; ++ni) acc[mi][ni] = (f32x4){0.f, 0.f, 0.f, 0.f};

  for (int k0 = 0; k0 < K; k0 += 64) {
#pragma unroll
    for (int r = 0; r < RA; ++r)
      gload16(gA + (size_t)(r * 32) * K + k0, lA + (size_t)r * 32 * 64);
#pragma unroll
    for (int r = 0; r < RB; ++r)
      gload16(gB + (size_t)(r * 32) * K + k0, lB + (size_t)r * 32 * 64);
    __syncthreads();
    bf16x8 af[MI][2], bfr[NI][2];
#pragma unroll
    for (int mi = 0; mi < MI; ++mi)
#pragma unroll
      for (int ks = 0; ks < 2; ++ks)
        af[mi][ks] = *(const bf16x8*)&As[wm + mi * 16 + r16][((quad + ks * 4) ^ (r16 & 7)) * 8];
#pragma unroll
    for (int ni = 0; ni < NI; ++ni)
#pragma unroll
      for (int ks = 0; ks < 2; ++ks)
        bfr[ni][ks] = *(const bf16x8*)&Bs[wn + ni * 16 + r16][((quad + ks * 4) ^ (r16 & 7)) * 8];
#pragma unroll
    for (int mi = 0; mi < MI; ++mi)
#pragma unroll
      for (int ni = 0; ni < NI; ++ni)
#pragma unroll
        for (int ks = 0; ks < 2; ++ks)
          acc[mi][ni] = __builtin_amdgcn_mfma_f32_16x16x32_bf16(
              af[mi][ks], bfr[ni][ks], acc[mi][ni], 0, 0, 0);
    __syncthreads();
  }
#pragma unroll
  for (int mi = 0; mi < MI; ++mi)
#pragma unroll
    for (int ni = 0; ni < NI; ++ni) {
      int col = n0 + wn + ni * 16 + r16;
      void* dst; int ld, c;
      if (col < ncol0) { dst = C0v; ld = ld0; c = col; }
      else             { dst = C1v; ld = ld1; c = col - ncol0; }
#pragma unroll
      for (int r = 0; r < 4; ++r) {
        int row = m0 + wm + mi * 16 + quad * 4 + r;
        if (OUT_BF16) ((unsigned short*)dst)[(size_t)row * ld + c] = f2bf(acc[mi][ni][r]);
        else          ((float*)dst)[(size_t)row * ld + c] = acc[mi][ni][r];
      }
    }
}

// ---------------- save last 3 raw xbc rows (bf16) for next segment ----------------
__global__ void k_halo(const unsigned short* __restrict__ src, unsigned short* __restrict__ dst)
{
  const int i = blockIdx.x * 256 + threadIdx.x;
  if (i < 3 * CD) dst[i] = src[i];
}

// ---------------- depthwise conv(4) + silu: sliding window, each input read once ----------------
__global__ __launch_bounds__(256)
void k_conv2(const unsigned short* __restrict__ xbc, const float* __restrict__ cw,
             const float* __restrict__ cb, float* __restrict__ xs,
             float* __restrict__ Bm, float* __restrict__ Cm,
             const unsigned short* __restrict__ halo, int g)
{
  const int ch = blockIdx.x * 256 + threadIdx.x;
  if (ch >= CD) return;
  const int r0 = blockIdx.y * CROWS;
  const float w0 = cw[ch * 4], w1 = cw[ch * 4 + 1], w2 = cw[ch * 4 + 2], w3 = cw[ch * 4 + 3];
  const float bias = cb[ch];
  float a, b, c;
  if (r0 == 0) {
    if (g > 0) { a = bf2f(halo[ch]); b = bf2f(halo[CD + ch]); c = bf2f(halo[2 * CD + ch]); }
    else       { a = 0.f; b = 0.f; c = 0.f; }
  } else {
    a = bf2f(xbc[(size_t)(r0 - 3) * CD + ch]);
    b = bf2f(xbc[(size_t)(r0 - 2) * CD + ch]);
    c = bf2f(xbc[(size_t)(r0 - 1) * CD + ch]);
  }
#pragma unroll
  for (int i = 0; i < CROWS; ++i) {
    const int lr = r0 + i;
    float d = bf2f(xbc[(size_t)lr * CD + ch]);
    float v = siluf(bias + a * w0 + b * w1 + c * w2 + d * w3);
    a = b; b = c; c = d;
    if (ch < DI)           xs[(size_t)lr * DI + ch] = v;
    else if (ch < DI + DS) Bm[(size_t)lr * DS + (ch - DI)] = v;
    else                   Cm[(size_t)lr * DS + (ch - DI - DS)] = v;
  }
}

// ---------------- exact fp32 dt via LDS-staged WdtT ----------------
__global__ __launch_bounds__(192)
void k_dt2(const float* __restrict__ x, const float* __restrict__ WdtT,
           const float* __restrict__ dt_bias, float* __restrict__ dtv, int row0)
{
  __shared__ float sW[H_][WDS];
  for (int i = threadIdx.x; i < H_ * DM; i += 192)
    sW[i / DM][i % DM] = WdtT[i];
  const int h = threadIdx.x % H_, rloc = threadIdx.x / H_;
  const int lrow = blockIdx.x * 8 + rloc;
  const float* xr = x + (size_t)(row0 + lrow) * DM;
  __syncthreads();
  float acc = 0.f;
#pragma unroll 8
  for (int k = 0; k < DM; k += 4) {
    f32x4 xv = *(const f32x4*)(xr + k);
    f32x4 wv = *(const f32x4*)&sW[h][k];
    acc += xv[0] * wv[0] + xv[1] * wv[1] + xv[2] * wv[2] + xv[3] * wv[3];
  }
  dtv[(size_t)lrow * H_ + h] = softplusf(acc + dt_bias[h]);
}

// ---------------- per-chunk inclusive cumsum of dt*A ----------------
__global__ void k_cum(const float* __restrict__ dtv, const float* __restrict__ A_log,
                      float* __restrict__ cumA, int NCseg)
{
  const int idx = blockIdx.x * 256 + threadIdx.x;      // h*NCseg + c
  if (idx >= H_ * NCseg) return;
  const int c = idx % NCseg;
  const int h = idx / NCseg;
  const float A = -expf(A_log[h]);
  float cum = 0.f;
  const int rowbase = c * Q_;
  float* outp = cumA + (size_t)idx * Q_;
  for (int i = 0; i < Q_; ++i) {
    cum += dtv[(size_t)(rowbase + i) * H_ + h] * A;
    outp[i] = cum;
  }
}

// ---------------- intra-chunk via fp16 MFMA ----------------
__global__ __launch_bounds__(256)
void k_intra(const float* __restrict__ xs, const float* __restrict__ Bm,
             const float* __restrict__ Cm, const float* __restrict__ dtv,
             const float* __restrict__ cumA, float* __restrict__ ytot,
             float* __restrict__ Sbuf, int NCseg)
{
  const int c = blockIdx.x, h = blockIdx.y;
  __shared__ _Float16 sCW[Q_][HS];   // C, then W
  __shared__ _Float16 sB [Q_][HS];
  __shared__ _Float16 sBT[Q_][HS];   // (coef_j * B[j][n]) transposed -> [n][j]
  __shared__ _Float16 sXT[Q_][HS];   // X transposed -> [p][j]
  __shared__ float scum[Q_], sdt[Q_];
  const int tid = threadIdx.x;
  const int rowbase = c * Q_;

  {
    const int j = tid >> 2, s16 = (tid & 3) * 16;
    if (tid < Q_) {
      scum[tid] = cumA[((size_t)(h * NCseg + c)) * Q_ + tid];
      sdt[tid]  = dtv[(size_t)(rowbase + tid) * H_ + h];
    }
    f32x4 xv[4], bv[4], cv[4];
    const float* xsrc = xs + (size_t)(rowbase + j) * DI + h * P_ + s16;
    const float* bsrc = Bm + (size_t)(rowbase + j) * DS + s16;
    const float* csrc = Cm + (size_t)(rowbase + j) * DS + s16;
#pragma unroll
    for (int q = 0; q < 4; ++q) {
      xv[q] = *(const f32x4*)(xsrc + q * 4);
      bv[q] = *(const f32x4*)(bsrc + q * 4);
      cv[q] = *(const f32x4*)(csrc + q * 4);
    }
    __syncthreads();
    const float coef = expf(scum[Q_ - 1] - scum[j]) * sdt[j];
    union { f16x8 v; _Float16 e[8]; } pc[2], pb[2];
#pragma unroll
    for (int q = 0; q < 4; ++q)
#pragma unroll
      for (int e = 0; e < 4; ++e) {
        int o = q * 4 + e;
        pc[o >> 3].e[o & 7] = (_Float16)cv[q][e];
        pb[o >> 3].e[o & 7] = (_Float16)bv[q][e];
        sBT[s16 + o][j] = (_Float16)(bv[q][e] * coef);
        sXT[s16 + o][j] = (_Float16)xv[q][e];
      }
    *(f16x8*)&sCW[j][s16]     = pc[0].v;
    *(f16x8*)&sCW[j][s16 + 8] = pc[1].v;
    *(f16x8*)&sB [j][s16]     = pb[0].v;
    *(f16x8*)&sB [j][s16 + 8] = pb[1].v;
  }
  __syncthreads();

  const int wave = tid >> 6, lane = tid & 63;
  const int quad = lane >> 4, r16 = lane & 15;
  const int i0 = wave * 16;
  const int irow = i0 + quad * 4;

  f32x4 g[4];
#pragma unroll
  for (int q = 0; q < 4; ++q) g[q] = (f32x4){0.f, 0.f, 0.f, 0.f};
#pragma unroll
  for (int ni = 0; ni < 4; ++ni) {
    if (ni <= wave) {
#pragma unroll
      for (int ks = 0; ks < 2; ++ks)
        g[ni] = __builtin_amdgcn_mfma_f32_16x16x32_f16(
            *(const f16x8*)&sCW[i0 + r16][ks * 32 + quad * 8],
            *(const f16x8*)&sB [ni * 16 + r16][ks * 32 + quad * 8], g[ni], 0, 0, 0);
    }
  }
  float wv[4][4];
#pragma unroll
  for (int ni = 0; ni < 4; ++ni)
#pragma unroll
    for (int r = 0; r < 4; ++r) {
      int i = irow + r, jcol = ni * 16 + r16;
      float v = 0.f;
      if (ni <= wave && jcol <= i)
        v = g[ni][r] * expf(scum[i] - scum[jcol]) * sdt[jcol];
      wv[ni][r] = v;
    }
  __syncthreads();
#pragma unroll
  for (int ni = 0; ni < 4; ++ni)
#pragma unroll
    for (int r = 0; r < 4; ++r)
      sCW[irow + r][ni * 16 + r16] = (_Float16)wv[ni][r];
  __syncthreads();

  f32x4 y[4];
#pragma unroll
  for (int q = 0; q < 4; ++q) y[q] = (f32x4){0.f, 0.f, 0.f, 0.f};
#pragma unroll
  for (int ni = 0; ni < 4; ++ni)
#pragma unroll
    for (int ks = 0; ks < 2; ++ks) {
      if (ks == 0 || wave >= 2)
        y[ni] = __builtin_amdgcn_mfma_f32_16x16x32_f16(
            *(const f16x8*)&sCW[i0 + r16][ks * 32 + quad * 8],
            *(const f16x8*)&sXT[ni * 16 + r16][ks * 32 + quad * 8], y[ni], 0, 0, 0);
    }
#pragma unroll
  for (int ni = 0; ni < 4; ++ni)
#pragma unroll
    for (int r = 0; r < 4; ++r)
      ytot[(size_t)(rowbase + irow + r) * DI + h * P_ + ni * 16 + r16] = y[ni][r];

  f32x4 t4[4];
#pragma unroll
  for (int q = 0; q < 4; ++q) t4[q] = (f32x4){0.f, 0.f, 0.f, 0.f};
#pragma unroll
  for (int ni = 0; ni < 4; ++ni)
#pragma unroll
    for (int ks = 0; ks < 2; ++ks)
      t4[ni] = __builtin_amdgcn_mfma_f32_16x16x32_f16(
          *(const f16x8*)&sBT[i0 + r16][ks * 32 + quad * 8],
          *(const f16x8*)&sXT[ni * 16 + r16][ks * 32 + quad * 8], t4[ni], 0, 0, 0);
  float* sp = Sbuf + ((size_t)(h * NCseg + c)) * (DS * P_);
#pragma unroll
  for (int ni = 0; ni < 4; ++ni)
#pragma unroll
    for (int r = 0; r < 4; ++r)
      sp[(irow + r) * P_ + ni * 16 + r16] = t4[ni][r];
}

// ---------------- sequential inter-chunk recurrence (in-place: T -> S_prev) ----------------
__global__ void k_chunkscan(float* __restrict__ Sbuf, const float* __restrict__ cumA,
                            float* __restrict__ Scarry, int g, int NCseg)
{
  const int seg = blockIdx.x, h = blockIdx.y;
  __shared__ float dec[Q_];
  const int tid = threadIdx.x;
  if (tid < NCseg) dec[tid] = expf(cumA[((size_t)(h * NCseg + tid)) * Q_ + (Q_ - 1)]);
  __syncthreads();
  const size_t off = (size_t)seg * 256 + (size_t)tid * 4;
  float* carry = Scarry + (size_t)h * (DS * P_) + off;
  f32x4 s;
  if (g > 0) s = *(const f32x4*)carry;
  else       s = (f32x4){0.f, 0.f, 0.f, 0.f};
  size_t base = (size_t)h * NCseg * (DS * P_) + off;
  for (int c = 0; c < NCseg; ++c) {
    float* p = Sbuf + base + (size_t)c * (DS * P_);
    f32x4 v = *(const f32x4*)p;
    *(f32x4*)p = s;               // store state BEFORE chunk c
    s = s * dec[c] + v;
  }
  *(f32x4*)carry = s;
}

// ---------------- inter-chunk correction + D*x ----------------
__global__ __launch_bounds__(256)
void k_inter(const float* __restrict__ xs, const float* __restrict__ Cm,
             const float* __restrict__ cumA, const float* __restrict__ Sbuf,
             const float* __restrict__ Dp, float* __restrict__ ytot, int NCseg)
{
  const int c = blockIdx.x, h = blockIdx.y;
  __shared__ float sS[DS][SP];
  __shared__ float sC[Q_][SP];
  __shared__ float scum[Q_];
  const int tid = threadIdx.x;
  const int jr = tid >> 2, blk = (tid & 3) * 16;
  const int rowbase = c * Q_;
  {
    const float* ssrc = Sbuf + ((size_t)(h * NCseg + c)) * (DS * P_) + jr * P_ + blk;
    const float* csrc = Cm + (size_t)(rowbase + jr) * DS + blk;
#pragma unroll
    for (int q = 0; q < 4; ++q) {
      *(f32x4*)&sS[jr][blk + q * 4] = *(const f32x4*)(ssrc + q * 4);
      *(f32x4*)&sC[jr][blk + q * 4] = *(const f32x4*)(csrc + q * 4);
    }
    if (tid < Q_) scum[tid] = cumA[((size_t)(h * NCseg + c)) * Q_ + tid];
  }
  __syncthreads();
  const int i = jr;
  f32x4 acc[4];
#pragma unroll
  for (int q = 0; q < 4; ++q) acc[q] = (f32x4){0.f, 0.f, 0.f, 0.f};
  for (int n = 0; n < DS; ++n) {
    float cv = sC[i][n];
#pragma unroll
    for (int q = 0; q < 4; ++q) acc[q] += cv * *(const f32x4*)&sS[n][blk + q * 4];
  }
  const float e = expf(scum[i]);
  const float Dh = Dp[h];
  float* yt = ytot + (size_t)(rowbase + i) * DI + h * P_ + blk;
  const float* xsr = xs + (size_t)(rowbase + i) * DI + h * P_ + blk;
#pragma unroll
  for (int q = 0; q < 4; ++q) {
    f32x4 cur = *(const f32x4*)(yt + q * 4);
    f32x4 xv  = *(const f32x4*)(xsr + q * 4);
    cur += e * acc[q] + Dh * xv;
    *(f32x4*)(yt + q * 4) = cur;
  }
}

// ---------------- gate (silu(z)) + RMSNorm + cast bf16 ----------------
__global__ __launch_bounds__(192)
void k_rms(const unsigned short* __restrict__ z, const float* __restrict__ ytot,
           const float* __restrict__ norm_w, unsigned short* __restrict__ ynorm)
{
  const int row = blockIdx.x, tid = threadIdx.x;
  const int e0 = tid * 8;
  us8 zv = *(const us8*)(z + (size_t)row * DI + e0);
  const float* yr = ytot + (size_t)row * DI;
  f32x4 yv0 = *(const f32x4*)(yr + e0);
  f32x4 yv1 = *(const f32x4*)(yr + e0 + 4);
  float g[8];
  float ss = 0.f;
#pragma unroll
  for (int q = 0; q < 8; ++q) {
    float yq = (q < 4) ? yv0[q] : yv1[q - 4];
    g[q] = yq * siluf(bf2f(zv[q]));
    ss += g[q] * g[q];
  }
#pragma unroll
  for (int off = 32; off > 0; off >>= 1) ss += __shfl_down(ss, off);
  __shared__ float wsum[3];
  __shared__ float sscale;
  if ((tid & 63) == 0) wsum[tid >> 6] = ss;
  __syncthreads();
  if (tid == 0) sscale = rsqrtf((wsum[0] + wsum[1] + wsum[2]) * (1.f / DI) + 1e-5f);
  __syncthreads();
  const float sc = sscale;
  us8 o;
#pragma unroll
  for (int q = 0; q < 8; ++q) o[q] = f2bf(g[q] * sc * norm_w[e0 + q]);
  *(us8*)(ynorm + (size_t)row * DI + e0) = o;
}

extern "C" void kernel_launch(void* const* d_in, const int* in_sizes, int n_in,
                              void* d_out, int out_size, void* d_ws, size_t ws_size,
                              hipStream_t stream)
{
  (void)in_sizes; (void)n_in; (void)out_size;
  const float* x       = (const float*)d_in[0];
  const float* W_in    = (const float*)d_in[1];
  const float* conv_w  = (const float*)d_in[2];
  const float* conv_b  = (const float*)d_in[3];
  const float* dt_bias = (const float*)d_in[4];
  const float* A_log   = (const float*)d_in[5];
  const float* Dp      = (const float*)d_in[6];
  const float* norm_w  = (const float*)d_in[7];
  const float* W_out   = (const float*)d_in[8];
  float* out = (float*)d_out;

  // ---- pick largest segment size that fits ws_size ----
  // footprint(nr) = nr*25536 + fixed 7,798,272
  int nr = 512;
  {
    const int cands[4] = {4096, 2048, 1024, 512};
    for (int ci = 0; ci < 4; ++ci) {
      size_t need = (size_t)cands[ci] * 25536 + 7798272;
      if (need <= ws_size) { nr = cands[ci]; break; }
    }
  }
  const int G = L_ / nr;          // segments per batch
  const int S = B_ * G;           // total segments
  const int NCseg = nr / Q_;      // chunks per segment

  // ---- workspace layout ----
  char* ws = (char*)d_ws;
  unsigned short* zseg = (unsigned short*)ws;  ws += (size_t)nr * DI * 2;   // bf16 z
  unsigned short* xbc  = (unsigned short*)ws;  ws += (size_t)nr * CD * 2;   // bf16 xBC
  float* xs   = (float*)ws;  ws += (size_t)nr * DI * 4;
  float* ytot = (float*)ws;  ws += (size_t)nr * DI * 4;
  float* Bm   = (float*)ws;  ws += (size_t)nr * DS * 4;
  float* Cm   = (float*)ws;  ws += (size_t)nr * DS * 4;
  float* dtv  = (float*)ws;  ws += (size_t)nr * H_ * 4;
  float* cumA = (float*)ws;  ws += (size_t)H_ * nr * 4;
  float* Sbuf = (float*)ws;  ws += (size_t)nr * 6144;
  unsigned short* WinT  = (unsigned short*)ws; ws += (size_t)NPJ * DM * 2;
  unsigned short* WoutT = (unsigned short*)ws; ws += (size_t)DM * DI * 2;
  float* Scarry = (float*)ws;  ws += (size_t)H_ * DS * P_ * 4;
  unsigned short* halo = (unsigned short*)ws;  ws += (size_t)2 * 3 * CD * 2;
  float* WdtT   = (float*)ws;  ws += (size_t)H_ * DM * 4;
  unsigned short* xb    = (unsigned short*)Sbuf;     // overlay: Sbuf dead until k_intra
  unsigned short* ynorm = (unsigned short*)xs;       // overlay: xs dead after k_inter

  k_transpose_cast<<<dim3(24, (NPJ + 31) / 32), 256, 0, stream>>>(W_in, WinT, DM, NPJ);
  k_transpose_cast<<<dim3(48, 24), 256, 0, stream>>>(W_out, WoutT, DI, DM);
  k_wdtT<<<(H_ * DM + 255) / 256, 256, 0, stream>>>(W_in, WdtT);

  for (int s = 0; s < S; ++s) {
    const int g = s % G;
    const size_t row0 = (size_t)s * nr;

    k_cast<<<nr * DM / 1024, 256, 0, stream>>>(x + row0 * DM, xb, nr * DM);
    k_gemm_t<128, 128, 64, 64, true><<<dim3(nr / 128, N1 / 128), 256, 0, stream>>>(
        xb, WinT, zseg, DI, DI, xbc, CD, DM);
    k_halo<<<20, 256, 0, stream>>>(xbc + (size_t)(nr - 3) * CD,
                                   halo + ((g + 1) & 1) * (3 * CD));
    k_conv2<<<dim3(7, nr / CROWS), 256, 0, stream>>>(xbc, conv_w, conv_b, xs, Bm, Cm,
                                                     halo + (g & 1) * (3 * CD), g);
    k_dt2<<<nr / 8, 192, 0, stream>>>(x, WdtT, dt_bias, dtv, (int)row0);
    k_cum<<<(H_ * NCseg + 255) / 256, 256, 0, stream>>>(dtv, A_log, cumA, NCseg);
    k_intra<<<dim3(NCseg, H_), 256, 0, stream>>>(xs, Bm, Cm, dtv, cumA, ytot, Sbuf, NCseg);
    k_chunkscan<<<dim3(16, H_), 64, 0, stream>>>(Sbuf, cumA, Scarry, g, NCseg);
    k_inter<<<dim3(NCseg, H_), 256, 0, stream>>>(xs, Cm, cumA, Sbuf, Dp, ytot, NCseg);
    k_rms<<<nr, 192, 0, stream>>>(zseg, ytot, norm_w, ynorm);
    k_gemm_t<64, 64, 16, 64, false><<<dim3(nr / 64, DM / 64), 256, 0, stream>>>(
        ynorm, WoutT, out + row0 * DM, DM, DM, out + row0 * DM, DM, DI);
  }
}

// Round 8
// 364.941 us; speedup vs baseline: 1.8757x; 1.1982x over previous
//
#include <hip/hip_runtime.h>

// ---- problem constants ----
#define B_   2
#define L_   4096
#define DM   768
#define DI   1536     // D_INNER
#define DS   64       // D_STATE
#define H_   24       // NHEADS
#define P_   64       // HEADDIM
#define CD   1664     // CONV_DIM
#define NPJ  3224     // D_IN_PROJ
#define N1   3200     // GEMM1 useful cols (z + xBC; dt cols done exactly in k_dt2)
#define Q_   64       // chunk length
#define NC   64       // chunks per batch
#define SP   76       // LDS row stride (floats) for k_inter tiles
#define HS   72       // fp16 LDS row stride (halves): <=2-way conflicts
#define WDS  772      // k_dt2 LDS W stride
#define CROWS 16      // conv rows per thread

typedef short          bf16x8 __attribute__((ext_vector_type(8)));
typedef _Float16       f16x8  __attribute__((ext_vector_type(8)));
typedef unsigned short us8    __attribute__((ext_vector_type(8)));
typedef unsigned short us4    __attribute__((ext_vector_type(4)));
typedef float          f32x4  __attribute__((ext_vector_type(4)));

__device__ __forceinline__ unsigned short f2bf(float f) {
  unsigned u = __float_as_uint(f);
  u += 0x7fffu + ((u >> 16) & 1u);   // RNE
  return (unsigned short)(u >> 16);
}
__device__ __forceinline__ float bf2f(unsigned short u) {
  return __uint_as_float(((unsigned)u) << 16);
}
__device__ __forceinline__ float siluf(float x) { return x / (1.f + expf(-x)); }
__device__ __forceinline__ float softplusf(float x) { return (x > 20.f) ? x : log1pf(expf(x)); }

// async global->LDS, 16B per lane; LDS dest = uniform base + lane*16
__device__ __forceinline__ void gload16(const unsigned short* g, unsigned short* l) {
  __builtin_amdgcn_global_load_lds(
      (const __attribute__((address_space(1))) void*)g,
      (__attribute__((address_space(3))) void*)l, 16, 0, 0);
}

// ---------------- cast fp32 -> bf16 ----------------
__global__ void k_cast(const float* __restrict__ src, unsigned short* __restrict__ dst, int n)
{
  const int i = (blockIdx.x * 256 + threadIdx.x) * 4;
  if (i >= n) return;
  f32x4 v = *(const f32x4*)(src + i);
  us4 o;
#pragma unroll
  for (int q = 0; q < 4; ++q) o[q] = f2bf(v[q]);
  *(us4*)(dst + i) = o;
}

// ---------------- transpose + cast (R x C fp32) -> (C x R bf16) ----------------
__global__ __launch_bounds__(256)
void k_transpose_cast(const float* __restrict__ src, unsigned short* __restrict__ dst,
                      int R, int C)
{
  __shared__ float tile[32][33];
  const int tx = threadIdx.x & 31, ty = threadIdx.x >> 5;
  const int r0 = blockIdx.x * 32, c0 = blockIdx.y * 32;
#pragma unroll
  for (int r = 0; r < 4; ++r) {
    int rr = r0 + ty + r * 8, cc = c0 + tx;
    if (rr < R && cc < C) tile[ty + r * 8][tx] = src[(size_t)rr * C + cc];
  }
  __syncthreads();
#pragma unroll
  for (int r = 0; r < 4; ++r) {
    int orow = c0 + ty + r * 8, ocol = r0 + tx;
    if (orow < C && ocol < R) dst[(size_t)orow * R + ocol] = f2bf(tile[tx][ty + r * 8]);
  }
}

// ---------------- gather dt columns of W_in -> contiguous fp32 WdtT[24][768] ----------------
__global__ void k_wdtT(const float* __restrict__ W_in, float* __restrict__ WdtT)
{
  const int idx = blockIdx.x * 256 + threadIdx.x;
  if (idx >= H_ * DM) return;
  const int k = idx / H_, h = idx % H_;
  WdtT[(size_t)h * DM + k] = W_in[(size_t)k * NPJ + N1 + h];
}

// ---------------- bf16 MFMA GEMM, BK=64, XOR-swizzled LDS (conflict-free) ----------------
template<int BM, int BN, int WM, int WN, bool OUT_BF16>
__global__ __launch_bounds__(256)
void k_gemm_t(const unsigned short* __restrict__ A, const unsigned short* __restrict__ Bt,
              void* __restrict__ C0v, int ld0, int ncol0,
              void* __restrict__ C1v, int ld1, int K)
{
  constexpr int MI = WM / 16, NI = WN / 16;
  constexpr int WAVES_N = BN / WN;
  constexpr int RA = BM / 32, RB = BN / 32;
  const int m0 = blockIdx.x * BM, n0 = blockIdx.y * BN;
  __shared__ unsigned short As[BM][64];
  __shared__ unsigned short Bs[BN][64];
  const int tid  = threadIdx.x;
  const int wave = tid >> 6, lane = tid & 63;
  const int quad = lane >> 4, r16 = lane & 15;
  const int wm = (wave / WAVES_N) * WM, wn = (wave % WAVES_N) * WN;

  const int lr8 = lane >> 3;                                // 0..7 row-in-band
  const int csw = ((lane & 7) ^ lr8) * 8;                   // swizzled source col (shorts)
  const unsigned short* gA = A  + (size_t)(m0 + wave * 8 + lr8) * K + csw;
  const unsigned short* gB = Bt + (size_t)(n0 + wave * 8 + lr8) * K + csw;
  unsigned short* lA = &As[wave * 8][0] + (size_t)lane * 8; // +lane*16B
  unsigned short* lB = &Bs[wave * 8][0] + (size_t)lane * 8;

  f32x4 acc[MI][NI];
#pragma unroll
  for (int mi = 0; mi < MI; ++mi)
#pragma unroll
    for (int ni = 0; ni < NI; ++ni) acc[mi][ni] = (f32x4){0.f, 0.f, 0.f, 0.f};

  for (int k0 = 0; k0 < K; k0 += 64) {
#pragma unroll
    for (int r = 0; r < RA; ++r)
      gload16(gA + (size_t)(r * 32) * K + k0, lA + (size_t)r * 32 * 64);
#pragma unroll
    for (int r = 0; r < RB; ++r)
      gload16(gB + (size_t)(r * 32) * K + k0, lB + (size_t)r * 32 * 64);
    __syncthreads();
    bf16x8 af[MI][2], bfr[NI][2];
#pragma unroll
    for (int mi = 0; mi < MI; ++mi)
#pragma unroll
      for (int ks = 0; ks < 2; ++ks)
        af[mi][ks] = *(const bf16x8*)&As[wm + mi * 16 + r16][((quad + ks * 4) ^ (r16 & 7)) * 8];
#pragma unroll
    for (int ni = 0; ni < NI; ++ni)
#pragma unroll
      for (int ks = 0; ks < 2; ++ks)
        bfr[ni][ks] = *(const bf16x8*)&Bs[wn + ni * 16 + r16][((quad + ks * 4) ^ (r16 & 7)) * 8];
#pragma unroll
    for (int mi = 0; mi < MI; ++mi)
#pragma unroll
      for (int ni = 0; ni < NI; ++ni)
#pragma unroll
        for (int ks = 0; ks < 2; ++ks)
          acc[mi][ni] = __builtin_amdgcn_mfma_f32_16x16x32_bf16(
              af[mi][ks], bfr[ni][ks], acc[mi][ni], 0, 0, 0);
    __syncthreads();
  }
#pragma unroll
  for (int mi = 0; mi < MI; ++mi)
#pragma unroll
    for (int ni = 0; ni < NI; ++ni) {
      int col = n0 + wn + ni * 16 + r16;
      void* dst; int ld, c;
      if (col < ncol0) { dst = C0v; ld = ld0; c = col; }
      else             { dst = C1v; ld = ld1; c = col - ncol0; }
#pragma unroll
      for (int r = 0; r < 4; ++r) {
        int row = m0 + wm + mi * 16 + quad * 4 + r;
        if (OUT_BF16) ((unsigned short*)dst)[(size_t)row * ld + c] = f2bf(acc[mi][ni][r]);
        else          ((float*)dst)[(size_t)row * ld + c] = acc[mi][ni][r];
      }
    }
}

// ---------------- depthwise conv(4) + silu: sliding window, batch-boundary aware ----------------
// xs written as fp16; Bm/Cm fp32.
__global__ __launch_bounds__(256)
void k_conv2(const unsigned short* __restrict__ xbc, const float* __restrict__ cw,
             const float* __restrict__ cb, _Float16* __restrict__ xs,
             float* __restrict__ Bm, float* __restrict__ Cm)
{
  const int ch = blockIdx.x * 256 + threadIdx.x;
  if (ch >= CD) return;
  const int r0 = blockIdx.y * CROWS;
  const float w0 = cw[ch * 4], w1 = cw[ch * 4 + 1], w2 = cw[ch * 4 + 2], w3 = cw[ch * 4 + 3];
  const float bias = cb[ch];
  float a, b, c;
  if ((r0 & (L_ - 1)) == 0) {                 // batch start: zero history
    a = 0.f; b = 0.f; c = 0.f;
  } else {
    a = bf2f(xbc[(size_t)(r0 - 3) * CD + ch]);
    b = bf2f(xbc[(size_t)(r0 - 2) * CD + ch]);
    c = bf2f(xbc[(size_t)(r0 - 1) * CD + ch]);
  }
#pragma unroll
  for (int i = 0; i < CROWS; ++i) {
    const int lr = r0 + i;
    float d = bf2f(xbc[(size_t)lr * CD + ch]);
    float v = siluf(bias + a * w0 + b * w1 + c * w2 + d * w3);
    a = b; b = c; c = d;
    if (ch < DI)           xs[(size_t)lr * DI + ch] = (_Float16)v;
    else if (ch < DI + DS) Bm[(size_t)lr * DS + (ch - DI)] = v;
    else                   Cm[(size_t)lr * DS + (ch - DI - DS)] = v;
  }
}

// ---------------- exact fp32 dt via LDS-staged WdtT ----------------
__global__ __launch_bounds__(192)
void k_dt2(const float* __restrict__ x, const float* __restrict__ WdtT,
           const float* __restrict__ dt_bias, float* __restrict__ dtv)
{
  __shared__ float sW[H_][WDS];
  for (int i = threadIdx.x; i < H_ * DM; i += 192)
    sW[i / DM][i % DM] = WdtT[i];
  const int h = threadIdx.x % H_, rloc = threadIdx.x / H_;
  const int lrow = blockIdx.x * 8 + rloc;
  const float* xr = x + (size_t)lrow * DM;
  __syncthreads();
  float acc = 0.f;
#pragma unroll 8
  for (int k = 0; k < DM; k += 4) {
    f32x4 xv = *(const f32x4*)(xr + k);
    f32x4 wv = *(const f32x4*)&sW[h][k];
    acc += xv[0] * wv[0] + xv[1] * wv[1] + xv[2] * wv[2] + xv[3] * wv[3];
  }
  dtv[(size_t)lrow * H_ + h] = softplusf(acc + dt_bias[h]);
}

// ---------------- per-chunk inclusive cumsum of dt*A ----------------
__global__ void k_cum(const float* __restrict__ dtv, const float* __restrict__ A_log,
                      float* __restrict__ cumA, int n)
{
  const int idx = blockIdx.x * 256 + threadIdx.x;      // ((bz*H+h)*NC + c)
  if (idx >= n) return;
  const int c = idx % NC;
  const int h = (idx / NC) % H_;
  const int bz = idx / (NC * H_);
  const float A = -expf(A_log[h]);
  float cum = 0.f;
  const int rowbase = bz * L_ + c * Q_;
  float* outp = cumA + (size_t)idx * Q_;
  for (int i = 0; i < Q_; ++i) {
    cum += dtv[(size_t)(rowbase + i) * H_ + h] * A;
    outp[i] = cum;
  }
}

// ---------------- intra-chunk via fp16 MFMA ----------------
__global__ __launch_bounds__(256)
void k_intra(const _Float16* __restrict__ xs, const float* __restrict__ Bm,
             const float* __restrict__ Cm, const float* __restrict__ dtv,
             const float* __restrict__ cumA, float* __restrict__ ytot,
             float* __restrict__ Sbuf)
{
  const int c = blockIdx.x, h = blockIdx.y, bz = blockIdx.z;
  const int gidx = (bz * H_ + h) * NC + c;
  __shared__ _Float16 sCW[Q_][HS];   // C, then W
  __shared__ _Float16 sB [Q_][HS];
  __shared__ _Float16 sBT[Q_][HS];   // (coef_j * B[j][n]) transposed -> [n][j]
  __shared__ _Float16 sXT[Q_][HS];   // X transposed -> [p][j]
  __shared__ float scum[Q_], sdt[Q_];
  const int tid = threadIdx.x;
  const int rowbase = bz * L_ + c * Q_;

  {
    const int j = tid >> 2, s16 = (tid & 3) * 16;
    if (tid < Q_) {
      scum[tid] = cumA[(size_t)gidx * Q_ + tid];
      sdt[tid]  = dtv[(size_t)(rowbase + tid) * H_ + h];
    }
    const _Float16* xsrc = xs + (size_t)(rowbase + j) * DI + h * P_ + s16;
    f16x8 xv0 = *(const f16x8*)xsrc;
    f16x8 xv1 = *(const f16x8*)(xsrc + 8);
    f32x4 bv[4], cv[4];
    const float* bsrc = Bm + (size_t)(rowbase + j) * DS + s16;
    const float* csrc = Cm + (size_t)(rowbase + j) * DS + s16;
#pragma unroll
    for (int q = 0; q < 4; ++q) {
      bv[q] = *(const f32x4*)(bsrc + q * 4);
      cv[q] = *(const f32x4*)(csrc + q * 4);
    }
    __syncthreads();
    const float coef = expf(scum[Q_ - 1] - scum[j]) * sdt[j];
    union { f16x8 v; _Float16 e[8]; } pc[2], pb[2];
#pragma unroll
    for (int q = 0; q < 4; ++q)
#pragma unroll
      for (int e = 0; e < 4; ++e) {
        int o = q * 4 + e;
        pc[o >> 3].e[o & 7] = (_Float16)cv[q][e];
        pb[o >> 3].e[o & 7] = (_Float16)bv[q][e];
        sBT[s16 + o][j] = (_Float16)(bv[q][e] * coef);
        sXT[s16 + o][j] = (o < 8) ? xv0[o] : xv1[o - 8];
      }
    *(f16x8*)&sCW[j][s16]     = pc[0].v;
    *(f16x8*)&sCW[j][s16 + 8] = pc[1].v;
    *(f16x8*)&sB [j][s16]     = pb[0].v;
    *(f16x8*)&sB [j][s16 + 8] = pb[1].v;
  }
  __syncthreads();

  const int wave = tid >> 6, lane = tid & 63;
  const int quad = lane >> 4, r16 = lane & 15;
  const int i0 = wave * 16;
  const int irow = i0 + quad * 4;

  f32x4 g[4];
#pragma unroll
  for (int q = 0; q < 4; ++q) g[q] = (f32x4){0.f, 0.f, 0.f, 0.f};
#pragma unroll
  for (int ni = 0; ni < 4; ++ni) {
    if (ni <= wave) {
#pragma unroll
      for (int ks = 0; ks < 2; ++ks)
        g[ni] = __builtin_amdgcn_mfma_f32_16x16x32_f16(
            *(const f16x8*)&sCW[i0 + r16][ks * 32 + quad * 8],
            *(const f16x8*)&sB [ni * 16 + r16][ks * 32 + quad * 8], g[ni], 0, 0, 0);
    }
  }
  float wv[4][4];
#pragma unroll
  for (int ni = 0; ni < 4; ++ni)
#pragma unroll
    for (int r = 0; r < 4; ++r) {
      int i = irow + r, jcol = ni * 16 + r16;
      float v = 0.f;
      if (ni <= wave && jcol <= i)
        v = g[ni][r] * expf(scum[i] - scum[jcol]) * sdt[jcol];
      wv[ni][r] = v;
    }
  __syncthreads();
#pragma unroll
  for (int ni = 0; ni < 4; ++ni)
#pragma unroll
    for (int r = 0; r < 4; ++r)
      sCW[irow + r][ni * 16 + r16] = (_Float16)wv[ni][r];
  __syncthreads();

  f32x4 y[4];
#pragma unroll
  for (int q = 0; q < 4; ++q) y[q] = (f32x4){0.f, 0.f, 0.f, 0.f};
#pragma unroll
  for (int ni = 0; ni < 4; ++ni)
#pragma unroll
    for (int ks = 0; ks < 2; ++ks) {
      if (ks == 0 || wave >= 2)
        y[ni] = __builtin_amdgcn_mfma_f32_16x16x32_f16(
            *(const f16x8*)&sCW[i0 + r16][ks * 32 + quad * 8],
            *(const f16x8*)&sXT[ni * 16 + r16][ks * 32 + quad * 8], y[ni], 0, 0, 0);
    }
#pragma unroll
  for (int ni = 0; ni < 4; ++ni)
#pragma unroll
    for (int r = 0; r < 4; ++r)
      ytot[(size_t)(rowbase + irow + r) * DI + h * P_ + ni * 16 + r16] = y[ni][r];

  f32x4 t4[4];
#pragma unroll
  for (int q = 0; q < 4; ++q) t4[q] = (f32x4){0.f, 0.f, 0.f, 0.f};
#pragma unroll
  for (int ni = 0; ni < 4; ++ni)
#pragma unroll
    for (int ks = 0; ks < 2; ++ks)
      t4[ni] = __builtin_amdgcn_mfma_f32_16x16x32_f16(
          *(const f16x8*)&sBT[i0 + r16][ks * 32 + quad * 8],
          *(const f16x8*)&sXT[ni * 16 + r16][ks * 32 + quad * 8], t4[ni], 0, 0, 0);
  float* sp = Sbuf + (size_t)gidx * (DS * P_);
#pragma unroll
  for (int ni = 0; ni < 4; ++ni)
#pragma unroll
    for (int r = 0; r < 4; ++r)
      sp[(irow + r) * P_ + ni * 16 + r16] = t4[ni][r];
}

// ---------------- sequential inter-chunk recurrence (in-place: T -> S_prev) ----------------
__global__ void k_chunkscan(float* __restrict__ Sbuf, const float* __restrict__ cumA)
{
  const int seg = blockIdx.x, h = blockIdx.y, bz = blockIdx.z;
  const int bh = bz * H_ + h;
  __shared__ float dec[NC];
  const int tid = threadIdx.x;
  if (tid < NC) dec[tid] = expf(cumA[((size_t)(bh * NC + tid)) * Q_ + (Q_ - 1)]);
  __syncthreads();
  const size_t off = (size_t)seg * 256 + (size_t)tid * 4;
  f32x4 s = (f32x4){0.f, 0.f, 0.f, 0.f};
  size_t base = (size_t)bh * NC * (DS * P_) + off;
  for (int c = 0; c < NC; ++c) {
    float* p = Sbuf + base + (size_t)c * (DS * P_);
    f32x4 v = *(const f32x4*)p;
    *(f32x4*)p = s;               // store state BEFORE chunk c
    s = s * dec[c] + v;
  }
}

// ---------------- inter-chunk correction + D*x ----------------
__global__ __launch_bounds__(256)
void k_inter(const _Float16* __restrict__ xs, const float* __restrict__ Cm,
             const float* __restrict__ cumA, const float* __restrict__ Sbuf,
             const float* __restrict__ Dp, float* __restrict__ ytot)
{
  const int c = blockIdx.x, h = blockIdx.y, bz = blockIdx.z;
  const int gidx = (bz * H_ + h) * NC + c;
  __shared__ float sS[DS][SP];
  __shared__ float sC[Q_][SP];
  __shared__ float scum[Q_];
  const int tid = threadIdx.x;
  const int jr = tid >> 2, blk = (tid & 3) * 16;
  const int rowbase = bz * L_ + c * Q_;
  {
    const float* ssrc = Sbuf + (size_t)gidx * (DS * P_) + jr * P_ + blk;
    const float* csrc = Cm + (size_t)(rowbase + jr) * DS + blk;
#pragma unroll
    for (int q = 0; q < 4; ++q) {
      *(f32x4*)&sS[jr][blk + q * 4] = *(const f32x4*)(ssrc + q * 4);
      *(f32x4*)&sC[jr][blk + q * 4] = *(const f32x4*)(csrc + q * 4);
    }
    if (tid < Q_) scum[tid] = cumA[(size_t)gidx * Q_ + tid];
  }
  __syncthreads();
  const int i = jr;
  f32x4 acc[4];
#pragma unroll
  for (int q = 0; q < 4; ++q) acc[q] = (f32x4){0.f, 0.f, 0.f, 0.f};
  for (int n = 0; n < DS; ++n) {
    float cv = sC[i][n];
#pragma unroll
    for (int q = 0; q < 4; ++q) acc[q] += cv * *(const f32x4*)&sS[n][blk + q * 4];
  }
  const float e = expf(scum[i]);
  const float Dh = Dp[h];
  float* yt = ytot + (size_t)(rowbase + i) * DI + h * P_ + blk;
  const _Float16* xsr = xs + (size_t)(rowbase + i) * DI + h * P_ + blk;
  f16x8 xa = *(const f16x8*)xsr;
  f16x8 xb2 = *(const f16x8*)(xsr + 8);
#pragma unroll
  for (int q = 0; q < 4; ++q) {
    f32x4 cur = *(const f32x4*)(yt + q * 4);
#pragma unroll
    for (int e4 = 0; e4 < 4; ++e4) {
      int o = q * 4 + e4;
      float xf = (float)((o < 8) ? xa[o] : xb2[o - 8]);
      cur[e4] += e * acc[q][e4] + Dh * xf;
    }
    *(f32x4*)(yt + q * 4) = cur;
  }
}

// ---------------- gate (silu(z)) + RMSNorm + cast bf16 ----------------
__global__ __launch_bounds__(192)
void k_rms(const unsigned short* __restrict__ z, const float* __restrict__ ytot,
           const float* __restrict__ norm_w, unsigned short* __restrict__ ynorm)
{
  const int row = blockIdx.x, tid = threadIdx.x;
  const int e0 = tid * 8;
  us8 zv = *(const us8*)(z + (size_t)row * DI + e0);
  const float* yr = ytot + (size_t)row * DI;
  f32x4 yv0 = *(const f32x4*)(yr + e0);
  f32x4 yv1 = *(const f32x4*)(yr + e0 + 4);
  float g[8];
  float ss = 0.f;
#pragma unroll
  for (int q = 0; q < 8; ++q) {
    float yq = (q < 4) ? yv0[q] : yv1[q - 4];
    g[q] = yq * siluf(bf2f(zv[q]));
    ss += g[q] * g[q];
  }
#pragma unroll
  for (int off = 32; off > 0; off >>= 1) ss += __shfl_down(ss, off);
  __shared__ float wsum[3];
  __shared__ float sscale;
  if ((tid & 63) == 0) wsum[tid >> 6] = ss;
  __syncthreads();
  if (tid == 0) sscale = rsqrtf((wsum[0] + wsum[1] + wsum[2]) * (1.f / DI) + 1e-5f);
  __syncthreads();
  const float sc = sscale;
  us8 o;
#pragma unroll
  for (int q = 0; q < 8; ++q) o[q] = f2bf(g[q] * sc * norm_w[e0 + q]);
  *(us8*)(ynorm + (size_t)row * DI + e0) = o;
}

extern "C" void kernel_launch(void* const* d_in, const int* in_sizes, int n_in,
                              void* d_out, int out_size, void* d_ws, size_t ws_size,
                              hipStream_t stream)
{
  (void)in_sizes; (void)n_in; (void)out_size;
  const float* x       = (const float*)d_in[0];
  const float* W_in    = (const float*)d_in[1];
  const float* conv_w  = (const float*)d_in[2];
  const float* conv_b  = (const float*)d_in[3];
  const float* dt_bias = (const float*)d_in[4];
  const float* A_log   = (const float*)d_in[5];
  const float* Dp      = (const float*)d_in[6];
  const float* norm_w  = (const float*)d_in[7];
  const float* W_out   = (const float*)d_in[8];
  float* out = (float*)d_out;

  // ---- batches per pass: footprint(nb) = nb*L_*22464 + 7,385,088 ----
  const int nb = ((size_t)2 * L_ * 22464 + 7385088 <= ws_size) ? 2 : 1;
  const int rows = nb * L_;

  // ---- workspace layout (per-pass buffers) ----
  char* ws = (char*)d_ws;
  unsigned short* zseg = (unsigned short*)ws;  ws += (size_t)rows * DI * 2;   // bf16 z
  unsigned short* xbc  = (unsigned short*)ws;  ws += (size_t)rows * CD * 2;   // bf16 xBC
  _Float16* xs = (_Float16*)ws;  ws += (size_t)rows * DI * 2;                 // fp16 conv-x
  float* ytot = (float*)ws;  ws += (size_t)rows * DI * 4;
  float* Bm   = (float*)ws;  ws += (size_t)rows * DS * 4;
  float* Cm   = (float*)ws;  ws += (size_t)rows * DS * 4;
  float* dtv  = (float*)ws;  ws += (size_t)rows * H_ * 4;
  float* cumA = (float*)ws;  ws += (size_t)rows * H_ * 4;
  float* Sbuf = (float*)ws;  ws += (size_t)rows * 6144;      // nb*H_*NC*DS*P_*4
  unsigned short* WinT  = (unsigned short*)ws; ws += (size_t)NPJ * DM * 2;
  unsigned short* WoutT = (unsigned short*)ws; ws += (size_t)DM * DI * 2;
  float* WdtT   = (float*)ws;  ws += (size_t)H_ * DM * 4;
  unsigned short* xb    = (unsigned short*)Sbuf;     // overlay: Sbuf dead until k_intra
  unsigned short* ynorm = (unsigned short*)xs;       // overlay: xs dead after k_inter

  k_transpose_cast<<<dim3(24, (NPJ + 31) / 32), 256, 0, stream>>>(W_in, WinT, DM, NPJ);
  k_transpose_cast<<<dim3(48, 24), 256, 0, stream>>>(W_out, WoutT, DI, DM);
  k_wdtT<<<(H_ * DM + 255) / 256, 256, 0, stream>>>(W_in, WdtT);

  for (int b0 = 0; b0 < B_; b0 += nb) {
    const float* xp = x + (size_t)b0 * L_ * DM;

    k_cast<<<rows * DM / 1024, 256, 0, stream>>>(xp, xb, rows * DM);
    k_gemm_t<128, 128, 64, 64, true><<<dim3(rows / 128, N1 / 128), 256, 0, stream>>>(
        xb, WinT, zseg, DI, DI, xbc, CD, DM);
    k_conv2<<<dim3(7, rows / CROWS), 256, 0, stream>>>(xbc, conv_w, conv_b, xs, Bm, Cm);
    k_dt2<<<rows / 8, 192, 0, stream>>>(xp, WdtT, dt_bias, dtv);
    k_cum<<<(nb * H_ * NC + 255) / 256, 256, 0, stream>>>(dtv, A_log, cumA, nb * H_ * NC);
    k_intra<<<dim3(NC, H_, nb), 256, 0, stream>>>(xs, Bm, Cm, dtv, cumA, ytot, Sbuf);
    k_chunkscan<<<dim3(16, H_, nb), 64, 0, stream>>>(Sbuf, cumA);
    k_inter<<<dim3(NC, H_, nb), 256, 0, stream>>>(xs, Cm, cumA, Sbuf, Dp, ytot);
    k_rms<<<rows, 192, 0, stream>>>(zseg, ytot, norm_w, ynorm);
    k_gemm_t<64, 64, 16, 64, false><<<dim3(rows / 64, DM / 64), 256, 0, stream>>>(
        ynorm, WoutT, out + (size_t)b0 * L_ * DM, DM, DM, out + (size_t)b0 * L_ * DM, DM, DI);
  }
}

// Round 9
// 342.900 us; speedup vs baseline: 1.9963x; 1.0643x over previous
//
#include <hip/hip_runtime.h>

// ---- problem constants ----
#define B_   2
#define L_   4096
#define DM   768
#define DI   1536     // D_INNER
#define DS   64       // D_STATE
#define H_   24       // NHEADS
#define P_   64       // HEADDIM
#define CD   1664     // CONV_DIM
#define NPJ  3224     // D_IN_PROJ
#define N1   3200     // GEMM1 useful cols (z + xBC; dt cols done exactly in k_dt2)
#define Q_   64       // chunk length
#define NC   64       // chunks per batch
#define SP   76       // LDS row stride (floats) for k_inter tiles
#define HS   72       // fp16 LDS row stride (halves): <=2-way conflicts
#define WDS  772      // k_dt2 LDS W stride
#define CROWS 16      // conv rows per thread

typedef short          bf16x8 __attribute__((ext_vector_type(8)));
typedef _Float16       f16x8  __attribute__((ext_vector_type(8)));
typedef unsigned short us8    __attribute__((ext_vector_type(8)));
typedef unsigned short us4    __attribute__((ext_vector_type(4)));
typedef float          f32x4  __attribute__((ext_vector_type(4)));

__device__ __forceinline__ unsigned short f2bf(float f) {
  unsigned u = __float_as_uint(f);
  u += 0x7fffu + ((u >> 16) & 1u);   // RNE
  return (unsigned short)(u >> 16);
}
__device__ __forceinline__ float bf2f(unsigned short u) {
  return __uint_as_float(((unsigned)u) << 16);
}
__device__ __forceinline__ float siluf(float x) { return x / (1.f + expf(-x)); }
__device__ __forceinline__ float softplusf(float x) { return (x > 20.f) ? x : log1pf(expf(x)); }

// async global->LDS, 16B per lane; LDS dest = uniform base + lane*16
__device__ __forceinline__ void gload16(const unsigned short* g, unsigned short* l) {
  __builtin_amdgcn_global_load_lds(
      (const __attribute__((address_space(1))) void*)g,
      (__attribute__((address_space(3))) void*)l, 16, 0, 0);
}

// ---------------- transpose + cast (R x C fp32) -> (C x R bf16) ----------------
__global__ __launch_bounds__(256)
void k_transpose_cast(const float* __restrict__ src, unsigned short* __restrict__ dst,
                      int R, int C)
{
  __shared__ float tile[32][33];
  const int tx = threadIdx.x & 31, ty = threadIdx.x >> 5;
  const int r0 = blockIdx.x * 32, c0 = blockIdx.y * 32;
#pragma unroll
  for (int r = 0; r < 4; ++r) {
    int rr = r0 + ty + r * 8, cc = c0 + tx;
    if (rr < R && cc < C) tile[ty + r * 8][tx] = src[(size_t)rr * C + cc];
  }
  __syncthreads();
#pragma unroll
  for (int r = 0; r < 4; ++r) {
    int orow = c0 + ty + r * 8, ocol = r0 + tx;
    if (orow < C && ocol < R) dst[(size_t)orow * R + ocol] = f2bf(tile[tx][ty + r * 8]);
  }
}

// ---------------- gather dt columns of W_in -> contiguous fp32 WdtT[24][768] ----------------
__global__ void k_wdtT(const float* __restrict__ W_in, float* __restrict__ WdtT)
{
  const int idx = blockIdx.x * 256 + threadIdx.x;
  if (idx >= H_ * DM) return;
  const int k = idx / H_, h = idx % H_;
  WdtT[(size_t)h * DM + k] = W_in[(size_t)k * NPJ + N1 + h];
}

// ---------------- bf16 MFMA GEMM, BK=64, XOR-swizzled LDS (conflict-free) ----------------
template<int BM, int BN, int WM, int WN, bool OUT_BF16>
__global__ __launch_bounds__(256)
void k_gemm_t(const unsigned short* __restrict__ A, const unsigned short* __restrict__ Bt,
              void* __restrict__ C0v, int ld0, int ncol0,
              void* __restrict__ C1v, int ld1, int K)
{
  constexpr int MI = WM / 16, NI = WN / 16;
  constexpr int WAVES_N = BN / WN;
  constexpr int RA = BM / 32, RB = BN / 32;
  const int m0 = blockIdx.x * BM, n0 = blockIdx.y * BN;
  __shared__ unsigned short As[BM][64];
  __shared__ unsigned short Bs[BN][64];
  const int tid  = threadIdx.x;
  const int wave = tid >> 6, lane = tid & 63;
  const int quad = lane >> 4, r16 = lane & 15;
  const int wm = (wave / WAVES_N) * WM, wn = (wave % WAVES_N) * WN;

  const int lr8 = lane >> 3;                                // 0..7 row-in-band
  const int csw = ((lane & 7) ^ lr8) * 8;                   // swizzled source col (shorts)
  const unsigned short* gA = A  + (size_t)(m0 + wave * 8 + lr8) * K + csw;
  const unsigned short* gB = Bt + (size_t)(n0 + wave * 8 + lr8) * K + csw;
  unsigned short* lA = &As[wave * 8][0] + (size_t)lane * 8; // +lane*16B
  unsigned short* lB = &Bs[wave * 8][0] + (size_t)lane * 8;

  f32x4 acc[MI][NI];
#pragma unroll
  for (int mi = 0; mi < MI; ++mi)
#pragma unroll
    for (int ni = 0; ni < NI; ++ni) acc[mi][ni] = (f32x4){0.f, 0.f, 0.f, 0.f};

  for (int k0 = 0; k0 < K; k0 += 64) {
#pragma unroll
    for (int r = 0; r < RA; ++r)
      gload16(gA + (size_t)(r * 32) * K + k0, lA + (size_t)r * 32 * 64);
#pragma unroll
    for (int r = 0; r < RB; ++r)
      gload16(gB + (size_t)(r * 32) * K + k0, lB + (size_t)r * 32 * 64);
    __syncthreads();
    bf16x8 af[MI][2], bfr[NI][2];
#pragma unroll
    for (int mi = 0; mi < MI; ++mi)
#pragma unroll
      for (int ks = 0; ks < 2; ++ks)
        af[mi][ks] = *(const bf16x8*)&As[wm + mi * 16 + r16][((quad + ks * 4) ^ (r16 & 7)) * 8];
#pragma unroll
    for (int ni = 0; ni < NI; ++ni)
#pragma unroll
      for (int ks = 0; ks < 2; ++ks)
        bfr[ni][ks] = *(const bf16x8*)&Bs[wn + ni * 16 + r16][((quad + ks * 4) ^ (r16 & 7)) * 8];
#pragma unroll
    for (int mi = 0; mi < MI; ++mi)
#pragma unroll
      for (int ni = 0; ni < NI; ++ni)
#pragma unroll
        for (int ks = 0; ks < 2; ++ks)
          acc[mi][ni] = __builtin_amdgcn_mfma_f32_16x16x32_bf16(
              af[mi][ks], bfr[ni][ks], acc[mi][ni], 0, 0, 0);
    __syncthreads();
  }
#pragma unroll
  for (int mi = 0; mi < MI; ++mi)
#pragma unroll
    for (int ni = 0; ni < NI; ++ni) {
      int col = n0 + wn + ni * 16 + r16;
      void* dst; int ld, c;
      if (col < ncol0) { dst = C0v; ld = ld0; c = col; }
      else             { dst = C1v; ld = ld1; c = col - ncol0; }
#pragma unroll
      for (int r = 0; r < 4; ++r) {
        int row = m0 + wm + mi * 16 + quad * 4 + r;
        if (OUT_BF16) ((unsigned short*)dst)[(size_t)row * ld + c] = f2bf(acc[mi][ni][r]);
        else          ((float*)dst)[(size_t)row * ld + c] = acc[mi][ni][r];
      }
    }
}

// ---------------- depthwise conv(4) + silu: sliding window, batch-boundary aware ----------------
__global__ __launch_bounds__(256)
void k_conv2(const unsigned short* __restrict__ xbc, const float* __restrict__ cw,
             const float* __restrict__ cb, _Float16* __restrict__ xs,
             float* __restrict__ Bm, float* __restrict__ Cm)
{
  const int ch = blockIdx.x * 256 + threadIdx.x;
  if (ch >= CD) return;
  const int r0 = blockIdx.y * CROWS;
  const float w0 = cw[ch * 4], w1 = cw[ch * 4 + 1], w2 = cw[ch * 4 + 2], w3 = cw[ch * 4 + 3];
  const float bias = cb[ch];
  float a, b, c;
  if ((r0 & (L_ - 1)) == 0) {                 // batch start: zero history
    a = 0.f; b = 0.f; c = 0.f;
  } else {
    a = bf2f(xbc[(size_t)(r0 - 3) * CD + ch]);
    b = bf2f(xbc[(size_t)(r0 - 2) * CD + ch]);
    c = bf2f(xbc[(size_t)(r0 - 1) * CD + ch]);
  }
#pragma unroll
  for (int i = 0; i < CROWS; ++i) {
    const int lr = r0 + i;
    float d = bf2f(xbc[(size_t)lr * CD + ch]);
    float v = siluf(bias + a * w0 + b * w1 + c * w2 + d * w3);
    a = b; b = c; c = d;
    if (ch < DI)           xs[(size_t)lr * DI + ch] = (_Float16)v;
    else if (ch < DI + DS) Bm[(size_t)lr * DS + (ch - DI)] = v;
    else                   Cm[(size_t)lr * DS + (ch - DI - DS)] = v;
  }
}

// ---------------- exact fp32 dt via LDS-staged WdtT + fused x->bf16 cast ----------------
// block = 192 threads = 24 heads x 8 rows; thread h also casts x chunk [h*32,h*32+32)
__global__ __launch_bounds__(192)
void k_dt2(const float* __restrict__ x, const float* __restrict__ WdtT,
           const float* __restrict__ dt_bias, float* __restrict__ dtv,
           unsigned short* __restrict__ xb)
{
  __shared__ float sW[H_][WDS];
  for (int i = threadIdx.x; i < H_ * DM; i += 192)
    sW[i / DM][i % DM] = WdtT[i];
  const int h = threadIdx.x % H_, rloc = threadIdx.x / H_;
  const int lrow = blockIdx.x * 8 + rloc;
  const float* xr = x + (size_t)lrow * DM;
  __syncthreads();
  float acc = 0.f;
#pragma unroll 8
  for (int k = 0; k < DM; k += 4) {
    f32x4 xv = *(const f32x4*)(xr + k);
    f32x4 wv = *(const f32x4*)&sW[h][k];
    acc += xv[0] * wv[0] + xv[1] * wv[1] + xv[2] * wv[2] + xv[3] * wv[3];
  }
  dtv[(size_t)lrow * H_ + h] = softplusf(acc + dt_bias[h]);
  // fused cast: 32-elem chunk per thread (L1-hot re-read)
  const float* xi = xr + h * 32;
  unsigned short* xo = xb + (size_t)lrow * DM + h * 32;
#pragma unroll
  for (int j = 0; j < 32; j += 8) {
    f32x4 a = *(const f32x4*)(xi + j);
    f32x4 b = *(const f32x4*)(xi + j + 4);
    us8 o;
#pragma unroll
    for (int e = 0; e < 4; ++e) { o[e] = f2bf(a[e]); o[e + 4] = f2bf(b[e]); }
    *(us8*)(xo + j) = o;
  }
}

// ---------------- per-chunk inclusive cumsum of dt*A ----------------
__global__ void k_cum(const float* __restrict__ dtv, const float* __restrict__ A_log,
                      float* __restrict__ cumA, int n)
{
  const int idx = blockIdx.x * 256 + threadIdx.x;      // ((bz*H+h)*NC + c)
  if (idx >= n) return;
  const int c = idx % NC;
  const int h = (idx / NC) % H_;
  const int bz = idx / (NC * H_);
  const float A = -expf(A_log[h]);
  float cum = 0.f;
  const int rowbase = bz * L_ + c * Q_;
  float* outp = cumA + (size_t)idx * Q_;
  for (int i = 0; i < Q_; ++i) {
    cum += dtv[(size_t)(rowbase + i) * H_ + h] * A;
    outp[i] = cum;
  }
}

// ---------------- intra-chunk via fp16 MFMA; ytot/Sbuf stored fp16 ----------------
__global__ __launch_bounds__(256)
void k_intra(const _Float16* __restrict__ xs, const float* __restrict__ Bm,
             const float* __restrict__ Cm, const float* __restrict__ dtv,
             const float* __restrict__ cumA, _Float16* __restrict__ ytot,
             _Float16* __restrict__ Sbuf)
{
  const int c = blockIdx.x, h = blockIdx.y, bz = blockIdx.z;
  const int gidx = (bz * H_ + h) * NC + c;
  __shared__ _Float16 sCW[Q_][HS];   // C, then W
  __shared__ _Float16 sB [Q_][HS];
  __shared__ _Float16 sBT[Q_][HS];   // (coef_j * B[j][n]) transposed -> [n][j]
  __shared__ _Float16 sXT[Q_][HS];   // X transposed -> [p][j]
  __shared__ float scum[Q_], sdt[Q_];
  const int tid = threadIdx.x;
  const int rowbase = bz * L_ + c * Q_;

  {
    const int j = tid >> 2, s16 = (tid & 3) * 16;
    if (tid < Q_) {
      scum[tid] = cumA[(size_t)gidx * Q_ + tid];
      sdt[tid]  = dtv[(size_t)(rowbase + tid) * H_ + h];
    }
    const _Float16* xsrc = xs + (size_t)(rowbase + j) * DI + h * P_ + s16;
    f16x8 xv0 = *(const f16x8*)xsrc;
    f16x8 xv1 = *(const f16x8*)(xsrc + 8);
    f32x4 bv[4], cv[4];
    const float* bsrc = Bm + (size_t)(rowbase + j) * DS + s16;
    const float* csrc = Cm + (size_t)(rowbase + j) * DS + s16;
#pragma unroll
    for (int q = 0; q < 4; ++q) {
      bv[q] = *(const f32x4*)(bsrc + q * 4);
      cv[q] = *(const f32x4*)(csrc + q * 4);
    }
    __syncthreads();
    const float coef = expf(scum[Q_ - 1] - scum[j]) * sdt[j];
    union { f16x8 v; _Float16 e[8]; } pc[2], pb[2];
#pragma unroll
    for (int q = 0; q < 4; ++q)
#pragma unroll
      for (int e = 0; e < 4; ++e) {
        int o = q * 4 + e;
        pc[o >> 3].e[o & 7] = (_Float16)cv[q][e];
        pb[o >> 3].e[o & 7] = (_Float16)bv[q][e];
        sBT[s16 + o][j] = (_Float16)(bv[q][e] * coef);
        sXT[s16 + o][j] = (o < 8) ? xv0[o] : xv1[o - 8];
      }
    *(f16x8*)&sCW[j][s16]     = pc[0].v;
    *(f16x8*)&sCW[j][s16 + 8] = pc[1].v;
    *(f16x8*)&sB [j][s16]     = pb[0].v;
    *(f16x8*)&sB [j][s16 + 8] = pb[1].v;
  }
  __syncthreads();

  const int wave = tid >> 6, lane = tid & 63;
  const int quad = lane >> 4, r16 = lane & 15;
  const int i0 = wave * 16;
  const int irow = i0 + quad * 4;

  f32x4 g[4];
#pragma unroll
  for (int q = 0; q < 4; ++q) g[q] = (f32x4){0.f, 0.f, 0.f, 0.f};
#pragma unroll
  for (int ni = 0; ni < 4; ++ni) {
    if (ni <= wave) {
#pragma unroll
      for (int ks = 0; ks < 2; ++ks)
        g[ni] = __builtin_amdgcn_mfma_f32_16x16x32_f16(
            *(const f16x8*)&sCW[i0 + r16][ks * 32 + quad * 8],
            *(const f16x8*)&sB [ni * 16 + r16][ks * 32 + quad * 8], g[ni], 0, 0, 0);
    }
  }
  float wv[4][4];
#pragma unroll
  for (int ni = 0; ni < 4; ++ni)
#pragma unroll
    for (int r = 0; r < 4; ++r) {
      int i = irow + r, jcol = ni * 16 + r16;
      float v = 0.f;
      if (ni <= wave && jcol <= i)
        v = g[ni][r] * expf(scum[i] - scum[jcol]) * sdt[jcol];
      wv[ni][r] = v;
    }
  __syncthreads();
#pragma unroll
  for (int ni = 0; ni < 4; ++ni)
#pragma unroll
    for (int r = 0; r < 4; ++r)
      sCW[irow + r][ni * 16 + r16] = (_Float16)wv[ni][r];
  __syncthreads();

  f32x4 y[4];
#pragma unroll
  for (int q = 0; q < 4; ++q) y[q] = (f32x4){0.f, 0.f, 0.f, 0.f};
#pragma unroll
  for (int ni = 0; ni < 4; ++ni)
#pragma unroll
    for (int ks = 0; ks < 2; ++ks) {
      if (ks == 0 || wave >= 2)
        y[ni] = __builtin_amdgcn_mfma_f32_16x16x32_f16(
            *(const f16x8*)&sCW[i0 + r16][ks * 32 + quad * 8],
            *(const f16x8*)&sXT[ni * 16 + r16][ks * 32 + quad * 8], y[ni], 0, 0, 0);
    }
#pragma unroll
  for (int ni = 0; ni < 4; ++ni)
#pragma unroll
    for (int r = 0; r < 4; ++r)
      ytot[(size_t)(rowbase + irow + r) * DI + h * P_ + ni * 16 + r16] = (_Float16)y[ni][r];

  f32x4 t4[4];
#pragma unroll
  for (int q = 0; q < 4; ++q) t4[q] = (f32x4){0.f, 0.f, 0.f, 0.f};
#pragma unroll
  for (int ni = 0; ni < 4; ++ni)
#pragma unroll
    for (int ks = 0; ks < 2; ++ks)
      t4[ni] = __builtin_amdgcn_mfma_f32_16x16x32_f16(
          *(const f16x8*)&sBT[i0 + r16][ks * 32 + quad * 8],
          *(const f16x8*)&sXT[ni * 16 + r16][ks * 32 + quad * 8], t4[ni], 0, 0, 0);
  _Float16* sp = Sbuf + (size_t)gidx * (DS * P_);
#pragma unroll
  for (int ni = 0; ni < 4; ++ni)
#pragma unroll
    for (int r = 0; r < 4; ++r)
      sp[(irow + r) * P_ + ni * 16 + r16] = (_Float16)t4[ni][r];
}

// ---------------- sequential inter-chunk recurrence (in-place, fp16 storage) ----------------
__global__ void k_chunkscan(_Float16* __restrict__ Sbuf, const float* __restrict__ cumA)
{
  const int seg = blockIdx.x, h = blockIdx.y, bz = blockIdx.z;
  const int bh = bz * H_ + h;
  __shared__ float dec[NC];
  const int tid = threadIdx.x;
  if (tid < NC) dec[tid] = expf(cumA[((size_t)(bh * NC + tid)) * Q_ + (Q_ - 1)]);
  __syncthreads();
  const size_t off = (size_t)seg * 512 + (size_t)tid * 8;
  float s[8];
#pragma unroll
  for (int e = 0; e < 8; ++e) s[e] = 0.f;
  size_t base = (size_t)bh * NC * (DS * P_) + off;
  for (int c = 0; c < NC; ++c) {
    _Float16* p = Sbuf + base + (size_t)c * (DS * P_);
    f16x8 v = *(const f16x8*)p;
    f16x8 sto;
#pragma unroll
    for (int e = 0; e < 8; ++e) sto[e] = (_Float16)s[e];
    *(f16x8*)p = sto;                    // store state BEFORE chunk c
    const float d = dec[c];
#pragma unroll
    for (int e = 0; e < 8; ++e) s[e] = s[e] * d + (float)v[e];
  }
}

// ---------------- inter-chunk correction + D*x (ytot fp16 RMW) ----------------
__global__ __launch_bounds__(256)
void k_inter(const _Float16* __restrict__ xs, const float* __restrict__ Cm,
             const float* __restrict__ cumA, const _Float16* __restrict__ Sbuf,
             const float* __restrict__ Dp, _Float16* __restrict__ ytot)
{
  const int c = blockIdx.x, h = blockIdx.y, bz = blockIdx.z;
  const int gidx = (bz * H_ + h) * NC + c;
  __shared__ float sS[DS][SP];
  __shared__ float sC[Q_][SP];
  __shared__ float scum[Q_];
  const int tid = threadIdx.x;
  const int jr = tid >> 2, blk = (tid & 3) * 16;
  const int rowbase = bz * L_ + c * Q_;
  {
    const _Float16* ssrc = Sbuf + (size_t)gidx * (DS * P_) + jr * P_ + blk;
    f16x8 sv0 = *(const f16x8*)ssrc;
    f16x8 sv1 = *(const f16x8*)(ssrc + 8);
    const float* csrc = Cm + (size_t)(rowbase + jr) * DS + blk;
#pragma unroll
    for (int o = 0; o < 8; ++o) {
      sS[jr][blk + o]     = (float)sv0[o];
      sS[jr][blk + 8 + o] = (float)sv1[o];
    }
#pragma unroll
    for (int q = 0; q < 4; ++q)
      *(f32x4*)&sC[jr][blk + q * 4] = *(const f32x4*)(csrc + q * 4);
    if (tid < Q_) scum[tid] = cumA[(size_t)gidx * Q_ + tid];
  }
  __syncthreads();
  const int i = jr;
  f32x4 acc[4];
#pragma unroll
  for (int q = 0; q < 4; ++q) acc[q] = (f32x4){0.f, 0.f, 0.f, 0.f};
  for (int n = 0; n < DS; ++n) {
    float cv = sC[i][n];
#pragma unroll
    for (int q = 0; q < 4; ++q) acc[q] += cv * *(const f32x4*)&sS[n][blk + q * 4];
  }
  const float e = expf(scum[i]);
  const float Dh = Dp[h];
  _Float16* yt = ytot + (size_t)(rowbase + i) * DI + h * P_ + blk;
  const _Float16* xsr = xs + (size_t)(rowbase + i) * DI + h * P_ + blk;
  f16x8 xa = *(const f16x8*)xsr;
  f16x8 xb2 = *(const f16x8*)(xsr + 8);
  f16x8 y0 = *(const f16x8*)yt;
  f16x8 y1 = *(const f16x8*)(yt + 8);
#pragma unroll
  for (int o = 0; o < 16; ++o) {
    float cur = (float)((o < 8) ? y0[o] : y1[o - 8]);
    float xf  = (float)((o < 8) ? xa[o] : xb2[o - 8]);
    cur += e * acc[o >> 2][o & 3] + Dh * xf;
    if (o < 8) y0[o] = (_Float16)cur; else y1[o - 8] = (_Float16)cur;
  }
  *(f16x8*)yt = y0;
  *(f16x8*)(yt + 8) = y1;
}

// ---------------- gate (silu(z)) + RMSNorm + cast bf16 ----------------
__global__ __launch_bounds__(192)
void k_rms(const unsigned short* __restrict__ z, const _Float16* __restrict__ ytot,
           const float* __restrict__ norm_w, unsigned short* __restrict__ ynorm)
{
  const int row = blockIdx.x, tid = threadIdx.x;
  const int e0 = tid * 8;
  us8 zv = *(const us8*)(z + (size_t)row * DI + e0);
  f16x8 yv = *(const f16x8*)(ytot + (size_t)row * DI + e0);
  float g[8];
  float ss = 0.f;
#pragma unroll
  for (int q = 0; q < 8; ++q) {
    g[q] = (float)yv[q] * siluf(bf2f(zv[q]));
    ss += g[q] * g[q];
  }
#pragma unroll
  for (int off = 32; off > 0; off >>= 1) ss += __shfl_down(ss, off);
  __shared__ float wsum[3];
  __shared__ float sscale;
  if ((tid & 63) == 0) wsum[tid >> 6] = ss;
  __syncthreads();
  if (tid == 0) sscale = rsqrtf((wsum[0] + wsum[1] + wsum[2]) * (1.f / DI) + 1e-5f);
  __syncthreads();
  const float sc = sscale;
  us8 o;
#pragma unroll
  for (int q = 0; q < 8; ++q) o[q] = f2bf(g[q] * sc * norm_w[e0 + q]);
  *(us8*)(ynorm + (size_t)row * DI + e0) = o;
}

extern "C" void kernel_launch(void* const* d_in, const int* in_sizes, int n_in,
                              void* d_out, int out_size, void* d_ws, size_t ws_size,
                              hipStream_t stream)
{
  (void)in_sizes; (void)n_in; (void)out_size;
  const float* x       = (const float*)d_in[0];
  const float* W_in    = (const float*)d_in[1];
  const float* conv_w  = (const float*)d_in[2];
  const float* conv_b  = (const float*)d_in[3];
  const float* dt_bias = (const float*)d_in[4];
  const float* A_log   = (const float*)d_in[5];
  const float* Dp      = (const float*)d_in[6];
  const float* norm_w  = (const float*)d_in[7];
  const float* W_out   = (const float*)d_in[8];
  float* out = (float*)d_out;

  // ---- batches per pass: footprint(nb) = nb*L_*16320 + 7,385,088 ----
  const int nb = ((size_t)2 * L_ * 16320 + 7385088 <= ws_size) ? 2 : 1;
  const int rows = nb * L_;

  // ---- workspace layout (per-pass buffers) ----
  char* ws = (char*)d_ws;
  unsigned short* zseg = (unsigned short*)ws;  ws += (size_t)rows * DI * 2;   // bf16 z
  unsigned short* xbc  = (unsigned short*)ws;  ws += (size_t)rows * CD * 2;   // bf16 xBC
  _Float16* xs   = (_Float16*)ws;  ws += (size_t)rows * DI * 2;               // fp16 conv-x
  _Float16* ytot = (_Float16*)ws;  ws += (size_t)rows * DI * 2;               // fp16 y
  float* Bm   = (float*)ws;  ws += (size_t)rows * DS * 4;
  float* Cm   = (float*)ws;  ws += (size_t)rows * DS * 4;
  float* dtv  = (float*)ws;  ws += (size_t)rows * H_ * 4;
  float* cumA = (float*)ws;  ws += (size_t)rows * H_ * 4;
  _Float16* Sbuf = (_Float16*)ws;  ws += (size_t)rows * 3072;  // nb*H_*NC*DS*P_*2
  unsigned short* WinT  = (unsigned short*)ws; ws += (size_t)NPJ * DM * 2;
  unsigned short* WoutT = (unsigned short*)ws; ws += (size_t)DM * DI * 2;
  float* WdtT   = (float*)ws;  ws += (size_t)H_ * DM * 4;
  unsigned short* xb    = (unsigned short*)Sbuf;     // overlay: Sbuf dead until k_intra
  unsigned short* ynorm = (unsigned short*)xs;       // overlay: xs dead after k_inter

  k_transpose_cast<<<dim3(24, (NPJ + 31) / 32), 256, 0, stream>>>(W_in, WinT, DM, NPJ);
  k_transpose_cast<<<dim3(48, 24), 256, 0, stream>>>(W_out, WoutT, DI, DM);
  k_wdtT<<<(H_ * DM + 255) / 256, 256, 0, stream>>>(W_in, WdtT);

  for (int b0 = 0; b0 < B_; b0 += nb) {
    const float* xp = x + (size_t)b0 * L_ * DM;

    k_dt2<<<rows / 8, 192, 0, stream>>>(xp, WdtT, dt_bias, dtv, xb);
    k_gemm_t<128, 128, 64, 64, true><<<dim3(rows / 128, N1 / 128), 256, 0, stream>>>(
        xb, WinT, zseg, DI, DI, xbc, CD, DM);
    k_conv2<<<dim3(7, rows / CROWS), 256, 0, stream>>>(xbc, conv_w, conv_b, xs, Bm, Cm);
    k_cum<<<(nb * H_ * NC + 255) / 256, 256, 0, stream>>>(dtv, A_log, cumA, nb * H_ * NC);
    k_intra<<<dim3(NC, H_, nb), 256, 0, stream>>>(xs, Bm, Cm, dtv, cumA, ytot, Sbuf);
    k_chunkscan<<<dim3(8, H_, nb), 64, 0, stream>>>(Sbuf, cumA);
    k_inter<<<dim3(NC, H_, nb), 256, 0, stream>>>(xs, Cm, cumA, Sbuf, Dp, ytot);
    k_rms<<<rows, 192, 0, stream>>>(zseg, ytot, norm_w, ynorm);
    k_gemm_t<128, 64, 64, 32, false><<<dim3(rows / 128, DM / 64), 256, 0, stream>>>(
        ynorm, WoutT, out + (size_t)b0 * L_ * DM, DM, DM, out + (size_t)b0 * L_ * DM, DM, DI);
  }
}